// Round 3
// baseline (938.909 us; speedup 1.0000x reference)
//
#include <hip/hip_runtime.h>

typedef unsigned short u16;

#define HDIM 512
#define NHEAD 8
#define GNUM 64
#define CNUM 10
#define SLOPE 0.01f
#define BNEPS 1e-5f

__device__ __forceinline__ float b2f(u16 u) { return __uint_as_float(((unsigned)u) << 16); }
__device__ __forceinline__ u16 f2b(float f) {
    unsigned u = __float_as_uint(f);
    u += 0x7FFFu + ((u >> 16) & 1u);
    return (u16)(u >> 16);
}

// ---- dtype detect: flag=1 if x is bf16, 0 if f32 ----
// bf16 data: even u16 indices are real bf16 values of N(0,1) -> exp field in [100,140] ~99.8%.
// f32 data: even u16 indices are low mantissa halves -> uniform -> ~16% in range.
__global__ void detect_kernel(const void* x, int* flag) {
    const u16* p = (const u16*)x;
    int t = threadIdx.x;
    int cnt = 0;
    for (int i = t; i < 2048; i += 256) {
        u16 v = p[2 * i];
        int e = (v >> 7) & 0xFF;
        if (e >= 100 && e <= 140) cnt++;
    }
    __shared__ int s[256];
    s[t] = cnt;
    __syncthreads();
    for (int o = 128; o > 0; o >>= 1) { if (t < o) s[t] += s[t + o]; __syncthreads(); }
    if (t == 0) *flag = (s[0] > 1024) ? 1 : 0;
}

// ---- batched convert of all float tensors to f32 staging ----
#define NT 23
struct CvtTab { const void* src[NT]; float* dst[NT]; int n[NT]; };

__global__ void cvt_kernel(CvtTab tab, const int* flag) {
    int ti = blockIdx.y;
    int n = tab.n[ti];
    float* dst = tab.dst[ti];
    int bf = *flag;
    if (bf) {
        const u16* s = (const u16*)tab.src[ti];
        for (int i = blockIdx.x * 256 + threadIdx.x; i < n; i += gridDim.x * 256)
            dst[i] = b2f(s[i]);
    } else {
        const float* s = (const float*)tab.src[ti];
        for (int i = blockIdx.x * 256 + threadIdx.x; i < n; i += gridDim.x * 256)
            dst[i] = s[i];
    }
}

__global__ void sentinel_kernel(float* out, int n, float val) {
    int i = blockIdx.x * 256 + threadIdx.x;
    if (i < n) out[i] = val;
}

__global__ void zero_i32_kernel(int* __restrict__ p, int n) {
    int i = blockIdx.x * 256 + threadIdx.x;
    if (i < n) p[i] = 0;
}

// ---- fp32 VALU GEMM: C[M,512] = A[M,K] @ W[K,512], tile 64x64, BK=32, 4x4/thread ----
__global__ __launch_bounds__(256) void gemm_f32(const float* __restrict__ A,
                                                const float* __restrict__ W,
                                                float* __restrict__ C, int M, int K) {
    __shared__ float As[64 * 37];  // [m][k], pad 37 (scalar access, bank-spread)
    __shared__ float Ws[32 * 68];  // [k][n], pad 68 (16B-aligned float4 rows)
    int t = threadIdx.x;
    int bm = blockIdx.x * 64, bn = blockIdx.y * 64;
    int tx = t & 15, ty = t >> 4;
    int lr = t >> 2, lc = (t & 3) * 8;   // A stage: row lr, k cols lc..lc+7
    int wr = t >> 3, wc = (t & 7) * 8;   // W stage: k row wr, n cols wc..wc+7
    float acc[4][4];
    for (int i = 0; i < 4; i++) for (int j = 0; j < 4; j++) acc[i][j] = 0.f;

    for (int kt = 0; kt < K; kt += 32) {
        float a0[8], w0[8];
        int ar = bm + lr;
        bool aok = ar < M;
        const float* Ap = A + (size_t)ar * K + kt + lc;
        #pragma unroll
        for (int j = 0; j < 8; j++) a0[j] = aok ? Ap[j] : 0.f;
        const float* Wp = W + (size_t)(kt + wr) * HDIM + bn + wc;
        #pragma unroll
        for (int j = 0; j < 8; j++) w0[j] = Wp[j];
        __syncthreads();
        #pragma unroll
        for (int j = 0; j < 8; j++) As[lr * 37 + lc + j] = a0[j];
        #pragma unroll
        for (int j = 0; j < 8; j++) Ws[wr * 68 + wc + j] = w0[j];
        __syncthreads();
        #pragma unroll
        for (int kk = 0; kk < 32; kk++) {
            float av[4];
            #pragma unroll
            for (int i = 0; i < 4; i++) av[i] = As[(ty * 4 + i) * 37 + kk];
            float4 wq = *(const float4*)&Ws[kk * 68 + tx * 4];
            #pragma unroll
            for (int i = 0; i < 4; i++) {
                acc[i][0] += av[i] * wq.x;
                acc[i][1] += av[i] * wq.y;
                acc[i][2] += av[i] * wq.z;
                acc[i][3] += av[i] * wq.w;
            }
        }
    }
    for (int i = 0; i < 4; i++) {
        int r = bm + ty * 4 + i;
        if (r < M) {
            float4 o;
            o.x = acc[i][0]; o.y = acc[i][1]; o.z = acc[i][2]; o.w = acc[i][3];
            *(float4*)&C[(size_t)r * HDIM + bn + tx * 4] = o;
        }
    }
}

// ---- e_src/e_dst [N,8]: per-head dot of h row with a_src/a_dst ----
__global__ void escore_kernel(const float* __restrict__ h, const float* __restrict__ a_src,
                              const float* __restrict__ a_dst, float* __restrict__ es,
                              float* __restrict__ ed, int n) {
    int wid = blockIdx.x * 4 + (threadIdx.x >> 6);
    int lane = threadIdx.x & 63;
    if (wid >= n * NHEAD) return;
    int node = wid >> 3, hh = wid & 7;
    float hv = h[(size_t)node * HDIM + hh * 64 + lane];
    float s1 = hv * a_src[hh * 64 + lane];
    float s2 = hv * a_dst[hh * 64 + lane];
    for (int o = 32; o > 0; o >>= 1) {
        s1 += __shfl_down(s1, o);
        s2 += __shfl_down(s2, o);
    }
    if (lane == 0) { es[wid] = s1; ed[wid] = s2; }
}

// ---- counting sort of edges by dst ----
__global__ void hist_kernel(const int* __restrict__ ei, int* __restrict__ deg, int E) {
    int e = blockIdx.x * 256 + threadIdx.x;
    if (e < E) atomicAdd(&deg[ei[E + e]], 1);
}

__global__ void scan_kernel(const int* __restrict__ deg, int* __restrict__ offs,
                            int* __restrict__ cursor, int n) {
    __shared__ int lds[1024];
    int t = threadIdx.x;
    const int CH = 16;
    int base = t * CH;
    int local[CH];
    int s = 0;
    for (int i = 0; i < CH; i++) {
        int idx = base + i;
        local[i] = (idx < n) ? deg[idx] : 0;
        s += local[i];
    }
    lds[t] = s;
    __syncthreads();
    for (int off = 1; off < 1024; off <<= 1) {
        int v = lds[t];
        int add = (t >= off) ? lds[t - off] : 0;
        __syncthreads();
        lds[t] = v + add;
        __syncthreads();
    }
    int ex = (t == 0) ? 0 : lds[t - 1];
    for (int i = 0; i < CH; i++) {
        int idx = base + i;
        if (idx < n) { offs[idx] = ex; cursor[idx] = ex; ex += local[i]; }
    }
}

__global__ void scatter_kernel(const int* __restrict__ ei, int* __restrict__ cursor,
                               int* __restrict__ ssrc, int E) {
    int e = blockIdx.x * 256 + threadIdx.x;
    if (e < E) {
        int p = atomicAdd(&cursor[ei[E + e]], 1);
        ssrc[p] = ei[e];
    }
}

// ---- fused per-dst softmax + aggregation + bias + ELU (+ residual) ----
// one wave per dst node; lane covers features [lane*8, lane*8+8), head = lane>>3
__global__ void agg_kernel(const float* __restrict__ h, const float* __restrict__ es,
                           const float* __restrict__ ed, const int* __restrict__ offs,
                           const int* __restrict__ deg, const int* __restrict__ ssrc,
                           const float* __restrict__ bias, float* __restrict__ out,
                           const float* __restrict__ resid_in, float* __restrict__ resid_out,
                           int n) {
    int node = blockIdx.x * 4 + (threadIdx.x >> 6);
    int lane = threadIdx.x & 63;
    if (node >= n) return;
    int hh = lane >> 3, f = lane * 8;
    float edv = ed[node * NHEAD + hh];
    int st = offs[node], cnt = deg[node];

    float mx = -1e30f;
    for (int i = 0; i < cnt; i++) {
        int s = ssrc[st + i];
        float ev = es[s * NHEAD + hh] + edv;
        ev = ev > 0.f ? ev : SLOPE * ev;
        mx = fmaxf(mx, ev);
    }
    float den = 0.f;
    float acc[8] = {0.f, 0.f, 0.f, 0.f, 0.f, 0.f, 0.f, 0.f};
    for (int i = 0; i < cnt; i++) {
        int s = ssrc[st + i];
        float ev = es[s * NHEAD + hh] + edv;
        ev = ev > 0.f ? ev : SLOPE * ev;
        float w = __expf(ev - mx);
        den += w;
        const float* hp = h + (size_t)s * HDIM + f;
        float4 h0 = *(const float4*)hp;
        float4 h1 = *(const float4*)(hp + 4);
        acc[0] += w * h0.x; acc[1] += w * h0.y; acc[2] += w * h0.z; acc[3] += w * h0.w;
        acc[4] += w * h1.x; acc[5] += w * h1.y; acc[6] += w * h1.z; acc[7] += w * h1.w;
    }
    float inv = den > 0.f ? 1.f / den : 0.f;
    float o[8];
    for (int j = 0; j < 8; j++) {
        float v = acc[j] * inv + bias[f + j];
        o[j] = v > 0.f ? v : __expf(v) - 1.f;  // ELU
    }
    float* op = out + (size_t)node * HDIM + f;
    *(float4*)op = make_float4(o[0], o[1], o[2], o[3]);
    *(float4*)(op + 4) = make_float4(o[4], o[5], o[6], o[7]);
    if (resid_in) {
        const float* rp = resid_in + (size_t)node * HDIM + f;
        float4 r0 = *(const float4*)rp;
        float4 r1 = *(const float4*)(rp + 4);
        float* qp = resid_out + (size_t)node * HDIM + f;
        *(float4*)qp = make_float4(o[0] + r0.x, o[1] + r0.y, o[2] + r0.z, o[3] + r0.w);
        *(float4*)(qp + 4) = make_float4(o[4] + r1.x, o[5] + r1.y, o[6] + r1.z, o[7] + r1.w);
    }
}

// ---- pooling: pooled[g, 2048] = segment_max over batch (sorted); NaN guard is diagnostic ----
__global__ void pool_kernel(const float* __restrict__ xt, const float* __restrict__ x1,
                            const float* __restrict__ x2, const float* __restrict__ x3,
                            const int* __restrict__ batch, float* __restrict__ pooled, int n) {
    int g = blockIdx.x;
    int chunk = blockIdx.y;  // 0..7
    int t = threadIdx.x;
    const float* srcs[4] = {xt, x1, x2, x3};
    const float* src = srcs[chunk >> 1];
    int scol = (chunk & 1) * 256 + t;
    int lo = 0, hi = n;
    while (lo < hi) { int mid = (lo + hi) >> 1; if (batch[mid] < g) lo = mid + 1; else hi = mid; }
    int start = lo;
    lo = start; hi = n;
    while (lo < hi) { int mid = (lo + hi) >> 1; if (batch[mid] < g + 1) lo = mid + 1; else hi = mid; }
    int end = lo;
    float mx = -1e30f;
    int bad = 0;
    for (int i = start; i < end; i++) {
        float v = src[(size_t)i * HDIM + scol];
        if (v != v) bad = 1;       // NaN upstream -> diagnostic sentinel
        mx = fmaxf(mx, v);
    }
    if (start == end) mx = 0.f;    // empty segment: -inf -> 0 (isfinite clamp)
    if (bad) mx = 12345.f;
    pooled[g * (4 * HDIM) + chunk * 256 + t] = mx;
}

// ---- MLP layer 1: z[64,512] = pooled[64,2048] @ mW1 + mb1 ----
__global__ void mlp1_kernel(const float* __restrict__ pooled, const float* __restrict__ mW1f,
                            const float* __restrict__ mb1f, float* __restrict__ z) {
    int g = blockIdx.x;  // 64
    int t = threadIdx.x; // 256, each does cols t and t+256
    const float* pr = pooled + g * 2048;
    float acc0 = 0.f, acc1 = 0.f;
    for (int k = 0; k < 2048; k++) {
        float pv = pr[k];
        acc0 += pv * mW1f[(size_t)k * HDIM + t];
        acc1 += pv * mW1f[(size_t)k * HDIM + 256 + t];
    }
    z[g * HDIM + t] = acc0 + mb1f[t];
    z[g * HDIM + 256 + t] = acc1 + mb1f[256 + t];
}

// ---- BatchNorm (batch stats over 64 graphs) + ReLU ----
__global__ void bn_relu_kernel(const float* __restrict__ z, const float* __restrict__ gammaf,
                               const float* __restrict__ betaf, float* __restrict__ zn) {
    int col = blockIdx.x;  // 512
    int g = threadIdx.x;   // 64 = one wave
    float v = z[g * HDIM + col];
    float s = v;
    for (int o = 32; o > 0; o >>= 1) s += __shfl_xor(s, o);
    float mu = s * (1.f / 64.f);
    float d = v - mu;
    float s2 = d * d;
    for (int o = 32; o > 0; o >>= 1) s2 += __shfl_xor(s2, o);
    float var = s2 * (1.f / 64.f);
    float o = d * rsqrtf(var + BNEPS) * gammaf[col] + betaf[col];
    zn[g * HDIM + col] = fmaxf(o, 0.f);
}

// ---- final: out[64,10] = zn @ mW2 + mb2; output dtype per flag ----
__global__ void final_kernel(const float* __restrict__ zn, const float* __restrict__ mW2f,
                             const float* __restrict__ mb2f, void* __restrict__ out,
                             const int* __restrict__ flag) {
    int t = threadIdx.x;
    if (t >= GNUM * CNUM) return;
    int g = t / CNUM, c = t - g * CNUM;
    float acc = mb2f[c];
    for (int k = 0; k < HDIM; k++) acc += zn[g * HDIM + k] * mW2f[k * CNUM + c];
    if (*flag) ((u16*)out)[t] = f2b(acc);
    else ((float*)out)[t] = acc;
}

extern "C" void kernel_launch(void* const* d_in, const int* in_sizes, int n_in,
                              void* d_out, int out_size, void* d_ws, size_t ws_size,
                              hipStream_t stream) {
    const void* x = d_in[0];
    const int* ei = (const int*)d_in[1];
    const int* batch = (const int*)d_in[2];
    (void)n_in;

    int N = in_sizes[2];
    int E = in_sizes[1] / 2;
    int F0 = in_sizes[0] / N;

    // ---- workspace carve (256B-aligned) ----
    char* p = (char*)d_ws;
    auto alloc = [&](size_t bytes) -> char* {
        char* r = p;
        p += (bytes + 255) & ~(size_t)255;
        return r;
    };
    int* flag = (int*)alloc(4);
    float* xf = (float*)alloc((size_t)N * F0 * 4);
    float* Wf[4];
    Wf[0] = (float*)alloc((size_t)F0 * HDIM * 4);
    for (int l = 1; l < 4; l++) Wf[l] = (float*)alloc((size_t)HDIM * HDIM * 4);
    float* mW1f = (float*)alloc((size_t)4 * HDIM * HDIM * 4);
    float* asf[4], *adf[4], *bbf[4];
    for (int l = 0; l < 4; l++) {
        asf[l] = (float*)alloc(HDIM * 4);
        adf[l] = (float*)alloc(HDIM * 4);
        bbf[l] = (float*)alloc(HDIM * 4);
    }
    float* mb1f = (float*)alloc(HDIM * 4);
    float* gammaf = (float*)alloc(HDIM * 4);
    float* betaf = (float*)alloc(HDIM * 4);
    float* mW2f = (float*)alloc(HDIM * CNUM * 4);
    float* mb2f = (float*)alloc(CNUM * 4);
    float* hbuf = (float*)alloc((size_t)N * HDIM * 4);
    float* x0 = (float*)alloc((size_t)N * HDIM * 4);
    float* x1 = (float*)alloc((size_t)N * HDIM * 4);
    float* x2 = (float*)alloc((size_t)N * HDIM * 4);
    float* x3 = (float*)alloc((size_t)N * HDIM * 4);
    float* es = (float*)alloc((size_t)N * NHEAD * 4);
    float* ed = (float*)alloc((size_t)N * NHEAD * 4);
    int* deg = (int*)alloc((size_t)N * 4);
    int* offs = (int*)alloc((size_t)N * 4);
    int* cursor = (int*)alloc((size_t)N * 4);
    int* ssrc = (int*)alloc((size_t)E * 4);
    float* pooled = (float*)alloc((size_t)GNUM * 4 * HDIM * 4);
    float* z = (float*)alloc((size_t)GNUM * HDIM * 4);
    float* zn = (float*)alloc((size_t)GNUM * HDIM * 4);
    float* xt = x0;  // alias: x0 dead after residual add

    if ((size_t)(p - (char*)d_ws) > ws_size) {
        // diagnostic: workspace too small -> absmax ~997
        sentinel_kernel<<<(out_size + 255) / 256, 256, 0, stream>>>((float*)d_out, out_size, 999.f);
        return;
    }

    // ---- dtype detect + convert everything to f32 ----
    detect_kernel<<<1, 256, 0, stream>>>(x, flag);
    CvtTab tab;
    int ti = 0;
    auto add = [&](const void* s, float* d, int n) { tab.src[ti] = s; tab.dst[ti] = d; tab.n[ti] = n; ti++; };
    add(x, xf, N * F0);
    for (int l = 0; l < 4; l++) {
        add(d_in[3 + 4 * l], Wf[l], (l == 0 ? F0 : HDIM) * HDIM);
        add(d_in[4 + 4 * l], asf[l], HDIM);
        add(d_in[5 + 4 * l], adf[l], HDIM);
        add(d_in[6 + 4 * l], bbf[l], HDIM);
    }
    add(d_in[19], mW1f, 4 * HDIM * HDIM);
    add(d_in[20], mb1f, HDIM);
    add(d_in[21], gammaf, HDIM);
    add(d_in[22], betaf, HDIM);
    add(d_in[23], mW2f, HDIM * CNUM);
    add(d_in[24], mb2f, CNUM);
    dim3 cvt_grid(1024, NT);
    cvt_kernel<<<cvt_grid, 256, 0, stream>>>(tab, flag);

    // ---- counting sort of edges by dst (no float atomics anywhere) ----
    zero_i32_kernel<<<(N + 255) / 256, 256, 0, stream>>>(deg, N);
    hist_kernel<<<(E + 255) / 256, 256, 0, stream>>>(ei, deg, E);
    scan_kernel<<<1, 1024, 0, stream>>>(deg, offs, cursor, N);
    scatter_kernel<<<(E + 255) / 256, 256, 0, stream>>>(ei, cursor, ssrc, E);

    // ---- 4 GAT layers ----
    const float* lin[4] = {xf, x0, x1, x3};
    int lK[4] = {F0, HDIM, HDIM, HDIM};
    float* lout[4] = {x0, x1, x2, xt};
    dim3 gemm_grid((N + 63) / 64, HDIM / 64);
    int esc_blocks = (N * NHEAD + 3) / 4;
    int agg_blocks = (N + 3) / 4;
    for (int L = 0; L < 4; L++) {
        gemm_f32<<<gemm_grid, 256, 0, stream>>>(lin[L], Wf[L], hbuf, N, lK[L]);
        escore_kernel<<<esc_blocks, 256, 0, stream>>>(hbuf, asf[L], adf[L], es, ed, N);
        const float* rin = (L == 2) ? x0 : nullptr;
        float* rout = (L == 2) ? x3 : nullptr;
        agg_kernel<<<agg_blocks, 256, 0, stream>>>(hbuf, es, ed, offs, deg, ssrc, bbf[L],
                                                   lout[L], rin, rout, N);
    }

    // ---- pooling ----
    dim3 pool_grid(GNUM, 8);
    pool_kernel<<<pool_grid, 256, 0, stream>>>(xt, x1, x2, x3, batch, pooled, N);

    // ---- MLP head ----
    mlp1_kernel<<<GNUM, 256, 0, stream>>>(pooled, mW1f, mb1f, z);
    bn_relu_kernel<<<HDIM, 64, 0, stream>>>(z, gammaf, betaf, zn);
    final_kernel<<<1, 640, 0, stream>>>(zn, mW2f, mb2f, d_out, flag);
}

// Round 4
// 727.080 us; speedup vs baseline: 1.2913x; 1.2913x over previous
//
#include <hip/hip_runtime.h>

typedef unsigned short u16;
typedef __bf16 bfv8 __attribute__((ext_vector_type(8)));   // MFMA A/B fragment (4 VGPRs)
typedef float f32x4 __attribute__((ext_vector_type(4)));   // MFMA C/D fragment

#define HDIM 512
#define NHEAD 8
#define GNUM 64
#define CNUM 10
#define SLOPE 0.01f
#define BNEPS 1e-5f

__device__ __forceinline__ float b2f(u16 u) { return __uint_as_float(((unsigned)u) << 16); }
__device__ __forceinline__ u16 f2b(float f) {              // RNE f32->bf16
    unsigned u = __float_as_uint(f);
    u += 0x7FFFu + ((u >> 16) & 1u);
    return (u16)(u >> 16);
}
__device__ __forceinline__ void splitbf(float v, u16& hi, u16& lo) {
    u16 h = f2b(v);
    hi = h;
    lo = f2b(v - b2f(h));
}

__global__ void sentinel_kernel(float* out, int n, float val) {
    int i = blockIdx.x * 256 + threadIdx.x;
    if (i < n) out[i] = val;
}

__global__ void zero_i32_kernel(int* __restrict__ p, int n) {
    int i = blockIdx.x * 256 + threadIdx.x;
    if (i < n) p[i] = 0;
}

// ---- weight transpose+split: W[k][512] f32 -> Whi/Wlo[n][K] bf16 ----
__global__ void wsplit_kernel(const float* __restrict__ W, u16* __restrict__ Whi,
                              u16* __restrict__ Wlo, int K, int tot) {
    int idx = blockIdx.x * 256 + threadIdx.x;
    if (idx >= tot) return;
    int n = idx / K, k = idx - n * K;
    float v = W[(size_t)k * HDIM + n];
    splitbf(v, Whi[idx], Wlo[idx]);
}

// ---- activation split: f32 -> hi/lo bf16 ----
__global__ void xsplit_kernel(const float* __restrict__ x, u16* __restrict__ hi,
                              u16* __restrict__ lo, int n) {
    int i = blockIdx.x * 256 + threadIdx.x;
    if (i < n) splitbf(x[i], hi[i], lo[i]);
}

// ---- split-bf16 MFMA GEMM: C[M,512] = (Ah+Al) @ (Bh+Bl)^T, fp32-accurate (3-term) ----
__global__ __launch_bounds__(256) void gemm_split(const u16* __restrict__ Ah,
                                                  const u16* __restrict__ Al,
                                                  const u16* __restrict__ Bh,
                                                  const u16* __restrict__ Bl,
                                                  float* __restrict__ C, int M, int K) {
    __shared__ u16 sAh[64 * 40];   // [m][k], 32-k rows padded to 40 (80B stride, 16B-aligned)
    __shared__ u16 sAl[64 * 40];
    __shared__ u16 sBh[64 * 40];   // [n][k]
    __shared__ u16 sBl[64 * 40];
    int t = threadIdx.x;
    int bm = blockIdx.x * 64, bn = blockIdx.y * 64;
    int wv = t >> 6, lane = t & 63;
    int wm = (wv >> 1) * 32, wn = (wv & 1) * 32;
    int row = t >> 2, kc = (t & 3) * 8;
    int quad = lane >> 4, l16 = lane & 15;

    f32x4 acc[2][2];
    for (int a = 0; a < 2; a++)
        for (int b = 0; b < 2; b++)
            for (int r = 0; r < 4; r++) acc[a][b][r] = 0.f;

    bool aok = (bm + row) < M;
    const u16* Ahp = Ah + (size_t)(bm + row) * K + kc;
    const u16* Alp = Al + (size_t)(bm + row) * K + kc;
    const u16* Bhp = Bh + (size_t)(bn + row) * K + kc;
    const u16* Blp = Bl + (size_t)(bn + row) * K + kc;

    for (int kt = 0; kt < K; kt += 32) {
        int4 avh = make_int4(0, 0, 0, 0), avl = make_int4(0, 0, 0, 0);
        if (aok) { avh = *(const int4*)(Ahp + kt); avl = *(const int4*)(Alp + kt); }
        int4 bvh = *(const int4*)(Bhp + kt);
        int4 bvl = *(const int4*)(Blp + kt);
        __syncthreads();
        *(int4*)&sAh[row * 40 + kc] = avh;
        *(int4*)&sAl[row * 40 + kc] = avl;
        *(int4*)&sBh[row * 40 + kc] = bvh;
        *(int4*)&sBl[row * 40 + kc] = bvl;
        __syncthreads();
        bfv8 ah0 = *(bfv8*)&sAh[(wm + l16) * 40 + quad * 8];
        bfv8 ah1 = *(bfv8*)&sAh[(wm + 16 + l16) * 40 + quad * 8];
        bfv8 al0 = *(bfv8*)&sAl[(wm + l16) * 40 + quad * 8];
        bfv8 al1 = *(bfv8*)&sAl[(wm + 16 + l16) * 40 + quad * 8];
        bfv8 bh0 = *(bfv8*)&sBh[(wn + l16) * 40 + quad * 8];
        bfv8 bh1 = *(bfv8*)&sBh[(wn + 16 + l16) * 40 + quad * 8];
        bfv8 bl0 = *(bfv8*)&sBl[(wn + l16) * 40 + quad * 8];
        bfv8 bl1 = *(bfv8*)&sBl[(wn + 16 + l16) * 40 + quad * 8];
        acc[0][0] = __builtin_amdgcn_mfma_f32_16x16x32_bf16(al0, bh0, acc[0][0], 0, 0, 0);
        acc[0][0] = __builtin_amdgcn_mfma_f32_16x16x32_bf16(ah0, bl0, acc[0][0], 0, 0, 0);
        acc[0][0] = __builtin_amdgcn_mfma_f32_16x16x32_bf16(ah0, bh0, acc[0][0], 0, 0, 0);
        acc[0][1] = __builtin_amdgcn_mfma_f32_16x16x32_bf16(al0, bh1, acc[0][1], 0, 0, 0);
        acc[0][1] = __builtin_amdgcn_mfma_f32_16x16x32_bf16(ah0, bl1, acc[0][1], 0, 0, 0);
        acc[0][1] = __builtin_amdgcn_mfma_f32_16x16x32_bf16(ah0, bh1, acc[0][1], 0, 0, 0);
        acc[1][0] = __builtin_amdgcn_mfma_f32_16x16x32_bf16(al1, bh0, acc[1][0], 0, 0, 0);
        acc[1][0] = __builtin_amdgcn_mfma_f32_16x16x32_bf16(ah1, bl0, acc[1][0], 0, 0, 0);
        acc[1][0] = __builtin_amdgcn_mfma_f32_16x16x32_bf16(ah1, bh0, acc[1][0], 0, 0, 0);
        acc[1][1] = __builtin_amdgcn_mfma_f32_16x16x32_bf16(al1, bh1, acc[1][1], 0, 0, 0);
        acc[1][1] = __builtin_amdgcn_mfma_f32_16x16x32_bf16(ah1, bl1, acc[1][1], 0, 0, 0);
        acc[1][1] = __builtin_amdgcn_mfma_f32_16x16x32_bf16(ah1, bh1, acc[1][1], 0, 0, 0);
    }
    // C/D layout: row=(lane>>4)*4+r, col=lane&15 per 16x16 tile (m89/m91-verified)
    for (int mm = 0; mm < 2; mm++)
        for (int nn = 0; nn < 2; nn++)
            for (int r = 0; r < 4; r++) {
                int rr = bm + wm + mm * 16 + quad * 4 + r;
                int cc = bn + wn + nn * 16 + l16;
                if (rr < M) C[(size_t)rr * HDIM + cc] = acc[mm][nn][r];
            }
}

// ---- e_src/e_dst [N,8]: per-head dot of h row with a_src/a_dst ----
__global__ void escore_kernel(const float* __restrict__ h, const float* __restrict__ a_src,
                              const float* __restrict__ a_dst, float* __restrict__ es,
                              float* __restrict__ ed, int n) {
    int wid = blockIdx.x * 4 + (threadIdx.x >> 6);
    int lane = threadIdx.x & 63;
    if (wid >= n * NHEAD) return;
    int node = wid >> 3, hh = wid & 7;
    float hv = h[(size_t)node * HDIM + hh * 64 + lane];
    float s1 = hv * a_src[hh * 64 + lane];
    float s2 = hv * a_dst[hh * 64 + lane];
    for (int o = 32; o > 0; o >>= 1) {
        s1 += __shfl_down(s1, o);
        s2 += __shfl_down(s2, o);
    }
    if (lane == 0) { es[wid] = s1; ed[wid] = s2; }
}

// ---- counting sort of edges by dst ----
__global__ void hist_kernel(const int* __restrict__ ei, int* __restrict__ deg, int E) {
    int e = blockIdx.x * 256 + threadIdx.x;
    if (e < E) atomicAdd(&deg[ei[E + e]], 1);
}

__global__ void scan_kernel(const int* __restrict__ deg, int* __restrict__ offs,
                            int* __restrict__ cursor, int n) {
    __shared__ int lds[1024];
    int t = threadIdx.x;
    const int CH = 16;
    int base = t * CH;
    int local[CH];
    int s = 0;
    for (int i = 0; i < CH; i++) {
        int idx = base + i;
        local[i] = (idx < n) ? deg[idx] : 0;
        s += local[i];
    }
    lds[t] = s;
    __syncthreads();
    for (int off = 1; off < 1024; off <<= 1) {
        int v = lds[t];
        int add = (t >= off) ? lds[t - off] : 0;
        __syncthreads();
        lds[t] = v + add;
        __syncthreads();
    }
    int ex = (t == 0) ? 0 : lds[t - 1];
    for (int i = 0; i < CH; i++) {
        int idx = base + i;
        if (idx < n) { offs[idx] = ex; cursor[idx] = ex; ex += local[i]; }
    }
}

__global__ void scatter_kernel(const int* __restrict__ ei, int* __restrict__ cursor,
                               int* __restrict__ ssrc, int* __restrict__ sdst, int E) {
    int e = blockIdx.x * 256 + threadIdx.x;
    if (e < E) {
        int d = ei[E + e];
        int p = atomicAdd(&cursor[d], 1);
        ssrc[p] = ei[e];
        sdst[p] = d;
    }
}

// ---- per-edge LeakyReLU scores, sorted order: ew[p][8] ----
__global__ void ew_kernel(const int* __restrict__ ssrc, const int* __restrict__ sdst,
                          const float* __restrict__ es, const float* __restrict__ ed,
                          float* __restrict__ ew, int E) {
    int p = blockIdx.x * 256 + threadIdx.x;
    if (p >= E) return;
    int s = ssrc[p], d = sdst[p];
    float4 a0 = *(const float4*)&es[s * 8];
    float4 a1 = *(const float4*)&es[s * 8 + 4];
    float4 b0 = *(const float4*)&ed[d * 8];
    float4 b1 = *(const float4*)&ed[d * 8 + 4];
    float v[8] = {a0.x + b0.x, a0.y + b0.y, a0.z + b0.z, a0.w + b0.w,
                  a1.x + b1.x, a1.y + b1.y, a1.z + b1.z, a1.w + b1.w};
    for (int j = 0; j < 8; j++) v[j] = v[j] > 0.f ? v[j] : SLOPE * v[j];
    *(float4*)&ew[(size_t)p * 8] = make_float4(v[0], v[1], v[2], v[3]);
    *(float4*)&ew[(size_t)p * 8 + 4] = make_float4(v[4], v[5], v[6], v[7]);
}

// ---- fused per-dst softmax + aggregation + bias + ELU (+ residual), bf16-split output ----
// one wave per dst node; lane covers features [lane*8, lane*8+8), head = lane>>3
__global__ void agg_kernel(const float* __restrict__ h, const float* __restrict__ ew,
                           const int* __restrict__ offs, const int* __restrict__ deg,
                           const int* __restrict__ ssrc, const float* __restrict__ bias,
                           u16* __restrict__ ohi, u16* __restrict__ olo,
                           const u16* __restrict__ rhi, const u16* __restrict__ rlo,
                           u16* __restrict__ qhi, u16* __restrict__ qlo, int n) {
    int node = blockIdx.x * 4 + (threadIdx.x >> 6);
    int lane = threadIdx.x & 63;
    if (node >= n) return;
    int hh = lane >> 3, f = lane * 8;
    int st = offs[node], cnt = deg[node];

    float mx = -1e30f;
    for (int i = 0; i < cnt; i++) mx = fmaxf(mx, ew[(size_t)(st + i) * 8 + hh]);
    float den = 0.f;
    float acc[8] = {0.f, 0.f, 0.f, 0.f, 0.f, 0.f, 0.f, 0.f};
    for (int i = 0; i < cnt; i++) {
        float w = __expf(ew[(size_t)(st + i) * 8 + hh] - mx);
        den += w;
        int s = ssrc[st + i];
        const float* hp = h + (size_t)s * HDIM + f;
        float4 h0 = *(const float4*)hp;
        float4 h1 = *(const float4*)(hp + 4);
        acc[0] += w * h0.x; acc[1] += w * h0.y; acc[2] += w * h0.z; acc[3] += w * h0.w;
        acc[4] += w * h1.x; acc[5] += w * h1.y; acc[6] += w * h1.z; acc[7] += w * h1.w;
    }
    float inv = den > 0.f ? 1.f / den : 0.f;
    union { int4 v; u16 u[8]; } Hi, Lo;
    float o[8];
    for (int j = 0; j < 8; j++) {
        float v = acc[j] * inv + bias[f + j];
        o[j] = v > 0.f ? v : __expf(v) - 1.f;  // ELU
        splitbf(o[j], Hi.u[j], Lo.u[j]);
    }
    size_t base = (size_t)node * HDIM + f;
    *(int4*)&ohi[base] = Hi.v;
    *(int4*)&olo[base] = Lo.v;
    if (rhi) {
        union { int4 v; u16 u[8]; } Rh, Rl, Qh, Ql;
        Rh.v = *(const int4*)&rhi[base];
        Rl.v = *(const int4*)&rlo[base];
        for (int j = 0; j < 8; j++) {
            float v = o[j] + b2f(Rh.u[j]) + b2f(Rl.u[j]);
            splitbf(v, Qh.u[j], Ql.u[j]);
        }
        *(int4*)&qhi[base] = Qh.v;
        *(int4*)&qlo[base] = Ql.v;
    }
}

// ---- pooling: pooled[g, 2048] = segment_max over batch (sorted); hi+lo reconstruct ----
__global__ void pool_kernel(const u16* __restrict__ s0h, const u16* __restrict__ s0l,
                            const u16* __restrict__ s1h, const u16* __restrict__ s1l,
                            const u16* __restrict__ s2h, const u16* __restrict__ s2l,
                            const u16* __restrict__ s3h, const u16* __restrict__ s3l,
                            const int* __restrict__ batch, float* __restrict__ pooled, int n) {
    int g = blockIdx.x;
    int chunk = blockIdx.y;  // 0..7
    int t = threadIdx.x;
    const u16* hs[4] = {s0h, s1h, s2h, s3h};
    const u16* ls[4] = {s0l, s1l, s2l, s3l};
    const u16* sh = hs[chunk >> 1];
    const u16* sl = ls[chunk >> 1];
    int scol = (chunk & 1) * 256 + t;
    int lo = 0, hi = n;
    while (lo < hi) { int mid = (lo + hi) >> 1; if (batch[mid] < g) lo = mid + 1; else hi = mid; }
    int start = lo;
    lo = start; hi = n;
    while (lo < hi) { int mid = (lo + hi) >> 1; if (batch[mid] < g + 1) lo = mid + 1; else hi = mid; }
    int end = lo;
    float mx = -INFINITY;
    for (int i = start; i < end; i++) {
        size_t idx = (size_t)i * HDIM + scol;
        mx = fmaxf(mx, b2f(sh[idx]) + b2f(sl[idx]));
    }
    if (!isfinite(mx)) mx = 0.f;  // empty segment / isfinite clamp
    pooled[g * (4 * HDIM) + chunk * 256 + t] = mx;
}

// ---- MLP layer 1: z[64,512] = pooled[64,2048] @ mW1 + mb1 ----
__global__ void mlp1_kernel(const float* __restrict__ pooled, const float* __restrict__ mW1,
                            const float* __restrict__ mb1, float* __restrict__ z) {
    int g = blockIdx.x;  // 64
    int t = threadIdx.x; // 256, each does cols t and t+256
    const float* pr = pooled + g * 2048;
    float acc0 = 0.f, acc1 = 0.f;
    for (int k = 0; k < 2048; k++) {
        float pv = pr[k];
        acc0 += pv * mW1[(size_t)k * HDIM + t];
        acc1 += pv * mW1[(size_t)k * HDIM + 256 + t];
    }
    z[g * HDIM + t] = acc0 + mb1[t];
    z[g * HDIM + 256 + t] = acc1 + mb1[256 + t];
}

// ---- BatchNorm (batch stats over 64 graphs) + ReLU ----
__global__ void bn_relu_kernel(const float* __restrict__ z, const float* __restrict__ gammaf,
                               const float* __restrict__ betaf, float* __restrict__ zn) {
    int col = blockIdx.x;  // 512
    int g = threadIdx.x;   // 64 = one wave
    float v = z[g * HDIM + col];
    float s = v;
    for (int o = 32; o > 0; o >>= 1) s += __shfl_xor(s, o);
    float mu = s * (1.f / 64.f);
    float d = v - mu;
    float s2 = d * d;
    for (int o = 32; o > 0; o >>= 1) s2 += __shfl_xor(s2, o);
    float var = s2 * (1.f / 64.f);
    float o = d * rsqrtf(var + BNEPS) * gammaf[col] + betaf[col];
    zn[g * HDIM + col] = fmaxf(o, 0.f);
}

// ---- final: out[64,10] = zn @ mW2 + mb2 (f32 out) ----
__global__ void final_kernel(const float* __restrict__ zn, const float* __restrict__ mW2,
                             const float* __restrict__ mb2, float* __restrict__ out) {
    int t = threadIdx.x;
    if (t >= GNUM * CNUM) return;
    int g = t / CNUM, c = t - g * CNUM;
    float acc = mb2[c];
    for (int k = 0; k < HDIM; k++) acc += zn[g * HDIM + k] * mW2[k * CNUM + c];
    out[t] = acc;
}

extern "C" void kernel_launch(void* const* d_in, const int* in_sizes, int n_in,
                              void* d_out, int out_size, void* d_ws, size_t ws_size,
                              hipStream_t stream) {
    const float* x = (const float*)d_in[0];
    const int* ei = (const int*)d_in[1];
    const int* batch = (const int*)d_in[2];
    const float* Wm[4] = {(const float*)d_in[3], (const float*)d_in[7],
                          (const float*)d_in[11], (const float*)d_in[15]};
    const float* Asc[4] = {(const float*)d_in[4], (const float*)d_in[8],
                           (const float*)d_in[12], (const float*)d_in[16]};
    const float* Adc[4] = {(const float*)d_in[5], (const float*)d_in[9],
                           (const float*)d_in[13], (const float*)d_in[17]};
    const float* Bb[4] = {(const float*)d_in[6], (const float*)d_in[10],
                          (const float*)d_in[14], (const float*)d_in[18]};
    const float* mW1 = (const float*)d_in[19];
    const float* mb1 = (const float*)d_in[20];
    const float* gammaf = (const float*)d_in[21];
    const float* betaf = (const float*)d_in[22];
    const float* mW2 = (const float*)d_in[23];
    const float* mb2 = (const float*)d_in[24];
    (void)n_in;

    int N = in_sizes[2];
    int E = in_sizes[1] / 2;
    int F0 = in_sizes[0] / N;

    // ---- workspace carve (256B-aligned), ~114 MB ----
    char* p = (char*)d_ws;
    auto alloc = [&](size_t bytes) -> char* {
        char* r = p;
        p += (bytes + 255) & ~(size_t)255;
        return r;
    };
    u16 *Wh[4], *Wl[4];
    Wh[0] = (u16*)alloc((size_t)HDIM * F0 * 2);
    Wl[0] = (u16*)alloc((size_t)HDIM * F0 * 2);
    for (int l = 1; l < 4; l++) {
        Wh[l] = (u16*)alloc((size_t)HDIM * HDIM * 2);
        Wl[l] = (u16*)alloc((size_t)HDIM * HDIM * 2);
    }
    size_t xin_bytes = (size_t)N * F0 * 2 * 2;          // hi+lo
    size_t ew_bytes = (size_t)E * 8 * 4;
    char* xin_base = alloc(xin_bytes > ew_bytes ? xin_bytes : ew_bytes);
    u16* xinh = (u16*)xin_base;
    u16* xinl = (u16*)(xin_base + (size_t)N * F0 * 2);
    float* ew = (float*)xin_base;                       // aliases xin (dead after layer-0 GEMM)
    float* hbuf = (float*)alloc((size_t)N * HDIM * 4);
    u16 *xh[4], *xl[4];                                 // x0,x1,x2,x3 as hi/lo bf16 pairs
    for (int l = 0; l < 4; l++) {
        xh[l] = (u16*)alloc((size_t)N * HDIM * 2);
        xl[l] = (u16*)alloc((size_t)N * HDIM * 2);
    }
    float* es = (float*)alloc((size_t)N * NHEAD * 4);
    float* ed = (float*)alloc((size_t)N * NHEAD * 4);
    int* deg = (int*)alloc((size_t)N * 4);
    int* offs = (int*)alloc((size_t)N * 4);
    int* cursor = (int*)alloc((size_t)N * 4);
    int* ssrc = (int*)alloc((size_t)E * 4);
    int* sdst = (int*)alloc((size_t)E * 4);
    float* pooled = (float*)alloc((size_t)GNUM * 4 * HDIM * 4);
    float* z = (float*)alloc((size_t)GNUM * HDIM * 4);
    float* zn = (float*)alloc((size_t)GNUM * HDIM * 4);

    if ((size_t)(p - (char*)d_ws) > ws_size) {
        sentinel_kernel<<<(out_size + 255) / 256, 256, 0, stream>>>((float*)d_out, out_size, 999.f);
        return;
    }

    // ---- weight transpose+split, input split ----
    for (int l = 0; l < 4; l++) {
        int K = (l == 0) ? F0 : HDIM;
        int tot = HDIM * K;
        wsplit_kernel<<<(tot + 255) / 256, 256, 0, stream>>>(Wm[l], Wh[l], Wl[l], K, tot);
    }
    xsplit_kernel<<<(N * F0 + 255) / 256, 256, 0, stream>>>(x, xinh, xinl, N * F0);

    // ---- counting sort of edges by dst ----
    zero_i32_kernel<<<(N + 255) / 256, 256, 0, stream>>>(deg, N);
    hist_kernel<<<(E + 255) / 256, 256, 0, stream>>>(ei, deg, E);
    scan_kernel<<<1, 1024, 0, stream>>>(deg, offs, cursor, N);
    scatter_kernel<<<(E + 255) / 256, 256, 0, stream>>>(ei, cursor, ssrc, sdst, E);

    // ---- 4 GAT layers ----
    const u16* linh[4] = {xinh, xh[0], xh[1], xh[3]};
    const u16* linl[4] = {xinl, xl[0], xl[1], xl[3]};
    int lK[4] = {F0, HDIM, HDIM, HDIM};
    // layer outputs: L0->x0, L1->x1, L2->x2 (+x3 residual), L3->xt (aliases x0, dead)
    u16* louth[4] = {xh[0], xh[1], xh[2], xh[0]};
    u16* loutl[4] = {xl[0], xl[1], xl[2], xl[0]};
    dim3 gemm_grid((N + 63) / 64, HDIM / 64);
    int esc_blocks = (N * NHEAD + 3) / 4;
    int agg_blocks = (N + 3) / 4;
    for (int L = 0; L < 4; L++) {
        gemm_split<<<gemm_grid, 256, 0, stream>>>(linh[L], linl[L], Wh[L], Wl[L], hbuf, N, lK[L]);
        escore_kernel<<<esc_blocks, 256, 0, stream>>>(hbuf, Asc[L], Adc[L], es, ed, N);
        ew_kernel<<<(E + 255) / 256, 256, 0, stream>>>(ssrc, sdst, es, ed, ew, E);
        const u16* rh = (L == 2) ? xh[0] : nullptr;
        const u16* rl = (L == 2) ? xl[0] : nullptr;
        u16* qh = (L == 2) ? xh[3] : nullptr;
        u16* ql = (L == 2) ? xl[3] : nullptr;
        agg_kernel<<<agg_blocks, 256, 0, stream>>>(hbuf, ew, offs, deg, ssrc, Bb[L],
                                                   louth[L], loutl[L], rh, rl, qh, ql, N);
    }

    // ---- pooling: concat order (xt, x1, x2, x3); xt lives in xh/xl[0] ----
    dim3 pool_grid(GNUM, 8);
    pool_kernel<<<pool_grid, 256, 0, stream>>>(xh[0], xl[0], xh[1], xl[1], xh[2], xl[2],
                                               xh[3], xl[3], batch, pooled, N);

    // ---- MLP head ----
    mlp1_kernel<<<GNUM, 256, 0, stream>>>(pooled, mW1, mb1, z);
    bn_relu_kernel<<<HDIM, 64, 0, stream>>>(z, gammaf, betaf, zn);
    final_kernel<<<1, 640, 0, stream>>>(zn, mW2, mb2, (float*)d_out);
}

// Round 5
// 638.457 us; speedup vs baseline: 1.4706x; 1.1388x over previous
//
#include <hip/hip_runtime.h>

typedef unsigned short u16;
typedef __bf16 bfv8 __attribute__((ext_vector_type(8)));   // MFMA A/B fragment (4 VGPRs)
typedef float f32x4 __attribute__((ext_vector_type(4)));   // MFMA C/D fragment

#define HDIM 512
#define NHEAD 8
#define GNUM 64
#define CNUM 10
#define SLOPE 0.01f
#define BNEPS 1e-5f

__device__ __forceinline__ float b2f(u16 u) { return __uint_as_float(((unsigned)u) << 16); }
__device__ __forceinline__ u16 f2b(float f) {              // RNE f32->bf16
    unsigned u = __float_as_uint(f);
    u += 0x7FFFu + ((u >> 16) & 1u);
    return (u16)(u >> 16);
}
__device__ __forceinline__ void splitbf(float v, u16& hi, u16& lo) {
    u16 h = f2b(v);
    hi = h;
    lo = f2b(v - b2f(h));
}

__global__ void sentinel_kernel(float* out, int n, float val) {
    int i = blockIdx.x * 256 + threadIdx.x;
    if (i < n) out[i] = val;
}

__global__ void zero_i32_kernel(int* __restrict__ p, int n) {
    int i = blockIdx.x * 256 + threadIdx.x;
    if (i < n) p[i] = 0;
}

// ---- weight transpose+split: W[k][512] f32 -> Whi/Wlo[n][K] bf16 ----
__global__ void wsplit_kernel(const float* __restrict__ W, u16* __restrict__ Whi,
                              u16* __restrict__ Wlo, int K, int tot) {
    int idx = blockIdx.x * 256 + threadIdx.x;
    if (idx >= tot) return;
    int n = idx / K, k = idx - n * K;
    float v = W[(size_t)k * HDIM + n];
    splitbf(v, Whi[idx], Wlo[idx]);
}

// ---- activation split: f32 -> hi/lo bf16 ----
__global__ void xsplit_kernel(const float* __restrict__ x, u16* __restrict__ hi,
                              u16* __restrict__ lo, int n) {
    int i = blockIdx.x * 256 + threadIdx.x;
    if (i < n) splitbf(x[i], hi[i], lo[i]);
}

// ---- split-bf16 MFMA GEMM, 128x128 tile, BK=32: C = (Ah+Al) @ (Bh+Bl)^T (3-term) ----
// 4 waves; wave w computes 64x64 quadrant (wm=(w>>1)*64, wn=(w&1)*64) as 4x4 16x16 tiles.
__global__ __launch_bounds__(256) void gemm_split(const u16* __restrict__ Ah,
                                                  const u16* __restrict__ Al,
                                                  const u16* __restrict__ Bh,
                                                  const u16* __restrict__ Bl,
                                                  float* __restrict__ C, int M, int K) {
    __shared__ u16 sAh[128 * 40];   // [m][k], 32-k rows padded to 40 (80B stride)
    __shared__ u16 sAl[128 * 40];
    __shared__ u16 sBh[128 * 40];   // [n][k]
    __shared__ u16 sBl[128 * 40];
    int t = threadIdx.x;
    int bm = blockIdx.x * 128, bn = blockIdx.y * 128;
    int wv = t >> 6, lane = t & 63;
    int wm = (wv >> 1) * 64, wn = (wv & 1) * 64;
    int r0 = t >> 2, r1 = r0 + 64, kc = (t & 3) * 8;
    int quad = lane >> 4, l16 = lane & 15;

    f32x4 acc[4][4];
    for (int a = 0; a < 4; a++)
        for (int b = 0; b < 4; b++)
            for (int r = 0; r < 4; r++) acc[a][b][r] = 0.f;

    bool aok0 = (bm + r0) < M, aok1 = (bm + r1) < M;
    const u16* Ahp0 = Ah + (size_t)(bm + r0) * K + kc;
    const u16* Alp0 = Al + (size_t)(bm + r0) * K + kc;
    const u16* Ahp1 = Ah + (size_t)(bm + r1) * K + kc;
    const u16* Alp1 = Al + (size_t)(bm + r1) * K + kc;
    const u16* Bhp0 = Bh + (size_t)(bn + r0) * K + kc;
    const u16* Blp0 = Bl + (size_t)(bn + r0) * K + kc;
    const u16* Bhp1 = Bh + (size_t)(bn + r1) * K + kc;
    const u16* Blp1 = Bl + (size_t)(bn + r1) * K + kc;

    for (int kt = 0; kt < K; kt += 32) {
        int4 avh0 = make_int4(0, 0, 0, 0), avl0 = avh0, avh1 = avh0, avl1 = avh0;
        if (aok0) { avh0 = *(const int4*)(Ahp0 + kt); avl0 = *(const int4*)(Alp0 + kt); }
        if (aok1) { avh1 = *(const int4*)(Ahp1 + kt); avl1 = *(const int4*)(Alp1 + kt); }
        int4 bvh0 = *(const int4*)(Bhp0 + kt);
        int4 bvl0 = *(const int4*)(Blp0 + kt);
        int4 bvh1 = *(const int4*)(Bhp1 + kt);
        int4 bvl1 = *(const int4*)(Blp1 + kt);
        __syncthreads();
        *(int4*)&sAh[r0 * 40 + kc] = avh0;
        *(int4*)&sAl[r0 * 40 + kc] = avl0;
        *(int4*)&sAh[r1 * 40 + kc] = avh1;
        *(int4*)&sAl[r1 * 40 + kc] = avl1;
        *(int4*)&sBh[r0 * 40 + kc] = bvh0;
        *(int4*)&sBl[r0 * 40 + kc] = bvl0;
        *(int4*)&sBh[r1 * 40 + kc] = bvh1;
        *(int4*)&sBl[r1 * 40 + kc] = bvl1;
        __syncthreads();
        bfv8 fah[4], fal[4], fbh[4], fbl[4];
        #pragma unroll
        for (int mt = 0; mt < 4; mt++) {
            int ro = (wm + mt * 16 + l16) * 40 + quad * 8;
            fah[mt] = *(bfv8*)&sAh[ro];
            fal[mt] = *(bfv8*)&sAl[ro];
        }
        #pragma unroll
        for (int nt = 0; nt < 4; nt++) {
            int ro = (wn + nt * 16 + l16) * 40 + quad * 8;
            fbh[nt] = *(bfv8*)&sBh[ro];
            fbl[nt] = *(bfv8*)&sBl[ro];
        }
        #pragma unroll
        for (int mt = 0; mt < 4; mt++)
            #pragma unroll
            for (int nt = 0; nt < 4; nt++) {
                acc[mt][nt] = __builtin_amdgcn_mfma_f32_16x16x32_bf16(fal[mt], fbh[nt], acc[mt][nt], 0, 0, 0);
                acc[mt][nt] = __builtin_amdgcn_mfma_f32_16x16x32_bf16(fah[mt], fbl[nt], acc[mt][nt], 0, 0, 0);
                acc[mt][nt] = __builtin_amdgcn_mfma_f32_16x16x32_bf16(fah[mt], fbh[nt], acc[mt][nt], 0, 0, 0);
            }
    }
    // C/D layout: row=(lane>>4)*4+r, col=lane&15 per 16x16 tile (m89/m91-verified)
    for (int mt = 0; mt < 4; mt++)
        for (int nt = 0; nt < 4; nt++)
            for (int r = 0; r < 4; r++) {
                int rr = bm + wm + mt * 16 + quad * 4 + r;
                int cc = bn + wn + nt * 16 + l16;
                if (rr < M) C[(size_t)rr * HDIM + cc] = acc[mt][nt][r];
            }
}

// ---- e_src/e_dst [N,8]: per-head dot of h row with a_src/a_dst ----
__global__ void escore_kernel(const float* __restrict__ h, const float* __restrict__ a_src,
                              const float* __restrict__ a_dst, float* __restrict__ es,
                              float* __restrict__ ed, int n) {
    int wid = blockIdx.x * 4 + (threadIdx.x >> 6);
    int lane = threadIdx.x & 63;
    if (wid >= n * NHEAD) return;
    int node = wid >> 3, hh = wid & 7;
    float hv = h[(size_t)node * HDIM + hh * 64 + lane];
    float s1 = hv * a_src[hh * 64 + lane];
    float s2 = hv * a_dst[hh * 64 + lane];
    for (int o = 32; o > 0; o >>= 1) {
        s1 += __shfl_down(s1, o);
        s2 += __shfl_down(s2, o);
    }
    if (lane == 0) { es[wid] = s1; ed[wid] = s2; }
}

// ---- counting sort of edges by dst ----
__global__ void hist_kernel(const int* __restrict__ ei, int* __restrict__ deg, int E) {
    int e = blockIdx.x * 256 + threadIdx.x;
    if (e < E) atomicAdd(&deg[ei[E + e]], 1);
}

__global__ void scan_kernel(const int* __restrict__ deg, int* __restrict__ offs,
                            int* __restrict__ cursor, int n) {
    __shared__ int lds[1024];
    int t = threadIdx.x;
    const int CH = 16;
    int base = t * CH;
    int local[CH];
    int s = 0;
    for (int i = 0; i < CH; i++) {
        int idx = base + i;
        local[i] = (idx < n) ? deg[idx] : 0;
        s += local[i];
    }
    lds[t] = s;
    __syncthreads();
    for (int off = 1; off < 1024; off <<= 1) {
        int v = lds[t];
        int add = (t >= off) ? lds[t - off] : 0;
        __syncthreads();
        lds[t] = v + add;
        __syncthreads();
    }
    int ex = (t == 0) ? 0 : lds[t - 1];
    for (int i = 0; i < CH; i++) {
        int idx = base + i;
        if (idx < n) { offs[idx] = ex; cursor[idx] = ex; ex += local[i]; }
    }
}

__global__ void scatter_kernel(const int* __restrict__ ei, int* __restrict__ cursor,
                               int* __restrict__ ssrc, int* __restrict__ sdst, int E) {
    int e = blockIdx.x * 256 + threadIdx.x;
    if (e < E) {
        int d = ei[E + e];
        int p = atomicAdd(&cursor[d], 1);
        ssrc[p] = ei[e];
        sdst[p] = d;
    }
}

// ---- per-edge LeakyReLU scores, sorted order: ew[p][8] ----
__global__ void ew_kernel(const int* __restrict__ ssrc, const int* __restrict__ sdst,
                          const float* __restrict__ es, const float* __restrict__ ed,
                          float* __restrict__ ew, int E) {
    int p = blockIdx.x * 256 + threadIdx.x;
    if (p >= E) return;
    int s = ssrc[p], d = sdst[p];
    float4 a0 = *(const float4*)&es[s * 8];
    float4 a1 = *(const float4*)&es[s * 8 + 4];
    float4 b0 = *(const float4*)&ed[d * 8];
    float4 b1 = *(const float4*)&ed[d * 8 + 4];
    float v[8] = {a0.x + b0.x, a0.y + b0.y, a0.z + b0.z, a0.w + b0.w,
                  a1.x + b1.x, a1.y + b1.y, a1.z + b1.z, a1.w + b1.w};
    for (int j = 0; j < 8; j++) v[j] = v[j] > 0.f ? v[j] : SLOPE * v[j];
    *(float4*)&ew[(size_t)p * 8] = make_float4(v[0], v[1], v[2], v[3]);
    *(float4*)&ew[(size_t)p * 8 + 4] = make_float4(v[4], v[5], v[6], v[7]);
}

// ---- fused per-dst softmax + aggregation + bias + ELU (+ residual), bf16-split output ----
__global__ void agg_kernel(const float* __restrict__ h, const float* __restrict__ ew,
                           const int* __restrict__ offs, const int* __restrict__ deg,
                           const int* __restrict__ ssrc, const float* __restrict__ bias,
                           u16* __restrict__ ohi, u16* __restrict__ olo,
                           const u16* __restrict__ rhi, const u16* __restrict__ rlo,
                           u16* __restrict__ qhi, u16* __restrict__ qlo, int n) {
    int node = blockIdx.x * 4 + (threadIdx.x >> 6);
    int lane = threadIdx.x & 63;
    if (node >= n) return;
    int hh = lane >> 3, f = lane * 8;
    int st = offs[node], cnt = deg[node];

    float mx = -1e30f;
    for (int i = 0; i < cnt; i++) mx = fmaxf(mx, ew[(size_t)(st + i) * 8 + hh]);
    float den = 0.f;
    float acc[8] = {0.f, 0.f, 0.f, 0.f, 0.f, 0.f, 0.f, 0.f};
    for (int i = 0; i < cnt; i++) {
        float w = __expf(ew[(size_t)(st + i) * 8 + hh] - mx);
        den += w;
        int s = ssrc[st + i];
        const float* hp = h + (size_t)s * HDIM + f;
        float4 h0 = *(const float4*)hp;
        float4 h1 = *(const float4*)(hp + 4);
        acc[0] += w * h0.x; acc[1] += w * h0.y; acc[2] += w * h0.z; acc[3] += w * h0.w;
        acc[4] += w * h1.x; acc[5] += w * h1.y; acc[6] += w * h1.z; acc[7] += w * h1.w;
    }
    float inv = den > 0.f ? 1.f / den : 0.f;
    union { int4 v; u16 u[8]; } Hi, Lo;
    float o[8];
    for (int j = 0; j < 8; j++) {
        float v = acc[j] * inv + bias[f + j];
        o[j] = v > 0.f ? v : __expf(v) - 1.f;  // ELU
        splitbf(o[j], Hi.u[j], Lo.u[j]);
    }
    size_t base = (size_t)node * HDIM + f;
    *(int4*)&ohi[base] = Hi.v;
    *(int4*)&olo[base] = Lo.v;
    if (rhi) {
        union { int4 v; u16 u[8]; } Rh, Rl, Qh, Ql;
        Rh.v = *(const int4*)&rhi[base];
        Rl.v = *(const int4*)&rlo[base];
        for (int j = 0; j < 8; j++) {
            float v = o[j] + b2f(Rh.u[j]) + b2f(Rl.u[j]);
            splitbf(v, Qh.u[j], Ql.u[j]);
        }
        *(int4*)&qhi[base] = Qh.v;
        *(int4*)&qlo[base] = Ql.v;
    }
}

// ---- pooling: pooled[g, 2048] = segment_max over batch (sorted); hi+lo reconstruct ----
__global__ void pool_kernel(const u16* __restrict__ s0h, const u16* __restrict__ s0l,
                            const u16* __restrict__ s1h, const u16* __restrict__ s1l,
                            const u16* __restrict__ s2h, const u16* __restrict__ s2l,
                            const u16* __restrict__ s3h, const u16* __restrict__ s3l,
                            const int* __restrict__ batch, float* __restrict__ pooled, int n) {
    int g = blockIdx.x;
    int chunk = blockIdx.y;  // 0..7
    int t = threadIdx.x;
    const u16* hs[4] = {s0h, s1h, s2h, s3h};
    const u16* ls[4] = {s0l, s1l, s2l, s3l};
    const u16* sh = hs[chunk >> 1];
    const u16* sl = ls[chunk >> 1];
    int scol = (chunk & 1) * 256 + t;
    int lo = 0, hi = n;
    while (lo < hi) { int mid = (lo + hi) >> 1; if (batch[mid] < g) lo = mid + 1; else hi = mid; }
    int start = lo;
    lo = start; hi = n;
    while (lo < hi) { int mid = (lo + hi) >> 1; if (batch[mid] < g + 1) lo = mid + 1; else hi = mid; }
    int end = lo;
    float mx = -INFINITY;
    for (int i = start; i < end; i++) {
        size_t idx = (size_t)i * HDIM + scol;
        mx = fmaxf(mx, b2f(sh[idx]) + b2f(sl[idx]));
    }
    if (!isfinite(mx)) mx = 0.f;  // empty segment / isfinite clamp
    pooled[g * (4 * HDIM) + chunk * 256 + t] = mx;
}

// ---- z init: z[g][c] = mb1[c] ----
__global__ void zinit_kernel(float* __restrict__ z, const float* __restrict__ mb1) {
    int i = blockIdx.x * 256 + threadIdx.x;
    if (i < GNUM * HDIM) z[i] = mb1[i & (HDIM - 1)];
}

// ---- MLP layer 1, split-K: z[64,512] += pooled[64,2048-chunk] @ mW1-chunk ----
// grid (64 g, 8 kchunk), block 256; LDS-staged pooled chunk; each thread 2 cols x 256 k.
__global__ __launch_bounds__(256) void mlp1_splitk(const float* __restrict__ pooled,
                                                   const float* __restrict__ mW1,
                                                   float* __restrict__ z) {
    __shared__ float sp[256];
    int g = blockIdx.x, kc = blockIdx.y * 256;
    int t = threadIdx.x;
    sp[t] = pooled[g * 2048 + kc + t];
    __syncthreads();
    float acc0 = 0.f, acc1 = 0.f;
    const float* wp = mW1 + (size_t)kc * HDIM;
    #pragma unroll 8
    for (int k = 0; k < 256; k++) {
        float pv = sp[k];
        acc0 += pv * wp[(size_t)k * HDIM + t];
        acc1 += pv * wp[(size_t)k * HDIM + 256 + t];
    }
    atomicAdd(&z[g * HDIM + t], acc0);
    atomicAdd(&z[g * HDIM + 256 + t], acc1);
}

// ---- BatchNorm (batch stats over 64 graphs) + ReLU ----
__global__ void bn_relu_kernel(const float* __restrict__ z, const float* __restrict__ gammaf,
                               const float* __restrict__ betaf, float* __restrict__ zn) {
    int col = blockIdx.x;  // 512
    int g = threadIdx.x;   // 64 = one wave
    float v = z[g * HDIM + col];
    float s = v;
    for (int o = 32; o > 0; o >>= 1) s += __shfl_xor(s, o);
    float mu = s * (1.f / 64.f);
    float d = v - mu;
    float s2 = d * d;
    for (int o = 32; o > 0; o >>= 1) s2 += __shfl_xor(s2, o);
    float var = s2 * (1.f / 64.f);
    float o = d * rsqrtf(var + BNEPS) * gammaf[col] + betaf[col];
    zn[g * HDIM + col] = fmaxf(o, 0.f);
}

// ---- final: out[64,10] = zn @ mW2 + mb2 (f32 out) ----
__global__ void final_kernel(const float* __restrict__ zn, const float* __restrict__ mW2,
                             const float* __restrict__ mb2, float* __restrict__ out) {
    int t = threadIdx.x;
    if (t >= GNUM * CNUM) return;
    int g = t / CNUM, c = t - g * CNUM;
    float acc = mb2[c];
    for (int k = 0; k < HDIM; k++) acc += zn[g * HDIM + k] * mW2[k * CNUM + c];
    out[t] = acc;
}

extern "C" void kernel_launch(void* const* d_in, const int* in_sizes, int n_in,
                              void* d_out, int out_size, void* d_ws, size_t ws_size,
                              hipStream_t stream) {
    const float* x = (const float*)d_in[0];
    const int* ei = (const int*)d_in[1];
    const int* batch = (const int*)d_in[2];
    const float* Wm[4] = {(const float*)d_in[3], (const float*)d_in[7],
                          (const float*)d_in[11], (const float*)d_in[15]};
    const float* Asc[4] = {(const float*)d_in[4], (const float*)d_in[8],
                           (const float*)d_in[12], (const float*)d_in[16]};
    const float* Adc[4] = {(const float*)d_in[5], (const float*)d_in[9],
                           (const float*)d_in[13], (const float*)d_in[17]};
    const float* Bb[4] = {(const float*)d_in[6], (const float*)d_in[10],
                          (const float*)d_in[14], (const float*)d_in[18]};
    const float* mW1 = (const float*)d_in[19];
    const float* mb1 = (const float*)d_in[20];
    const float* gammaf = (const float*)d_in[21];
    const float* betaf = (const float*)d_in[22];
    const float* mW2 = (const float*)d_in[23];
    const float* mb2 = (const float*)d_in[24];
    (void)n_in;

    int N = in_sizes[2];
    int E = in_sizes[1] / 2;
    int F0 = in_sizes[0] / N;

    // ---- workspace carve (256B-aligned) ----
    char* p = (char*)d_ws;
    auto alloc = [&](size_t bytes) -> char* {
        char* r = p;
        p += (bytes + 255) & ~(size_t)255;
        return r;
    };
    u16 *Wh[4], *Wl[4];
    Wh[0] = (u16*)alloc((size_t)HDIM * F0 * 2);
    Wl[0] = (u16*)alloc((size_t)HDIM * F0 * 2);
    for (int l = 1; l < 4; l++) {
        Wh[l] = (u16*)alloc((size_t)HDIM * HDIM * 2);
        Wl[l] = (u16*)alloc((size_t)HDIM * HDIM * 2);
    }
    size_t xin_bytes = (size_t)N * F0 * 2 * 2;          // hi+lo
    size_t ew_bytes = (size_t)E * 8 * 4;
    char* xin_base = alloc(xin_bytes > ew_bytes ? xin_bytes : ew_bytes);
    u16* xinh = (u16*)xin_base;
    u16* xinl = (u16*)(xin_base + (size_t)N * F0 * 2);
    float* ew = (float*)xin_base;                       // aliases xin (dead after layer-0 GEMM)
    float* hbuf = (float*)alloc((size_t)N * HDIM * 4);
    u16 *xh[4], *xl[4];                                 // x0,x1,x2,x3 as hi/lo bf16 pairs
    for (int l = 0; l < 4; l++) {
        xh[l] = (u16*)alloc((size_t)N * HDIM * 2);
        xl[l] = (u16*)alloc((size_t)N * HDIM * 2);
    }
    float* es = (float*)alloc((size_t)N * NHEAD * 4);
    float* ed = (float*)alloc((size_t)N * NHEAD * 4);
    int* deg = (int*)alloc((size_t)N * 4);
    int* offs = (int*)alloc((size_t)N * 4);
    int* cursor = (int*)alloc((size_t)N * 4);
    int* ssrc = (int*)alloc((size_t)E * 4);
    int* sdst = (int*)alloc((size_t)E * 4);
    float* pooled = (float*)alloc((size_t)GNUM * 4 * HDIM * 4);
    float* z = (float*)alloc((size_t)GNUM * HDIM * 4);
    float* zn = (float*)alloc((size_t)GNUM * HDIM * 4);

    if ((size_t)(p - (char*)d_ws) > ws_size) {
        sentinel_kernel<<<(out_size + 255) / 256, 256, 0, stream>>>((float*)d_out, out_size, 999.f);
        return;
    }

    // ---- weight transpose+split, input split ----
    for (int l = 0; l < 4; l++) {
        int K = (l == 0) ? F0 : HDIM;
        int tot = HDIM * K;
        wsplit_kernel<<<(tot + 255) / 256, 256, 0, stream>>>(Wm[l], Wh[l], Wl[l], K, tot);
    }
    xsplit_kernel<<<(N * F0 + 255) / 256, 256, 0, stream>>>(x, xinh, xinl, N * F0);

    // ---- counting sort of edges by dst ----
    zero_i32_kernel<<<(N + 255) / 256, 256, 0, stream>>>(deg, N);
    hist_kernel<<<(E + 255) / 256, 256, 0, stream>>>(ei, deg, E);
    scan_kernel<<<1, 1024, 0, stream>>>(deg, offs, cursor, N);
    scatter_kernel<<<(E + 255) / 256, 256, 0, stream>>>(ei, cursor, ssrc, sdst, E);

    // ---- 4 GAT layers ----
    const u16* linh[4] = {xinh, xh[0], xh[1], xh[3]};
    const u16* linl[4] = {xinl, xl[0], xl[1], xl[3]};
    int lK[4] = {F0, HDIM, HDIM, HDIM};
    // layer outputs: L0->x0, L1->x1, L2->x2 (+x3 residual), L3->xt (aliases x0, dead)
    u16* louth[4] = {xh[0], xh[1], xh[2], xh[0]};
    u16* loutl[4] = {xl[0], xl[1], xl[2], xl[0]};
    dim3 gemm_grid((N + 127) / 128, HDIM / 128);
    int esc_blocks = (N * NHEAD + 3) / 4;
    int agg_blocks = (N + 3) / 4;
    for (int L = 0; L < 4; L++) {
        gemm_split<<<gemm_grid, 256, 0, stream>>>(linh[L], linl[L], Wh[L], Wl[L], hbuf, N, lK[L]);
        escore_kernel<<<esc_blocks, 256, 0, stream>>>(hbuf, Asc[L], Adc[L], es, ed, N);
        ew_kernel<<<(E + 255) / 256, 256, 0, stream>>>(ssrc, sdst, es, ed, ew, E);
        const u16* rh = (L == 2) ? xh[0] : nullptr;
        const u16* rl = (L == 2) ? xl[0] : nullptr;
        u16* qh = (L == 2) ? xh[3] : nullptr;
        u16* ql = (L == 2) ? xl[3] : nullptr;
        agg_kernel<<<agg_blocks, 256, 0, stream>>>(hbuf, ew, offs, deg, ssrc, Bb[L],
                                                   louth[L], loutl[L], rh, rl, qh, ql, N);
    }

    // ---- pooling: concat order (xt, x1, x2, x3); xt lives in xh/xl[0] ----
    dim3 pool_grid(GNUM, 8);
    pool_kernel<<<pool_grid, 256, 0, stream>>>(xh[0], xl[0], xh[1], xl[1], xh[2], xl[2],
                                               xh[3], xl[3], batch, pooled, N);

    // ---- MLP head: bias-init z, split-K accumulate, BN+ReLU, final ----
    zinit_kernel<<<(GNUM * HDIM + 255) / 256, 256, 0, stream>>>(z, mb1);
    dim3 mlp_grid(GNUM, 8);
    mlp1_splitk<<<mlp_grid, 256, 0, stream>>>(pooled, mW1, z);
    bn_relu_kernel<<<HDIM, 64, 0, stream>>>(z, gammaf, betaf, zn);
    final_kernel<<<1, 640, 0, stream>>>(zn, mW2, mb2, (float*)d_out);
}

// Round 6
// 612.028 us; speedup vs baseline: 1.5341x; 1.0432x over previous
//
#include <hip/hip_runtime.h>

typedef unsigned short u16;
typedef __bf16 bfv8 __attribute__((ext_vector_type(8)));   // MFMA A/B fragment (4 VGPRs)
typedef float f32x4 __attribute__((ext_vector_type(4)));   // MFMA C/D fragment

#define HDIM 512
#define NHEAD 8
#define GNUM 64
#define CNUM 10
#define SLOPE 0.01f
#define BNEPS 1e-5f

__device__ __forceinline__ float b2f(u16 u) { return __uint_as_float(((unsigned)u) << 16); }
__device__ __forceinline__ u16 f2b(float f) {              // RNE f32->bf16
    unsigned u = __float_as_uint(f);
    u += 0x7FFFu + ((u >> 16) & 1u);
    return (u16)(u >> 16);
}
__device__ __forceinline__ void splitbf(float v, u16& hi, u16& lo) {
    u16 h = f2b(v);
    hi = h;
    lo = f2b(v - b2f(h));
}

__global__ void sentinel_kernel(float* out, int n, float val) {
    int i = blockIdx.x * 256 + threadIdx.x;
    if (i < n) out[i] = val;
}

__global__ void zero_i32_kernel(int* __restrict__ p, int n) {
    int i = blockIdx.x * 256 + threadIdx.x;
    if (i < n) p[i] = 0;
}

// ---- weight transpose+split via LDS tiles: W[K][512] f32 -> Whi/Wlo[n][K] bf16 ----
// grid (K/64, 512/64), block 256. Coalesced read AND write.
__global__ void wsplit_kernel(const float* __restrict__ W, u16* __restrict__ Whi,
                              u16* __restrict__ Wlo, int K) {
    __shared__ float tile[64][65];
    int kb = blockIdx.x * 64, nb = blockIdx.y * 64;
    int t = threadIdx.x;
    #pragma unroll
    for (int i = 0; i < 16; i++) {
        int idx = t + i * 256;
        int r = idx >> 6, c = idx & 63;                  // r = k-local, c = n-local
        tile[r][c] = W[(size_t)(kb + r) * HDIM + nb + c];
    }
    __syncthreads();
    #pragma unroll
    for (int i = 0; i < 16; i++) {
        int idx = t + i * 256;
        int r = idx >> 6, c = idx & 63;                  // r = n-local, c = k-local
        float v = tile[c][r];
        u16 hi, lo;
        splitbf(v, hi, lo);
        size_t o = (size_t)(nb + r) * K + kb + c;
        Whi[o] = hi;
        Wlo[o] = lo;
    }
}

// ---- activation split: f32 -> hi/lo bf16 ----
__global__ void xsplit_kernel(const float* __restrict__ x, u16* __restrict__ hi,
                              u16* __restrict__ lo, int n) {
    int i = blockIdx.x * 256 + threadIdx.x;
    if (i < n) splitbf(x[i], hi[i], lo[i]);
}

// ---- split-bf16 MFMA GEMM, 64x64 tile, BK=32: C = (Ah+Al) @ (Bh+Bl)^T (3-term) ----
// Also emits Ch = bf16-hi copy of C (for the aggregation gather).
__global__ __launch_bounds__(256) void gemm_split(const u16* __restrict__ Ah,
                                                  const u16* __restrict__ Al,
                                                  const u16* __restrict__ Bh,
                                                  const u16* __restrict__ Bl,
                                                  float* __restrict__ C,
                                                  u16* __restrict__ Ch, int M, int K) {
    __shared__ u16 sAh[64 * 40];   // [m][k], 32-k rows padded to 40 (80B stride)
    __shared__ u16 sAl[64 * 40];
    __shared__ u16 sBh[64 * 40];   // [n][k]
    __shared__ u16 sBl[64 * 40];
    int t = threadIdx.x;
    int bm = blockIdx.x * 64, bn = blockIdx.y * 64;
    int wv = t >> 6, lane = t & 63;
    int wm = (wv >> 1) * 32, wn = (wv & 1) * 32;
    int row = t >> 2, kc = (t & 3) * 8;
    int quad = lane >> 4, l16 = lane & 15;

    f32x4 acc[2][2];
    for (int a = 0; a < 2; a++)
        for (int b = 0; b < 2; b++)
            for (int r = 0; r < 4; r++) acc[a][b][r] = 0.f;

    bool aok = (bm + row) < M;
    const u16* Ahp = Ah + (size_t)(bm + row) * K + kc;
    const u16* Alp = Al + (size_t)(bm + row) * K + kc;
    const u16* Bhp = Bh + (size_t)(bn + row) * K + kc;
    const u16* Blp = Bl + (size_t)(bn + row) * K + kc;

    for (int kt = 0; kt < K; kt += 32) {
        int4 avh = make_int4(0, 0, 0, 0), avl = avh;
        if (aok) { avh = *(const int4*)(Ahp + kt); avl = *(const int4*)(Alp + kt); }
        int4 bvh = *(const int4*)(Bhp + kt);
        int4 bvl = *(const int4*)(Blp + kt);
        __syncthreads();
        *(int4*)&sAh[row * 40 + kc] = avh;
        *(int4*)&sAl[row * 40 + kc] = avl;
        *(int4*)&sBh[row * 40 + kc] = bvh;
        *(int4*)&sBl[row * 40 + kc] = bvl;
        __syncthreads();
        bfv8 ah0 = *(bfv8*)&sAh[(wm + l16) * 40 + quad * 8];
        bfv8 ah1 = *(bfv8*)&sAh[(wm + 16 + l16) * 40 + quad * 8];
        bfv8 al0 = *(bfv8*)&sAl[(wm + l16) * 40 + quad * 8];
        bfv8 al1 = *(bfv8*)&sAl[(wm + 16 + l16) * 40 + quad * 8];
        bfv8 bh0 = *(bfv8*)&sBh[(wn + l16) * 40 + quad * 8];
        bfv8 bh1 = *(bfv8*)&sBh[(wn + 16 + l16) * 40 + quad * 8];
        bfv8 bl0 = *(bfv8*)&sBl[(wn + l16) * 40 + quad * 8];
        bfv8 bl1 = *(bfv8*)&sBl[(wn + 16 + l16) * 40 + quad * 8];
        acc[0][0] = __builtin_amdgcn_mfma_f32_16x16x32_bf16(al0, bh0, acc[0][0], 0, 0, 0);
        acc[0][0] = __builtin_amdgcn_mfma_f32_16x16x32_bf16(ah0, bl0, acc[0][0], 0, 0, 0);
        acc[0][0] = __builtin_amdgcn_mfma_f32_16x16x32_bf16(ah0, bh0, acc[0][0], 0, 0, 0);
        acc[0][1] = __builtin_amdgcn_mfma_f32_16x16x32_bf16(al0, bh1, acc[0][1], 0, 0, 0);
        acc[0][1] = __builtin_amdgcn_mfma_f32_16x16x32_bf16(ah0, bl1, acc[0][1], 0, 0, 0);
        acc[0][1] = __builtin_amdgcn_mfma_f32_16x16x32_bf16(ah0, bh1, acc[0][1], 0, 0, 0);
        acc[1][0] = __builtin_amdgcn_mfma_f32_16x16x32_bf16(al1, bh0, acc[1][0], 0, 0, 0);
        acc[1][0] = __builtin_amdgcn_mfma_f32_16x16x32_bf16(ah1, bl0, acc[1][0], 0, 0, 0);
        acc[1][0] = __builtin_amdgcn_mfma_f32_16x16x32_bf16(ah1, bh0, acc[1][0], 0, 0, 0);
        acc[1][1] = __builtin_amdgcn_mfma_f32_16x16x32_bf16(al1, bh1, acc[1][1], 0, 0, 0);
        acc[1][1] = __builtin_amdgcn_mfma_f32_16x16x32_bf16(ah1, bl1, acc[1][1], 0, 0, 0);
        acc[1][1] = __builtin_amdgcn_mfma_f32_16x16x32_bf16(ah1, bh1, acc[1][1], 0, 0, 0);
    }
    // C/D layout: row=(lane>>4)*4+r, col=lane&15 per 16x16 tile (m89/m91-verified)
    for (int mm = 0; mm < 2; mm++)
        for (int nn = 0; nn < 2; nn++)
            for (int r = 0; r < 4; r++) {
                int rr = bm + wm + mm * 16 + quad * 4 + r;
                int cc = bn + wn + nn * 16 + l16;
                if (rr < M) {
                    float v = acc[mm][nn][r];
                    size_t o = (size_t)rr * HDIM + cc;
                    C[o] = v;
                    Ch[o] = f2b(v);
                }
            }
}

// ---- e_src/e_dst [N,8]: per-head dot of h row with a_src/a_dst (f32 h, exact) ----
__global__ void escore_kernel(const float* __restrict__ h, const float* __restrict__ a_src,
                              const float* __restrict__ a_dst, float* __restrict__ es,
                              float* __restrict__ ed, int n) {
    int wid = blockIdx.x * 4 + (threadIdx.x >> 6);
    int lane = threadIdx.x & 63;
    if (wid >= n * NHEAD) return;
    int node = wid >> 3, hh = wid & 7;
    float hv = h[(size_t)node * HDIM + hh * 64 + lane];
    float s1 = hv * a_src[hh * 64 + lane];
    float s2 = hv * a_dst[hh * 64 + lane];
    for (int o = 32; o > 0; o >>= 1) {
        s1 += __shfl_down(s1, o);
        s2 += __shfl_down(s2, o);
    }
    if (lane == 0) { es[wid] = s1; ed[wid] = s2; }
}

// ---- counting sort of edges by dst ----
__global__ void hist_kernel(const int* __restrict__ ei, int* __restrict__ deg, int E) {
    int e = blockIdx.x * 256 + threadIdx.x;
    if (e < E) atomicAdd(&deg[ei[E + e]], 1);
}

__global__ void scan_kernel(const int* __restrict__ deg, int* __restrict__ offs,
                            int* __restrict__ cursor, int n) {
    __shared__ int lds[1024];
    int t = threadIdx.x;
    const int CH = 16;
    int base = t * CH;
    int local[CH];
    int s = 0;
    for (int i = 0; i < CH; i++) {
        int idx = base + i;
        local[i] = (idx < n) ? deg[idx] : 0;
        s += local[i];
    }
    lds[t] = s;
    __syncthreads();
    for (int off = 1; off < 1024; off <<= 1) {
        int v = lds[t];
        int add = (t >= off) ? lds[t - off] : 0;
        __syncthreads();
        lds[t] = v + add;
        __syncthreads();
    }
    int ex = (t == 0) ? 0 : lds[t - 1];
    for (int i = 0; i < CH; i++) {
        int idx = base + i;
        if (idx < n) { offs[idx] = ex; cursor[idx] = ex; ex += local[i]; }
    }
}

__global__ void scatter_kernel(const int* __restrict__ ei, int* __restrict__ cursor,
                               int* __restrict__ ssrc, int* __restrict__ sdst, int E) {
    int e = blockIdx.x * 256 + threadIdx.x;
    if (e < E) {
        int d = ei[E + e];
        int p = atomicAdd(&cursor[d], 1);
        ssrc[p] = ei[e];
        sdst[p] = d;
    }
}

// ---- per-edge LeakyReLU scores, sorted order: ew[p][8] ----
__global__ void ew_kernel(const int* __restrict__ ssrc, const int* __restrict__ sdst,
                          const float* __restrict__ es, const float* __restrict__ ed,
                          float* __restrict__ ew, int E) {
    int p = blockIdx.x * 256 + threadIdx.x;
    if (p >= E) return;
    int s = ssrc[p], d = sdst[p];
    float4 a0 = *(const float4*)&es[s * 8];
    float4 a1 = *(const float4*)&es[s * 8 + 4];
    float4 b0 = *(const float4*)&ed[d * 8];
    float4 b1 = *(const float4*)&ed[d * 8 + 4];
    float v[8] = {a0.x + b0.x, a0.y + b0.y, a0.z + b0.z, a0.w + b0.w,
                  a1.x + b1.x, a1.y + b1.y, a1.z + b1.z, a1.w + b1.w};
    for (int j = 0; j < 8; j++) v[j] = v[j] > 0.f ? v[j] : SLOPE * v[j];
    *(float4*)&ew[(size_t)p * 8] = make_float4(v[0], v[1], v[2], v[3]);
    *(float4*)&ew[(size_t)p * 8 + 4] = make_float4(v[4], v[5], v[6], v[7]);
}

// ---- fused per-dst softmax + aggregation + bias + ELU (+ residual) ----
// h gathered as bf16-hi (halves gather traffic; softmax weights stay fp32-exact).
__global__ void agg_kernel(const u16* __restrict__ hh_buf, const float* __restrict__ ew,
                           const int* __restrict__ offs, const int* __restrict__ deg,
                           const int* __restrict__ ssrc, const float* __restrict__ bias,
                           u16* __restrict__ ohi, u16* __restrict__ olo,
                           const u16* __restrict__ rhi, const u16* __restrict__ rlo,
                           u16* __restrict__ qhi, u16* __restrict__ qlo, int n) {
    int node = blockIdx.x * 4 + (threadIdx.x >> 6);
    int lane = threadIdx.x & 63;
    if (node >= n) return;
    int hh = lane >> 3, f = lane * 8;
    int st = offs[node], cnt = deg[node];

    float mx = -1e30f;
    for (int i = 0; i < cnt; i++) mx = fmaxf(mx, ew[(size_t)(st + i) * 8 + hh]);
    float den = 0.f;
    float acc[8] = {0.f, 0.f, 0.f, 0.f, 0.f, 0.f, 0.f, 0.f};
    for (int i = 0; i < cnt; i++) {
        float w = __expf(ew[(size_t)(st + i) * 8 + hh] - mx);
        den += w;
        int s = ssrc[st + i];
        union { int4 v; u16 u[8]; } U;
        U.v = *(const int4*)(hh_buf + (size_t)s * HDIM + f);   // 8 bf16 = 16B/lane
        for (int j = 0; j < 8; j++) acc[j] += w * b2f(U.u[j]);
    }
    float inv = den > 0.f ? 1.f / den : 0.f;
    union { int4 v; u16 u[8]; } Hi, Lo;
    float o[8];
    for (int j = 0; j < 8; j++) {
        float v = acc[j] * inv + bias[f + j];
        o[j] = v > 0.f ? v : __expf(v) - 1.f;  // ELU
        splitbf(o[j], Hi.u[j], Lo.u[j]);
    }
    size_t base = (size_t)node * HDIM + f;
    *(int4*)&ohi[base] = Hi.v;
    *(int4*)&olo[base] = Lo.v;
    if (rhi) {
        union { int4 v; u16 u[8]; } Rh, Rl, Qh, Ql;
        Rh.v = *(const int4*)&rhi[base];
        Rl.v = *(const int4*)&rlo[base];
        for (int j = 0; j < 8; j++) {
            float v = o[j] + b2f(Rh.u[j]) + b2f(Rl.u[j]);
            splitbf(v, Qh.u[j], Ql.u[j]);
        }
        *(int4*)&qhi[base] = Qh.v;
        *(int4*)&qlo[base] = Ql.v;
    }
}

// ---- pooling, coalesced: grid (64 graphs, 4 buffers); threads sweep contiguous rows ----
__global__ void pool_kernel(const u16* __restrict__ s0h, const u16* __restrict__ s0l,
                            const u16* __restrict__ s1h, const u16* __restrict__ s1l,
                            const u16* __restrict__ s2h, const u16* __restrict__ s2l,
                            const u16* __restrict__ s3h, const u16* __restrict__ s3l,
                            const int* __restrict__ batch, float* __restrict__ pooled, int n) {
    int g = blockIdx.x;
    int b = blockIdx.y;  // which buffer (concat order xt,x1,x2,x3)
    int t = threadIdx.x;
    const u16* hs[4] = {s0h, s1h, s2h, s3h};
    const u16* ls[4] = {s0l, s1l, s2l, s3l};
    const u16* sh = hs[b];
    const u16* sl = ls[b];
    int lo = 0, hi = n;
    while (lo < hi) { int mid = (lo + hi) >> 1; if (batch[mid] < g) lo = mid + 1; else hi = mid; }
    int start = lo;
    lo = start; hi = n;
    while (lo < hi) { int mid = (lo + hi) >> 1; if (batch[mid] < g + 1) lo = mid + 1; else hi = mid; }
    int end = lo;
    float mx0 = -INFINITY, mx1 = -INFINITY;
    for (int i = start; i < end; i++) {
        size_t ro = (size_t)i * HDIM;
        mx0 = fmaxf(mx0, b2f(sh[ro + t]) + b2f(sl[ro + t]));
        mx1 = fmaxf(mx1, b2f(sh[ro + 256 + t]) + b2f(sl[ro + 256 + t]));
    }
    if (!isfinite(mx0)) mx0 = 0.f;  // empty segment
    if (!isfinite(mx1)) mx1 = 0.f;
    pooled[g * 2048 + b * 512 + t] = mx0;
    pooled[g * 2048 + b * 512 + 256 + t] = mx1;
}

// ---- z init: z[g][c] = mb1[c] ----
__global__ void zinit_kernel(float* __restrict__ z, const float* __restrict__ mb1) {
    int i = blockIdx.x * 256 + threadIdx.x;
    if (i < GNUM * HDIM) z[i] = mb1[i & (HDIM - 1)];
}

// ---- MLP layer 1, split-K: z[64,512] += pooled[64,2048-chunk] @ mW1-chunk ----
__global__ __launch_bounds__(256) void mlp1_splitk(const float* __restrict__ pooled,
                                                   const float* __restrict__ mW1,
                                                   float* __restrict__ z) {
    __shared__ float sp[256];
    int g = blockIdx.x, kc = blockIdx.y * 256;
    int t = threadIdx.x;
    sp[t] = pooled[g * 2048 + kc + t];
    __syncthreads();
    float acc0 = 0.f, acc1 = 0.f;
    const float* wp = mW1 + (size_t)kc * HDIM;
    #pragma unroll 8
    for (int k = 0; k < 256; k++) {
        float pv = sp[k];
        acc0 += pv * wp[(size_t)k * HDIM + t];
        acc1 += pv * wp[(size_t)k * HDIM + 256 + t];
    }
    atomicAdd(&z[g * HDIM + t], acc0);
    atomicAdd(&z[g * HDIM + 256 + t], acc1);
}

// ---- BatchNorm (batch stats over 64 graphs) + ReLU ----
__global__ void bn_relu_kernel(const float* __restrict__ z, const float* __restrict__ gammaf,
                               const float* __restrict__ betaf, float* __restrict__ zn) {
    int col = blockIdx.x;  // 512
    int g = threadIdx.x;   // 64 = one wave
    float v = z[g * HDIM + col];
    float s = v;
    for (int o = 32; o > 0; o >>= 1) s += __shfl_xor(s, o);
    float mu = s * (1.f / 64.f);
    float d = v - mu;
    float s2 = d * d;
    for (int o = 32; o > 0; o >>= 1) s2 += __shfl_xor(s2, o);
    float var = s2 * (1.f / 64.f);
    float o = d * rsqrtf(var + BNEPS) * gammaf[col] + betaf[col];
    zn[g * HDIM + col] = fmaxf(o, 0.f);
}

// ---- final: out[64,10] = zn @ mW2 + mb2 (f32 out) ----
__global__ void final_kernel(const float* __restrict__ zn, const float* __restrict__ mW2,
                             const float* __restrict__ mb2, float* __restrict__ out) {
    int t = threadIdx.x;
    if (t >= GNUM * CNUM) return;
    int g = t / CNUM, c = t - g * CNUM;
    float acc = mb2[c];
    for (int k = 0; k < HDIM; k++) acc += zn[g * HDIM + k] * mW2[k * CNUM + c];
    out[t] = acc;
}

extern "C" void kernel_launch(void* const* d_in, const int* in_sizes, int n_in,
                              void* d_out, int out_size, void* d_ws, size_t ws_size,
                              hipStream_t stream) {
    const float* x = (const float*)d_in[0];
    const int* ei = (const int*)d_in[1];
    const int* batch = (const int*)d_in[2];
    const float* Wm[4] = {(const float*)d_in[3], (const float*)d_in[7],
                          (const float*)d_in[11], (const float*)d_in[15]};
    const float* Asc[4] = {(const float*)d_in[4], (const float*)d_in[8],
                           (const float*)d_in[12], (const float*)d_in[16]};
    const float* Adc[4] = {(const float*)d_in[5], (const float*)d_in[9],
                           (const float*)d_in[13], (const float*)d_in[17]};
    const float* Bb[4] = {(const float*)d_in[6], (const float*)d_in[10],
                          (const float*)d_in[14], (const float*)d_in[18]};
    const float* mW1 = (const float*)d_in[19];
    const float* mb1 = (const float*)d_in[20];
    const float* gammaf = (const float*)d_in[21];
    const float* betaf = (const float*)d_in[22];
    const float* mW2 = (const float*)d_in[23];
    const float* mb2 = (const float*)d_in[24];
    (void)n_in;

    int N = in_sizes[2];
    int E = in_sizes[1] / 2;
    int F0 = in_sizes[0] / N;

    // ---- workspace carve (256B-aligned) ----
    char* p = (char*)d_ws;
    auto alloc = [&](size_t bytes) -> char* {
        char* r = p;
        p += (bytes + 255) & ~(size_t)255;
        return r;
    };
    u16 *Wh[4], *Wl[4];
    Wh[0] = (u16*)alloc((size_t)HDIM * F0 * 2);
    Wl[0] = (u16*)alloc((size_t)HDIM * F0 * 2);
    for (int l = 1; l < 4; l++) {
        Wh[l] = (u16*)alloc((size_t)HDIM * HDIM * 2);
        Wl[l] = (u16*)alloc((size_t)HDIM * HDIM * 2);
    }
    size_t xin_bytes = (size_t)N * F0 * 2 * 2;          // hi+lo
    size_t ew_bytes = (size_t)E * 8 * 4;
    char* xin_base = alloc(xin_bytes > ew_bytes ? xin_bytes : ew_bytes);
    u16* xinh = (u16*)xin_base;
    u16* xinl = (u16*)(xin_base + (size_t)N * F0 * 2);
    float* ew = (float*)xin_base;                       // aliases xin (dead after layer-0 GEMM)
    float* hbuf = (float*)alloc((size_t)N * HDIM * 4);  // f32 h (escore)
    u16* hbh = (u16*)alloc((size_t)N * HDIM * 2);       // bf16-hi h (agg gather)
    u16 *xh[4], *xl[4];                                 // x0,x1,x2,x3 as hi/lo bf16 pairs
    for (int l = 0; l < 4; l++) {
        xh[l] = (u16*)alloc((size_t)N * HDIM * 2);
        xl[l] = (u16*)alloc((size_t)N * HDIM * 2);
    }
    float* es = (float*)alloc((size_t)N * NHEAD * 4);
    float* ed = (float*)alloc((size_t)N * NHEAD * 4);
    int* deg = (int*)alloc((size_t)N * 4);
    int* offs = (int*)alloc((size_t)N * 4);
    int* cursor = (int*)alloc((size_t)N * 4);
    int* ssrc = (int*)alloc((size_t)E * 4);
    int* sdst = (int*)alloc((size_t)E * 4);
    float* pooled = (float*)alloc((size_t)GNUM * 4 * HDIM * 4);
    float* z = (float*)alloc((size_t)GNUM * HDIM * 4);
    float* zn = (float*)alloc((size_t)GNUM * HDIM * 4);

    if ((size_t)(p - (char*)d_ws) > ws_size) {
        sentinel_kernel<<<(out_size + 255) / 256, 256, 0, stream>>>((float*)d_out, out_size, 999.f);
        return;
    }

    // ---- weight transpose+split (tiled, coalesced), input split ----
    for (int l = 0; l < 4; l++) {
        int K = (l == 0) ? F0 : HDIM;
        dim3 wg(K / 64, HDIM / 64);
        wsplit_kernel<<<wg, 256, 0, stream>>>(Wm[l], Wh[l], Wl[l], K);
    }
    xsplit_kernel<<<(N * F0 + 255) / 256, 256, 0, stream>>>(x, xinh, xinl, N * F0);

    // ---- counting sort of edges by dst ----
    zero_i32_kernel<<<(N + 255) / 256, 256, 0, stream>>>(deg, N);
    hist_kernel<<<(E + 255) / 256, 256, 0, stream>>>(ei, deg, E);
    scan_kernel<<<1, 1024, 0, stream>>>(deg, offs, cursor, N);
    scatter_kernel<<<(E + 255) / 256, 256, 0, stream>>>(ei, cursor, ssrc, sdst, E);

    // ---- 4 GAT layers ----
    const u16* linh[4] = {xinh, xh[0], xh[1], xh[3]};
    const u16* linl[4] = {xinl, xl[0], xl[1], xl[3]};
    int lK[4] = {F0, HDIM, HDIM, HDIM};
    // layer outputs: L0->x0, L1->x1, L2->x2 (+x3 residual), L3->xt (aliases x0, dead)
    u16* louth[4] = {xh[0], xh[1], xh[2], xh[0]};
    u16* loutl[4] = {xl[0], xl[1], xl[2], xl[0]};
    dim3 gemm_grid((N + 63) / 64, HDIM / 64);
    int esc_blocks = (N * NHEAD + 3) / 4;
    int agg_blocks = (N + 3) / 4;
    for (int L = 0; L < 4; L++) {
        gemm_split<<<gemm_grid, 256, 0, stream>>>(linh[L], linl[L], Wh[L], Wl[L], hbuf, hbh,
                                                  N, lK[L]);
        escore_kernel<<<esc_blocks, 256, 0, stream>>>(hbuf, Asc[L], Adc[L], es, ed, N);
        ew_kernel<<<(E + 255) / 256, 256, 0, stream>>>(ssrc, sdst, es, ed, ew, E);
        const u16* rh = (L == 2) ? xh[0] : nullptr;
        const u16* rl = (L == 2) ? xl[0] : nullptr;
        u16* qh = (L == 2) ? xh[3] : nullptr;
        u16* ql = (L == 2) ? xl[3] : nullptr;
        agg_kernel<<<agg_blocks, 256, 0, stream>>>(hbh, ew, offs, deg, ssrc, Bb[L],
                                                   louth[L], loutl[L], rh, rl, qh, ql, N);
    }

    // ---- pooling: concat order (xt, x1, x2, x3); xt lives in xh/xl[0] ----
    dim3 pool_grid(GNUM, 4);
    pool_kernel<<<pool_grid, 256, 0, stream>>>(xh[0], xl[0], xh[1], xl[1], xh[2], xl[2],
                                               xh[3], xl[3], batch, pooled, N);

    // ---- MLP head: bias-init z, split-K accumulate, BN+ReLU, final ----
    zinit_kernel<<<(GNUM * HDIM + 255) / 256, 256, 0, stream>>>(z, mb1);
    dim3 mlp_grid(GNUM, 8);
    mlp1_splitk<<<mlp_grid, 256, 0, stream>>>(pooled, mW1, z);
    bn_relu_kernel<<<HDIM, 64, 0, stream>>>(z, gammaf, betaf, zn);
    final_kernel<<<1, 640, 0, stream>>>(zn, mW2, mb2, (float*)d_out);
}

// Round 7
// 589.769 us; speedup vs baseline: 1.5920x; 1.0377x over previous
//
#include <hip/hip_runtime.h>

typedef unsigned short u16;
typedef __bf16 bfv8 __attribute__((ext_vector_type(8)));     // MFMA A/B fragment (4 VGPRs)
typedef float f32x16 __attribute__((ext_vector_type(16)));   // MFMA 32x32 C/D fragment

#define HDIM 512
#define NHEAD 8
#define GNUM 64
#define CNUM 10
#define SLOPE 0.01f
#define BNEPS 1e-5f
#define PSPLIT 8

__device__ __forceinline__ float b2f(u16 u) { return __uint_as_float(((unsigned)u) << 16); }
__device__ __forceinline__ u16 f2b(float f) {              // RNE f32->bf16
    unsigned u = __float_as_uint(f);
    u += 0x7FFFu + ((u >> 16) & 1u);
    return (u16)(u >> 16);
}
__device__ __forceinline__ void splitbf(float v, u16& hi, u16& lo) {
    u16 h = f2b(v);
    hi = h;
    lo = f2b(v - b2f(h));
}

__global__ void sentinel_kernel(float* out, int n, float val) {
    int i = blockIdx.x * 256 + threadIdx.x;
    if (i < n) out[i] = val;
}

__global__ void zero_i32_kernel(int* __restrict__ p, int n) {
    int i = blockIdx.x * 256 + threadIdx.x;
    if (i < n) p[i] = 0;
}

// ---- weight transpose+split via LDS tiles: W[K][512] f32 -> Whi/Wlo[n][K] bf16 ----
__global__ void wsplit_kernel(const float* __restrict__ W, u16* __restrict__ Whi,
                              u16* __restrict__ Wlo, int K) {
    __shared__ float tile[64][65];
    int kb = blockIdx.x * 64, nb = blockIdx.y * 64;
    int t = threadIdx.x;
    #pragma unroll
    for (int i = 0; i < 16; i++) {
        int idx = t + i * 256;
        int r = idx >> 6, c = idx & 63;
        tile[r][c] = W[(size_t)(kb + r) * HDIM + nb + c];
    }
    __syncthreads();
    #pragma unroll
    for (int i = 0; i < 16; i++) {
        int idx = t + i * 256;
        int r = idx >> 6, c = idx & 63;
        float v = tile[c][r];
        u16 hi, lo;
        splitbf(v, hi, lo);
        size_t o = (size_t)(nb + r) * K + kb + c;
        Whi[o] = hi;
        Wlo[o] = lo;
    }
}

// ---- activation split: f32 -> hi/lo bf16 ----
__global__ void xsplit_kernel(const float* __restrict__ x, u16* __restrict__ hi,
                              u16* __restrict__ lo, int n) {
    int i = blockIdx.x * 256 + threadIdx.x;
    if (i < n) splitbf(x[i], hi[i], lo[i]);
}

// ---- split-bf16 MFMA GEMM, 32x32x16 shape, block tile 128x64, BK=32, 3-term ----
// 4 waves: wave w covers rows wm=(w>>1)*64 (2 m-tiles of 32) x cols wn=(w&1)*32.
// Output written as hi/lo bf16 pair (exact f32 recoverable as hi+lo).
__global__ __launch_bounds__(256, 2) void gemm_split(const u16* __restrict__ Ah,
                                                     const u16* __restrict__ Al,
                                                     const u16* __restrict__ Bh,
                                                     const u16* __restrict__ Bl,
                                                     u16* __restrict__ Chi,
                                                     u16* __restrict__ Clo, int M, int K) {
    __shared__ u16 sAh[128 * 40];   // [m][k], pad 40 (80B row stride)
    __shared__ u16 sAl[128 * 40];
    __shared__ u16 sBh[64 * 40];    // [n][k]
    __shared__ u16 sBl[64 * 40];
    int t = threadIdx.x;
    int bm = blockIdx.x * 128, bn = blockIdx.y * 64;
    int wv = t >> 6, lane = t & 63;
    int wm = (wv >> 1) * 64, wn = (wv & 1) * 32;
    int l32 = lane & 31, kh = lane >> 5;           // kh in {0,1}

    // staging assignments: A 128 rows x 32k, 2 slots/thread; B 64 rows x 32k, 1 slot/thread
    int ar0 = (2 * t) >> 2, ac0 = ((2 * t) & 3) * 8;
    int ar1 = (2 * t + 1) >> 2, ac1 = ((2 * t + 1) & 3) * 8;
    int br = t >> 2, bc = (t & 3) * 8;

    f32x16 acc[2];
    for (int m = 0; m < 2; m++)
        for (int r = 0; r < 16; r++) acc[m][r] = 0.f;

    bool ok0 = (bm + ar0) < M, ok1 = (bm + ar1) < M;
    const u16* Ahp0 = Ah + (size_t)(bm + ar0) * K + ac0;
    const u16* Alp0 = Al + (size_t)(bm + ar0) * K + ac0;
    const u16* Ahp1 = Ah + (size_t)(bm + ar1) * K + ac1;
    const u16* Alp1 = Al + (size_t)(bm + ar1) * K + ac1;
    const u16* Bhp = Bh + (size_t)(bn + br) * K + bc;
    const u16* Blp = Bl + (size_t)(bn + br) * K + bc;

    for (int kt = 0; kt < K; kt += 32) {
        int4 a0h = make_int4(0, 0, 0, 0), a0l = a0h, a1h = a0h, a1l = a0h;
        if (ok0) { a0h = *(const int4*)(Ahp0 + kt); a0l = *(const int4*)(Alp0 + kt); }
        if (ok1) { a1h = *(const int4*)(Ahp1 + kt); a1l = *(const int4*)(Alp1 + kt); }
        int4 bvh = *(const int4*)(Bhp + kt);
        int4 bvl = *(const int4*)(Blp + kt);
        __syncthreads();
        *(int4*)&sAh[ar0 * 40 + ac0] = a0h;
        *(int4*)&sAl[ar0 * 40 + ac0] = a0l;
        *(int4*)&sAh[ar1 * 40 + ac1] = a1h;
        *(int4*)&sAl[ar1 * 40 + ac1] = a1l;
        *(int4*)&sBh[br * 40 + bc] = bvh;
        *(int4*)&sBl[br * 40 + bc] = bvl;
        __syncthreads();
        #pragma unroll
        for (int ks = 0; ks < 32; ks += 16) {
            int ko = ks + kh * 8;
            bfv8 a0 = *(bfv8*)&sAh[(wm + l32) * 40 + ko];
            bfv8 a0lo = *(bfv8*)&sAl[(wm + l32) * 40 + ko];
            bfv8 a1 = *(bfv8*)&sAh[(wm + 32 + l32) * 40 + ko];
            bfv8 a1lo = *(bfv8*)&sAl[(wm + 32 + l32) * 40 + ko];
            bfv8 b = *(bfv8*)&sBh[(wn + l32) * 40 + ko];
            bfv8 blo = *(bfv8*)&sBl[(wn + l32) * 40 + ko];
            acc[0] = __builtin_amdgcn_mfma_f32_32x32x16_bf16(a0lo, b, acc[0], 0, 0, 0);
            acc[0] = __builtin_amdgcn_mfma_f32_32x32x16_bf16(a0, blo, acc[0], 0, 0, 0);
            acc[0] = __builtin_amdgcn_mfma_f32_32x32x16_bf16(a0, b, acc[0], 0, 0, 0);
            acc[1] = __builtin_amdgcn_mfma_f32_32x32x16_bf16(a1lo, b, acc[1], 0, 0, 0);
            acc[1] = __builtin_amdgcn_mfma_f32_32x32x16_bf16(a1, blo, acc[1], 0, 0, 0);
            acc[1] = __builtin_amdgcn_mfma_f32_32x32x16_bf16(a1, b, acc[1], 0, 0, 0);
        }
    }
    // C/D layout (m74/m101-verified): col=lane&31, row=(reg&3)+8*(reg>>2)+4*(lane>>5)
    int col = bn + wn + l32;
    for (int mt = 0; mt < 2; mt++)
        for (int r = 0; r < 16; r++) {
            int row = bm + wm + mt * 32 + (r & 3) + 8 * (r >> 2) + 4 * kh;
            if (row < M) {
                u16 hi, lo;
                splitbf(acc[mt][r], hi, lo);
                size_t o = (size_t)row * HDIM + col;
                Chi[o] = hi;
                Clo[o] = lo;
            }
        }
}

// ---- e_src/e_dst [N,8]: per-head dot of h row (hi+lo exact) with a_src/a_dst ----
__global__ void escore_kernel(const u16* __restrict__ hhi, const u16* __restrict__ hlo,
                              const float* __restrict__ a_src, const float* __restrict__ a_dst,
                              float* __restrict__ es, float* __restrict__ ed, int n) {
    int wid = blockIdx.x * 4 + (threadIdx.x >> 6);
    int lane = threadIdx.x & 63;
    if (wid >= n * NHEAD) return;
    int node = wid >> 3, hh = wid & 7;
    size_t idx = (size_t)node * HDIM + hh * 64 + lane;
    float hv = b2f(hhi[idx]) + b2f(hlo[idx]);
    float s1 = hv * a_src[hh * 64 + lane];
    float s2 = hv * a_dst[hh * 64 + lane];
    for (int o = 32; o > 0; o >>= 1) {
        s1 += __shfl_down(s1, o);
        s2 += __shfl_down(s2, o);
    }
    if (lane == 0) { es[wid] = s1; ed[wid] = s2; }
}

// ---- counting sort of edges by dst ----
__global__ void hist_kernel(const int* __restrict__ ei, int* __restrict__ deg, int E) {
    int e = blockIdx.x * 256 + threadIdx.x;
    if (e < E) atomicAdd(&deg[ei[E + e]], 1);
}

__global__ void scan_kernel(const int* __restrict__ deg, int* __restrict__ offs,
                            int* __restrict__ cursor, int n) {
    __shared__ int lds[1024];
    int t = threadIdx.x;
    const int CH = 16;
    int base = t * CH;
    int local[CH];
    int s = 0;
    for (int i = 0; i < CH; i++) {
        int idx = base + i;
        local[i] = (idx < n) ? deg[idx] : 0;
        s += local[i];
    }
    lds[t] = s;
    __syncthreads();
    for (int off = 1; off < 1024; off <<= 1) {
        int v = lds[t];
        int add = (t >= off) ? lds[t - off] : 0;
        __syncthreads();
        lds[t] = v + add;
        __syncthreads();
    }
    int ex = (t == 0) ? 0 : lds[t - 1];
    for (int i = 0; i < CH; i++) {
        int idx = base + i;
        if (idx < n) { offs[idx] = ex; cursor[idx] = ex; ex += local[i]; }
    }
}

__global__ void scatter_kernel(const int* __restrict__ ei, int* __restrict__ cursor,
                               int* __restrict__ ssrc, int E) {
    int e = blockIdx.x * 256 + threadIdx.x;
    if (e < E) {
        int p = atomicAdd(&cursor[ei[E + e]], 1);
        ssrc[p] = ei[e];
    }
}

// ---- fused per-dst softmax + aggregation + bias + ELU (+ residual) ----
// e-scores recomputed from es/ed (320 KB, L2-resident) -- no materialized edge weights.
__global__ void agg_kernel(const u16* __restrict__ hh_buf, const float* __restrict__ es,
                           const float* __restrict__ ed, const int* __restrict__ offs,
                           const int* __restrict__ deg, const int* __restrict__ ssrc,
                           const float* __restrict__ bias,
                           u16* __restrict__ ohi, u16* __restrict__ olo,
                           const u16* __restrict__ rhi, const u16* __restrict__ rlo,
                           u16* __restrict__ qhi, u16* __restrict__ qlo, int n) {
    int node = blockIdx.x * 4 + (threadIdx.x >> 6);
    int lane = threadIdx.x & 63;
    if (node >= n) return;
    int hh = lane >> 3, f = lane * 8;
    float edv = ed[node * NHEAD + hh];
    int st = offs[node], cnt = deg[node];

    float mx = -1e30f;
    for (int i = 0; i < cnt; i++) {
        int s = ssrc[st + i];
        float e = es[s * NHEAD + hh] + edv;
        e = e > 0.f ? e : SLOPE * e;
        mx = fmaxf(mx, e);
    }
    float den = 0.f;
    float acc[8] = {0.f, 0.f, 0.f, 0.f, 0.f, 0.f, 0.f, 0.f};
    for (int i = 0; i < cnt; i++) {
        int s = ssrc[st + i];
        float e = es[s * NHEAD + hh] + edv;
        e = e > 0.f ? e : SLOPE * e;
        float w = __expf(e - mx);
        den += w;
        union { int4 v; u16 u[8]; } U;
        U.v = *(const int4*)(hh_buf + (size_t)s * HDIM + f);   // 8 bf16 = 16B/lane
        for (int j = 0; j < 8; j++) acc[j] += w * b2f(U.u[j]);
    }
    float inv = den > 0.f ? 1.f / den : 0.f;
    union { int4 v; u16 u[8]; } Hi, Lo;
    float o[8];
    for (int j = 0; j < 8; j++) {
        float v = acc[j] * inv + bias[f + j];
        o[j] = v > 0.f ? v : __expf(v) - 1.f;  // ELU
        splitbf(o[j], Hi.u[j], Lo.u[j]);
    }
    size_t base = (size_t)node * HDIM + f;
    *(int4*)&ohi[base] = Hi.v;
    *(int4*)&olo[base] = Lo.v;
    if (rhi) {
        union { int4 v; u16 u[8]; } Rh, Rl, Qh, Ql;
        Rh.v = *(const int4*)&rhi[base];
        Rl.v = *(const int4*)&rlo[base];
        for (int j = 0; j < 8; j++) {
            float v = o[j] + b2f(Rh.u[j]) + b2f(Rl.u[j]);
            splitbf(v, Qh.u[j], Ql.u[j]);
        }
        *(int4*)&qhi[base] = Qh.v;
        *(int4*)&qlo[base] = Ql.v;
    }
}

// ---- pooling stage 1: partial segment-max, grid (64 g, 4 buf, PSPLIT chunks) ----
__global__ void pool1_kernel(const u16* __restrict__ s0h, const u16* __restrict__ s0l,
                             const u16* __restrict__ s1h, const u16* __restrict__ s1l,
                             const u16* __restrict__ s2h, const u16* __restrict__ s2l,
                             const u16* __restrict__ s3h, const u16* __restrict__ s3l,
                             const int* __restrict__ batch, float* __restrict__ partial, int n) {
    int g = blockIdx.x, b = blockIdx.y, c = blockIdx.z;
    int t = threadIdx.x;
    const u16* hs[4] = {s0h, s1h, s2h, s3h};
    const u16* ls[4] = {s0l, s1l, s2l, s3l};
    const u16* sh = hs[b];
    const u16* sl = ls[b];
    int lo = 0, hi = n;
    while (lo < hi) { int mid = (lo + hi) >> 1; if (batch[mid] < g) lo = mid + 1; else hi = mid; }
    int start = lo;
    lo = start; hi = n;
    while (lo < hi) { int mid = (lo + hi) >> 1; if (batch[mid] < g + 1) lo = mid + 1; else hi = mid; }
    int end = lo;
    int len = end - start;
    int cb = start + (int)(((long long)len * c) / PSPLIT);
    int ce = start + (int)(((long long)len * (c + 1)) / PSPLIT);
    float mx0 = -INFINITY, mx1 = -INFINITY;
    for (int i = cb; i < ce; i++) {
        size_t ro = (size_t)i * HDIM;
        mx0 = fmaxf(mx0, b2f(sh[ro + t]) + b2f(sl[ro + t]));
        mx1 = fmaxf(mx1, b2f(sh[ro + 256 + t]) + b2f(sl[ro + 256 + t]));
    }
    size_t pb = (size_t)((g * 4 + b) * PSPLIT + c) * 512;
    partial[pb + t] = mx0;
    partial[pb + 256 + t] = mx1;
}

// ---- pooling stage 2: reduce PSPLIT partials, clamp empties ----
__global__ void pool2_kernel(const float* __restrict__ partial, float* __restrict__ pooled) {
    int g = blockIdx.x, b = blockIdx.y;
    int t = threadIdx.x;
    float mx0 = -INFINITY, mx1 = -INFINITY;
    for (int c = 0; c < PSPLIT; c++) {
        size_t pb = (size_t)((g * 4 + b) * PSPLIT + c) * 512;
        mx0 = fmaxf(mx0, partial[pb + t]);
        mx1 = fmaxf(mx1, partial[pb + 256 + t]);
    }
    if (!isfinite(mx0)) mx0 = 0.f;
    if (!isfinite(mx1)) mx1 = 0.f;
    pooled[g * 2048 + b * 512 + t] = mx0;
    pooled[g * 2048 + b * 512 + 256 + t] = mx1;
}

// ---- z init: z[g][c] = mb1[c] ----
__global__ void zinit_kernel(float* __restrict__ z, const float* __restrict__ mb1) {
    int i = blockIdx.x * 256 + threadIdx.x;
    if (i < GNUM * HDIM) z[i] = mb1[i & (HDIM - 1)];
}

// ---- MLP layer 1, split-K: z[64,512] += pooled[64,2048-chunk] @ mW1-chunk ----
__global__ __launch_bounds__(256) void mlp1_splitk(const float* __restrict__ pooled,
                                                   const float* __restrict__ mW1,
                                                   float* __restrict__ z) {
    __shared__ float sp[256];
    int g = blockIdx.x, kc = blockIdx.y * 256;
    int t = threadIdx.x;
    sp[t] = pooled[g * 2048 + kc + t];
    __syncthreads();
    float acc0 = 0.f, acc1 = 0.f;
    const float* wp = mW1 + (size_t)kc * HDIM;
    #pragma unroll 8
    for (int k = 0; k < 256; k++) {
        float pv = sp[k];
        acc0 += pv * wp[(size_t)k * HDIM + t];
        acc1 += pv * wp[(size_t)k * HDIM + 256 + t];
    }
    atomicAdd(&z[g * HDIM + t], acc0);
    atomicAdd(&z[g * HDIM + 256 + t], acc1);
}

// ---- BatchNorm (batch stats over 64 graphs) + ReLU ----
__global__ void bn_relu_kernel(const float* __restrict__ z, const float* __restrict__ gammaf,
                               const float* __restrict__ betaf, float* __restrict__ zn) {
    int col = blockIdx.x;
    int g = threadIdx.x;   // 64 = one wave
    float v = z[g * HDIM + col];
    float s = v;
    for (int o = 32; o > 0; o >>= 1) s += __shfl_xor(s, o);
    float mu = s * (1.f / 64.f);
    float d = v - mu;
    float s2 = d * d;
    for (int o = 32; o > 0; o >>= 1) s2 += __shfl_xor(s2, o);
    float var = s2 * (1.f / 64.f);
    float o = d * rsqrtf(var + BNEPS) * gammaf[col] + betaf[col];
    zn[g * HDIM + col] = fmaxf(o, 0.f);
}

// ---- final: out[64,10] = zn @ mW2 + mb2 (f32 out) ----
__global__ void final_kernel(const float* __restrict__ zn, const float* __restrict__ mW2,
                             const float* __restrict__ mb2, float* __restrict__ out) {
    int t = threadIdx.x;
    if (t >= GNUM * CNUM) return;
    int g = t / CNUM, c = t - g * CNUM;
    float acc = mb2[c];
    for (int k = 0; k < HDIM; k++) acc += zn[g * HDIM + k] * mW2[k * CNUM + c];
    out[t] = acc;
}

extern "C" void kernel_launch(void* const* d_in, const int* in_sizes, int n_in,
                              void* d_out, int out_size, void* d_ws, size_t ws_size,
                              hipStream_t stream) {
    const float* x = (const float*)d_in[0];
    const int* ei = (const int*)d_in[1];
    const int* batch = (const int*)d_in[2];
    const float* Wm[4] = {(const float*)d_in[3], (const float*)d_in[7],
                          (const float*)d_in[11], (const float*)d_in[15]};
    const float* Asc[4] = {(const float*)d_in[4], (const float*)d_in[8],
                           (const float*)d_in[12], (const float*)d_in[16]};
    const float* Adc[4] = {(const float*)d_in[5], (const float*)d_in[9],
                           (const float*)d_in[13], (const float*)d_in[17]};
    const float* Bb[4] = {(const float*)d_in[6], (const float*)d_in[10],
                          (const float*)d_in[14], (const float*)d_in[18]};
    const float* mW1 = (const float*)d_in[19];
    const float* mb1 = (const float*)d_in[20];
    const float* gammaf = (const float*)d_in[21];
    const float* betaf = (const float*)d_in[22];
    const float* mW2 = (const float*)d_in[23];
    const float* mb2 = (const float*)d_in[24];
    (void)n_in;

    int N = in_sizes[2];
    int E = in_sizes[1] / 2;
    int F0 = in_sizes[0] / N;

    // ---- workspace carve (256B-aligned) ----
    char* p = (char*)d_ws;
    auto alloc = [&](size_t bytes) -> char* {
        char* r = p;
        p += (bytes + 255) & ~(size_t)255;
        return r;
    };
    u16 *Wh[4], *Wl[4];
    Wh[0] = (u16*)alloc((size_t)HDIM * F0 * 2);
    Wl[0] = (u16*)alloc((size_t)HDIM * F0 * 2);
    for (int l = 1; l < 4; l++) {
        Wh[l] = (u16*)alloc((size_t)HDIM * HDIM * 2);
        Wl[l] = (u16*)alloc((size_t)HDIM * HDIM * 2);
    }
    u16* xinh = (u16*)alloc((size_t)N * F0 * 2);
    u16* xinl = (u16*)alloc((size_t)N * F0 * 2);
    u16* hhi = (u16*)alloc((size_t)N * HDIM * 2);       // h of current layer, hi
    u16* hlo = (u16*)alloc((size_t)N * HDIM * 2);       // h of current layer, lo
    u16 *xh[4], *xl[4];                                 // x0,x1,x2,x3 as hi/lo bf16 pairs
    for (int l = 0; l < 4; l++) {
        xh[l] = (u16*)alloc((size_t)N * HDIM * 2);
        xl[l] = (u16*)alloc((size_t)N * HDIM * 2);
    }
    float* es = (float*)alloc((size_t)N * NHEAD * 4);
    float* ed = (float*)alloc((size_t)N * NHEAD * 4);
    int* deg = (int*)alloc((size_t)N * 4);
    int* offs = (int*)alloc((size_t)N * 4);
    int* cursor = (int*)alloc((size_t)N * 4);
    int* ssrc = (int*)alloc((size_t)E * 4);
    float* partial = (float*)alloc((size_t)GNUM * 4 * PSPLIT * 512 * 4);
    float* pooled = (float*)alloc((size_t)GNUM * 4 * HDIM * 4);
    float* z = (float*)alloc((size_t)GNUM * HDIM * 4);
    float* zn = (float*)alloc((size_t)GNUM * HDIM * 4);

    if ((size_t)(p - (char*)d_ws) > ws_size) {
        sentinel_kernel<<<(out_size + 255) / 256, 256, 0, stream>>>((float*)d_out, out_size, 999.f);
        return;
    }

    // ---- weight transpose+split (tiled, coalesced), input split ----
    for (int l = 0; l < 4; l++) {
        int K = (l == 0) ? F0 : HDIM;
        dim3 wg(K / 64, HDIM / 64);
        wsplit_kernel<<<wg, 256, 0, stream>>>(Wm[l], Wh[l], Wl[l], K);
    }
    xsplit_kernel<<<(N * F0 + 255) / 256, 256, 0, stream>>>(x, xinh, xinl, N * F0);

    // ---- counting sort of edges by dst ----
    zero_i32_kernel<<<(N + 255) / 256, 256, 0, stream>>>(deg, N);
    hist_kernel<<<(E + 255) / 256, 256, 0, stream>>>(ei, deg, E);
    scan_kernel<<<1, 1024, 0, stream>>>(deg, offs, cursor, N);
    scatter_kernel<<<(E + 255) / 256, 256, 0, stream>>>(ei, cursor, ssrc, E);

    // ---- 4 GAT layers ----
    const u16* linh[4] = {xinh, xh[0], xh[1], xh[3]};
    const u16* linl[4] = {xinl, xl[0], xl[1], xl[3]};
    int lK[4] = {F0, HDIM, HDIM, HDIM};
    // layer outputs: L0->x0, L1->x1, L2->x2 (+x3 residual), L3->xt (aliases x0, dead)
    u16* louth[4] = {xh[0], xh[1], xh[2], xh[0]};
    u16* loutl[4] = {xl[0], xl[1], xl[2], xl[0]};
    dim3 gemm_grid((N + 127) / 128, HDIM / 64);
    int esc_blocks = (N * NHEAD + 3) / 4;
    int agg_blocks = (N + 3) / 4;
    for (int L = 0; L < 4; L++) {
        gemm_split<<<gemm_grid, 256, 0, stream>>>(linh[L], linl[L], Wh[L], Wl[L], hhi, hlo,
                                                  N, lK[L]);
        escore_kernel<<<esc_blocks, 256, 0, stream>>>(hhi, hlo, Asc[L], Adc[L], es, ed, N);
        const u16* rh = (L == 2) ? xh[0] : nullptr;
        const u16* rl = (L == 2) ? xl[0] : nullptr;
        u16* qh = (L == 2) ? xh[3] : nullptr;
        u16* ql = (L == 2) ? xl[3] : nullptr;
        agg_kernel<<<agg_blocks, 256, 0, stream>>>(hhi, es, ed, offs, deg, ssrc, Bb[L],
                                                   louth[L], loutl[L], rh, rl, qh, ql, N);
    }

    // ---- pooling (two-stage): concat order (xt, x1, x2, x3); xt lives in xh/xl[0] ----
    dim3 pool1_grid(GNUM, 4, PSPLIT);
    pool1_kernel<<<pool1_grid, 256, 0, stream>>>(xh[0], xl[0], xh[1], xl[1], xh[2], xl[2],
                                                 xh[3], xl[3], batch, partial, N);
    dim3 pool2_grid(GNUM, 4);
    pool2_kernel<<<pool2_grid, 256, 0, stream>>>(partial, pooled);

    // ---- MLP head: bias-init z, split-K accumulate, BN+ReLU, final ----
    zinit_kernel<<<(GNUM * HDIM + 255) / 256, 256, 0, stream>>>(z, mb1);
    dim3 mlp_grid(GNUM, 8);
    mlp1_splitk<<<mlp_grid, 256, 0, stream>>>(pooled, mW1, z);
    bn_relu_kernel<<<HDIM, 64, 0, stream>>>(z, gammaf, betaf, zn);
    final_kernel<<<1, 640, 0, stream>>>(zn, mW2, mb2, (float*)d_out);
}

// Round 8
// 507.459 us; speedup vs baseline: 1.8502x; 1.1622x over previous
//
#include <hip/hip_runtime.h>

typedef unsigned short u16;
typedef __bf16 bfv8 __attribute__((ext_vector_type(8)));     // MFMA A/B fragment (4 VGPRs)
typedef float f32x16 __attribute__((ext_vector_type(16)));   // MFMA 32x32 C/D fragment

#define HDIM 512
#define NHEAD 8
#define GNUM 64
#define CNUM 10
#define SLOPE 0.01f
#define BNEPS 1e-5f
#define PSPLIT 8

__device__ __forceinline__ float b2f(u16 u) { return __uint_as_float(((unsigned)u) << 16); }
__device__ __forceinline__ u16 f2b(float f) {              // RNE f32->bf16
    unsigned u = __float_as_uint(f);
    u += 0x7FFFu + ((u >> 16) & 1u);
    return (u16)(u >> 16);
}
__device__ __forceinline__ void splitbf(float v, u16& hi, u16& lo) {
    u16 h = f2b(v);
    hi = h;
    lo = f2b(v - b2f(h));
}

__global__ void sentinel_kernel(float* out, int n, float val) {
    int i = blockIdx.x * 256 + threadIdx.x;
    if (i < n) out[i] = val;
}

__global__ void zero_i32_kernel(int* __restrict__ p, int n) {
    int i = blockIdx.x * 256 + threadIdx.x;
    if (i < n) p[i] = 0;
}

// ---- weight transpose+split via LDS tiles: W[K][512] f32 -> Whi/Wlo[n][K] bf16 ----
__device__ __forceinline__ void wsplit_body(const float* __restrict__ W, u16* __restrict__ Whi,
                                            u16* __restrict__ Wlo, int K) {
    __shared__ float tile[64][65];
    int kb = blockIdx.x * 64, nb = blockIdx.y * 64;
    int t = threadIdx.x;
    #pragma unroll
    for (int i = 0; i < 16; i++) {
        int idx = t + i * 256;
        int r = idx >> 6, c = idx & 63;
        tile[r][c] = W[(size_t)(kb + r) * HDIM + nb + c];
    }
    __syncthreads();
    #pragma unroll
    for (int i = 0; i < 16; i++) {
        int idx = t + i * 256;
        int r = idx >> 6, c = idx & 63;
        float v = tile[c][r];
        u16 hi, lo;
        splitbf(v, hi, lo);
        size_t o = (size_t)(nb + r) * K + kb + c;
        Whi[o] = hi;
        Wlo[o] = lo;
    }
}

__global__ void wsplit_kernel(const float* __restrict__ W, u16* __restrict__ Whi,
                              u16* __restrict__ Wlo, int K) {
    wsplit_body(W, Whi, Wlo, K);
}

// W1,W2,W3 (all K=512) in one launch, grid.z selects layer
__global__ void wsplit3_kernel(const float* __restrict__ W1, const float* __restrict__ W2,
                               const float* __restrict__ W3,
                               u16* __restrict__ h1, u16* __restrict__ l1,
                               u16* __restrict__ h2, u16* __restrict__ l2,
                               u16* __restrict__ h3, u16* __restrict__ l3) {
    const float* W = (blockIdx.z == 0) ? W1 : (blockIdx.z == 1) ? W2 : W3;
    u16* Wh = (blockIdx.z == 0) ? h1 : (blockIdx.z == 1) ? h2 : h3;
    u16* Wl = (blockIdx.z == 0) ? l1 : (blockIdx.z == 1) ? l2 : l3;
    wsplit_body(W, Wh, Wl, HDIM);
}

// ---- activation split: f32 -> hi/lo bf16 ----
__global__ void xsplit_kernel(const float* __restrict__ x, u16* __restrict__ hi,
                              u16* __restrict__ lo, int n) {
    int i = blockIdx.x * 256 + threadIdx.x;
    if (i < n) splitbf(x[i], hi[i], lo[i]);
}

// ---- split-bf16 MFMA GEMM (32x32x16), block tile 128x64, BK=32, 3-term ----
// Epilogue: writes h as bf16-hi AND computes exact es/ed = h . a_src/a_dst for this
// head (bn block of 64 cols == one head) via cross-lane reduce + LDS combine.
__global__ __launch_bounds__(256, 2) void gemm_split(const u16* __restrict__ Ah,
                                                     const u16* __restrict__ Al,
                                                     const u16* __restrict__ Bh,
                                                     const u16* __restrict__ Bl,
                                                     const float* __restrict__ a_src,
                                                     const float* __restrict__ a_dst,
                                                     u16* __restrict__ Chi,
                                                     float* __restrict__ es,
                                                     float* __restrict__ ed, int M, int K) {
    __shared__ u16 sAh[128 * 40];   // [m][k], pad 40 (80B row stride)
    __shared__ u16 sAl[128 * 40];
    __shared__ u16 sBh[64 * 40];    // [n][k]
    __shared__ u16 sBl[64 * 40];
    __shared__ float sE[128][2][2]; // [row][wn-half][es/ed]
    int t = threadIdx.x;
    int bm = blockIdx.x * 128, bn = blockIdx.y * 64;
    int hh = blockIdx.y;            // head index (64 cols per head)
    int wv = t >> 6, lane = t & 63;
    int wm = (wv >> 1) * 64, wn = (wv & 1) * 32;
    int l32 = lane & 31, kh = lane >> 5;

    int ar0 = (2 * t) >> 2, ac0 = ((2 * t) & 3) * 8;
    int ar1 = (2 * t + 1) >> 2, ac1 = ((2 * t + 1) & 3) * 8;
    int br = t >> 2, bc = (t & 3) * 8;

    f32x16 acc[2];
    for (int m = 0; m < 2; m++)
        for (int r = 0; r < 16; r++) acc[m][r] = 0.f;

    bool ok0 = (bm + ar0) < M, ok1 = (bm + ar1) < M;
    const u16* Ahp0 = Ah + (size_t)(bm + ar0) * K + ac0;
    const u16* Alp0 = Al + (size_t)(bm + ar0) * K + ac0;
    const u16* Ahp1 = Ah + (size_t)(bm + ar1) * K + ac1;
    const u16* Alp1 = Al + (size_t)(bm + ar1) * K + ac1;
    const u16* Bhp = Bh + (size_t)(bn + br) * K + bc;
    const u16* Blp = Bl + (size_t)(bn + br) * K + bc;

    for (int kt = 0; kt < K; kt += 32) {
        int4 a0h = make_int4(0, 0, 0, 0), a0l = a0h, a1h = a0h, a1l = a0h;
        if (ok0) { a0h = *(const int4*)(Ahp0 + kt); a0l = *(const int4*)(Alp0 + kt); }
        if (ok1) { a1h = *(const int4*)(Ahp1 + kt); a1l = *(const int4*)(Alp1 + kt); }
        int4 bvh = *(const int4*)(Bhp + kt);
        int4 bvl = *(const int4*)(Blp + kt);
        __syncthreads();
        *(int4*)&sAh[ar0 * 40 + ac0] = a0h;
        *(int4*)&sAl[ar0 * 40 + ac0] = a0l;
        *(int4*)&sAh[ar1 * 40 + ac1] = a1h;
        *(int4*)&sAl[ar1 * 40 + ac1] = a1l;
        *(int4*)&sBh[br * 40 + bc] = bvh;
        *(int4*)&sBl[br * 40 + bc] = bvl;
        __syncthreads();
        #pragma unroll
        for (int ks = 0; ks < 32; ks += 16) {
            int ko = ks + kh * 8;
            bfv8 a0 = *(bfv8*)&sAh[(wm + l32) * 40 + ko];
            bfv8 a0lo = *(bfv8*)&sAl[(wm + l32) * 40 + ko];
            bfv8 a1 = *(bfv8*)&sAh[(wm + 32 + l32) * 40 + ko];
            bfv8 a1lo = *(bfv8*)&sAl[(wm + 32 + l32) * 40 + ko];
            bfv8 b = *(bfv8*)&sBh[(wn + l32) * 40 + ko];
            bfv8 blo = *(bfv8*)&sBl[(wn + l32) * 40 + ko];
            acc[0] = __builtin_amdgcn_mfma_f32_32x32x16_bf16(a0lo, b, acc[0], 0, 0, 0);
            acc[0] = __builtin_amdgcn_mfma_f32_32x32x16_bf16(a0, blo, acc[0], 0, 0, 0);
            acc[0] = __builtin_amdgcn_mfma_f32_32x32x16_bf16(a0, b, acc[0], 0, 0, 0);
            acc[1] = __builtin_amdgcn_mfma_f32_32x32x16_bf16(a1lo, b, acc[1], 0, 0, 0);
            acc[1] = __builtin_amdgcn_mfma_f32_32x32x16_bf16(a1, blo, acc[1], 0, 0, 0);
            acc[1] = __builtin_amdgcn_mfma_f32_32x32x16_bf16(a1, b, acc[1], 0, 0, 0);
        }
    }
    // a_src/a_dst element for this lane's column (d = wn + l32 within head hh)
    float asv = a_src[hh * 64 + wn + l32];
    float adv = a_dst[hh * 64 + wn + l32];
    // C/D layout (m74/m101-verified): col=lane&31, row=(reg&3)+8*(reg>>2)+4*(lane>>5)
    int col = bn + wn + l32;
    #pragma unroll
    for (int mt = 0; mt < 2; mt++)
        #pragma unroll
        for (int r = 0; r < 16; r++) {
            float v = acc[mt][r];
            int lr = wm + mt * 32 + (r & 3) + 8 * (r >> 2) + 4 * kh;   // block-local row
            int row = bm + lr;
            if (row < M) Chi[(size_t)row * HDIM + col] = f2b(v);
            float s1 = v * asv, s2 = v * adv;
            #pragma unroll
            for (int msk = 1; msk <= 16; msk <<= 1) {
                s1 += __shfl_xor(s1, msk);
                s2 += __shfl_xor(s2, msk);
            }
            if (l32 == 0) { sE[lr][wv & 1][0] = s1; sE[lr][wv & 1][1] = s2; }
        }
    __syncthreads();
    if (t < 128) {
        int row = bm + t;
        if (row < M) {
            es[row * NHEAD + hh] = sE[t][0][0] + sE[t][1][0];
            ed[row * NHEAD + hh] = sE[t][0][1] + sE[t][1][1];
        }
    }
}

// ---- counting sort of edges by dst ----
__global__ void hist_kernel(const int* __restrict__ ei, int* __restrict__ deg, int E) {
    int e = blockIdx.x * 256 + threadIdx.x;
    if (e < E) atomicAdd(&deg[ei[E + e]], 1);
}

__global__ void scan_kernel(const int* __restrict__ deg, int* __restrict__ offs,
                            int* __restrict__ cursor, int n) {
    __shared__ int lds[1024];
    int t = threadIdx.x;
    const int CH = 16;
    int base = t * CH;
    int local[CH];
    int s = 0;
    for (int i = 0; i < CH; i++) {
        int idx = base + i;
        local[i] = (idx < n) ? deg[idx] : 0;
        s += local[i];
    }
    lds[t] = s;
    __syncthreads();
    for (int off = 1; off < 1024; off <<= 1) {
        int v = lds[t];
        int add = (t >= off) ? lds[t - off] : 0;
        __syncthreads();
        lds[t] = v + add;
        __syncthreads();
    }
    int ex = (t == 0) ? 0 : lds[t - 1];
    for (int i = 0; i < CH; i++) {
        int idx = base + i;
        if (idx < n) { offs[idx] = ex; cursor[idx] = ex; ex += local[i]; }
    }
}

__global__ void scatter_kernel(const int* __restrict__ ei, int* __restrict__ cursor,
                               int* __restrict__ ssrc, int E) {
    int e = blockIdx.x * 256 + threadIdx.x;
    if (e < E) {
        int p = atomicAdd(&cursor[ei[E + e]], 1);
        ssrc[p] = ei[e];
    }
}

// ---- fused per-dst ONLINE softmax + aggregation + bias + ELU (+ residual) ----
// Single pass over edges, unrolled x2 so two gather chains are in flight.
__global__ void agg_kernel(const u16* __restrict__ hh_buf, const float* __restrict__ es,
                           const float* __restrict__ ed, const int* __restrict__ offs,
                           const int* __restrict__ deg, const int* __restrict__ ssrc,
                           const float* __restrict__ bias,
                           u16* __restrict__ ohi, u16* __restrict__ olo,
                           const u16* __restrict__ rhi, const u16* __restrict__ rlo,
                           u16* __restrict__ qhi, u16* __restrict__ qlo, int n) {
    int node = blockIdx.x * 4 + (threadIdx.x >> 6);
    int lane = threadIdx.x & 63;
    if (node >= n) return;
    int hh = lane >> 3, f = lane * 8;
    float edv = ed[node * NHEAD + hh];
    int st = offs[node], cnt = deg[node];

    float m = -INFINITY, den = 0.f;
    float acc[8] = {0.f, 0.f, 0.f, 0.f, 0.f, 0.f, 0.f, 0.f};
    int i = 0;
    for (; i + 2 <= cnt; i += 2) {
        int s0 = ssrc[st + i];
        int s1 = ssrc[st + i + 1];
        float e0 = es[s0 * NHEAD + hh] + edv;
        float e1 = es[s1 * NHEAD + hh] + edv;
        union { int4 v; u16 u[8]; } U0, U1;
        U0.v = *(const int4*)(hh_buf + (size_t)s0 * HDIM + f);
        U1.v = *(const int4*)(hh_buf + (size_t)s1 * HDIM + f);
        e0 = e0 > 0.f ? e0 : SLOPE * e0;
        e1 = e1 > 0.f ? e1 : SLOPE * e1;
        float mn = fmaxf(m, fmaxf(e0, e1));
        float sc = __expf(m - mn);       // first iter: exp(-inf)=0
        float w0 = __expf(e0 - mn);
        float w1 = __expf(e1 - mn);
        den = den * sc + w0 + w1;
        #pragma unroll
        for (int j = 0; j < 8; j++)
            acc[j] = acc[j] * sc + w0 * b2f(U0.u[j]) + w1 * b2f(U1.u[j]);
        m = mn;
    }
    if (i < cnt) {
        int s0 = ssrc[st + i];
        float e0 = es[s0 * NHEAD + hh] + edv;
        union { int4 v; u16 u[8]; } U0;
        U0.v = *(const int4*)(hh_buf + (size_t)s0 * HDIM + f);
        e0 = e0 > 0.f ? e0 : SLOPE * e0;
        float mn = fmaxf(m, e0);
        float sc = __expf(m - mn);
        float w0 = __expf(e0 - mn);
        den = den * sc + w0;
        #pragma unroll
        for (int j = 0; j < 8; j++) acc[j] = acc[j] * sc + w0 * b2f(U0.u[j]);
    }
    float inv = den > 0.f ? 1.f / den : 0.f;
    union { int4 v; u16 u[8]; } Hi, Lo;
    float o[8];
    #pragma unroll
    for (int j = 0; j < 8; j++) {
        float v = acc[j] * inv + bias[f + j];
        o[j] = v > 0.f ? v : __expf(v) - 1.f;  // ELU
        splitbf(o[j], Hi.u[j], Lo.u[j]);
    }
    size_t base = (size_t)node * HDIM + f;
    *(int4*)&ohi[base] = Hi.v;
    *(int4*)&olo[base] = Lo.v;
    if (rhi) {
        union { int4 v; u16 u[8]; } Rh, Rl, Qh, Ql;
        Rh.v = *(const int4*)&rhi[base];
        Rl.v = *(const int4*)&rlo[base];
        #pragma unroll
        for (int j = 0; j < 8; j++) {
            float v = o[j] + b2f(Rh.u[j]) + b2f(Rl.u[j]);
            splitbf(v, Qh.u[j], Ql.u[j]);
        }
        *(int4*)&qhi[base] = Qh.v;
        *(int4*)&qlo[base] = Ql.v;
    }
}

// ---- pooling stage 1: partial segment-max, grid (64 g, 4 buf, PSPLIT chunks) ----
__global__ void pool1_kernel(const u16* __restrict__ s0h, const u16* __restrict__ s0l,
                             const u16* __restrict__ s1h, const u16* __restrict__ s1l,
                             const u16* __restrict__ s2h, const u16* __restrict__ s2l,
                             const u16* __restrict__ s3h, const u16* __restrict__ s3l,
                             const int* __restrict__ batch, float* __restrict__ partial, int n) {
    int g = blockIdx.x, b = blockIdx.y, c = blockIdx.z;
    int t = threadIdx.x;
    const u16* hs[4] = {s0h, s1h, s2h, s3h};
    const u16* ls[4] = {s0l, s1l, s2l, s3l};
    const u16* sh = hs[b];
    const u16* sl = ls[b];
    int lo = 0, hi = n;
    while (lo < hi) { int mid = (lo + hi) >> 1; if (batch[mid] < g) lo = mid + 1; else hi = mid; }
    int start = lo;
    lo = start; hi = n;
    while (lo < hi) { int mid = (lo + hi) >> 1; if (batch[mid] < g + 1) lo = mid + 1; else hi = mid; }
    int end = lo;
    int len = end - start;
    int cb = start + (int)(((long long)len * c) / PSPLIT);
    int ce = start + (int)(((long long)len * (c + 1)) / PSPLIT);
    float mx0 = -INFINITY, mx1 = -INFINITY;
    for (int i = cb; i < ce; i++) {
        size_t ro = (size_t)i * HDIM;
        mx0 = fmaxf(mx0, b2f(sh[ro + t]) + b2f(sl[ro + t]));
        mx1 = fmaxf(mx1, b2f(sh[ro + 256 + t]) + b2f(sl[ro + 256 + t]));
    }
    size_t pb = (size_t)((g * 4 + b) * PSPLIT + c) * 512;
    partial[pb + t] = mx0;
    partial[pb + 256 + t] = mx1;
}

// ---- pooling stage 2: reduce PSPLIT partials, clamp empties ----
__global__ void pool2_kernel(const float* __restrict__ partial, float* __restrict__ pooled) {
    int g = blockIdx.x, b = blockIdx.y;
    int t = threadIdx.x;
    float mx0 = -INFINITY, mx1 = -INFINITY;
    for (int c = 0; c < PSPLIT; c++) {
        size_t pb = (size_t)((g * 4 + b) * PSPLIT + c) * 512;
        mx0 = fmaxf(mx0, partial[pb + t]);
        mx1 = fmaxf(mx1, partial[pb + 256 + t]);
    }
    if (!isfinite(mx0)) mx0 = 0.f;
    if (!isfinite(mx1)) mx1 = 0.f;
    pooled[g * 2048 + b * 512 + t] = mx0;
    pooled[g * 2048 + b * 512 + 256 + t] = mx1;
}

// ---- z init: z[g][c] = mb1[c] ----
__global__ void zinit_kernel(float* __restrict__ z, const float* __restrict__ mb1) {
    int i = blockIdx.x * 256 + threadIdx.x;
    if (i < GNUM * HDIM) z[i] = mb1[i & (HDIM - 1)];
}

// ---- MLP layer 1, split-K: z[64,512] += pooled[64,2048-chunk] @ mW1-chunk ----
__global__ __launch_bounds__(256) void mlp1_splitk(const float* __restrict__ pooled,
                                                   const float* __restrict__ mW1,
                                                   float* __restrict__ z) {
    __shared__ float sp[256];
    int g = blockIdx.x, kc = blockIdx.y * 256;
    int t = threadIdx.x;
    sp[t] = pooled[g * 2048 + kc + t];
    __syncthreads();
    float acc0 = 0.f, acc1 = 0.f;
    const float* wp = mW1 + (size_t)kc * HDIM;
    #pragma unroll 8
    for (int k = 0; k < 256; k++) {
        float pv = sp[k];
        acc0 += pv * wp[(size_t)k * HDIM + t];
        acc1 += pv * wp[(size_t)k * HDIM + 256 + t];
    }
    atomicAdd(&z[g * HDIM + t], acc0);
    atomicAdd(&z[g * HDIM + 256 + t], acc1);
}

// ---- BatchNorm (batch stats over 64 graphs) + ReLU ----
__global__ void bn_relu_kernel(const float* __restrict__ z, const float* __restrict__ gammaf,
                               const float* __restrict__ betaf, float* __restrict__ zn) {
    int col = blockIdx.x;
    int g = threadIdx.x;   // 64 = one wave
    float v = z[g * HDIM + col];
    float s = v;
    for (int o = 32; o > 0; o >>= 1) s += __shfl_xor(s, o);
    float mu = s * (1.f / 64.f);
    float d = v - mu;
    float s2 = d * d;
    for (int o = 32; o > 0; o >>= 1) s2 += __shfl_xor(s2, o);
    float var = s2 * (1.f / 64.f);
    float o = d * rsqrtf(var + BNEPS) * gammaf[col] + betaf[col];
    zn[g * HDIM + col] = fmaxf(o, 0.f);
}

// ---- final: out[64,10] = zn @ mW2 + mb2 (f32 out) ----
__global__ void final_kernel(const float* __restrict__ zn, const float* __restrict__ mW2,
                             const float* __restrict__ mb2, float* __restrict__ out) {
    int t = threadIdx.x;
    if (t >= GNUM * CNUM) return;
    int g = t / CNUM, c = t - g * CNUM;
    float acc = mb2[c];
    for (int k = 0; k < HDIM; k++) acc += zn[g * HDIM + k] * mW2[k * CNUM + c];
    out[t] = acc;
}

extern "C" void kernel_launch(void* const* d_in, const int* in_sizes, int n_in,
                              void* d_out, int out_size, void* d_ws, size_t ws_size,
                              hipStream_t stream) {
    const float* x = (const float*)d_in[0];
    const int* ei = (const int*)d_in[1];
    const int* batch = (const int*)d_in[2];
    const float* Wm[4] = {(const float*)d_in[3], (const float*)d_in[7],
                          (const float*)d_in[11], (const float*)d_in[15]};
    const float* Asc[4] = {(const float*)d_in[4], (const float*)d_in[8],
                           (const float*)d_in[12], (const float*)d_in[16]};
    const float* Adc[4] = {(const float*)d_in[5], (const float*)d_in[9],
                           (const float*)d_in[13], (const float*)d_in[17]};
    const float* Bb[4] = {(const float*)d_in[6], (const float*)d_in[10],
                          (const float*)d_in[14], (const float*)d_in[18]};
    const float* mW1 = (const float*)d_in[19];
    const float* mb1 = (const float*)d_in[20];
    const float* gammaf = (const float*)d_in[21];
    const float* betaf = (const float*)d_in[22];
    const float* mW2 = (const float*)d_in[23];
    const float* mb2 = (const float*)d_in[24];
    (void)n_in;

    int N = in_sizes[2];
    int E = in_sizes[1] / 2;
    int F0 = in_sizes[0] / N;

    // ---- workspace carve (256B-aligned) ----
    char* p = (char*)d_ws;
    auto alloc = [&](size_t bytes) -> char* {
        char* r = p;
        p += (bytes + 255) & ~(size_t)255;
        return r;
    };
    u16 *Wh[4], *Wl[4];
    Wh[0] = (u16*)alloc((size_t)HDIM * F0 * 2);
    Wl[0] = (u16*)alloc((size_t)HDIM * F0 * 2);
    for (int l = 1; l < 4; l++) {
        Wh[l] = (u16*)alloc((size_t)HDIM * HDIM * 2);
        Wl[l] = (u16*)alloc((size_t)HDIM * HDIM * 2);
    }
    u16* xinh = (u16*)alloc((size_t)N * F0 * 2);
    u16* xinl = (u16*)alloc((size_t)N * F0 * 2);
    u16* hhi = (u16*)alloc((size_t)N * HDIM * 2);       // h of current layer (bf16-hi only)
    u16 *xh[4], *xl[4];                                 // x0,x1,x2,x3 as hi/lo bf16 pairs
    for (int l = 0; l < 4; l++) {
        xh[l] = (u16*)alloc((size_t)N * HDIM * 2);
        xl[l] = (u16*)alloc((size_t)N * HDIM * 2);
    }
    float* es = (float*)alloc((size_t)N * NHEAD * 4);
    float* ed = (float*)alloc((size_t)N * NHEAD * 4);
    int* deg = (int*)alloc((size_t)N * 4);
    int* offs = (int*)alloc((size_t)N * 4);
    int* cursor = (int*)alloc((size_t)N * 4);
    int* ssrc = (int*)alloc((size_t)E * 4);
    float* partial = (float*)alloc((size_t)GNUM * 4 * PSPLIT * 512 * 4);
    float* pooled = (float*)alloc((size_t)GNUM * 4 * HDIM * 4);
    float* z = (float*)alloc((size_t)GNUM * HDIM * 4);
    float* zn = (float*)alloc((size_t)GNUM * HDIM * 4);

    if ((size_t)(p - (char*)d_ws) > ws_size) {
        sentinel_kernel<<<(out_size + 255) / 256, 256, 0, stream>>>((float*)d_out, out_size, 999.f);
        return;
    }

    // ---- weight transpose+split (W0 alone; W1-3 batched), input split ----
    {
        dim3 wg0(F0 / 64, HDIM / 64);
        wsplit_kernel<<<wg0, 256, 0, stream>>>(Wm[0], Wh[0], Wl[0], F0);
        dim3 wg3(HDIM / 64, HDIM / 64, 3);
        wsplit3_kernel<<<wg3, 256, 0, stream>>>(Wm[1], Wm[2], Wm[3],
                                                Wh[1], Wl[1], Wh[2], Wl[2], Wh[3], Wl[3]);
    }
    xsplit_kernel<<<(N * F0 + 255) / 256, 256, 0, stream>>>(x, xinh, xinl, N * F0);

    // ---- counting sort of edges by dst ----
    zero_i32_kernel<<<(N + 255) / 256, 256, 0, stream>>>(deg, N);
    hist_kernel<<<(E + 255) / 256, 256, 0, stream>>>(ei, deg, E);
    scan_kernel<<<1, 1024, 0, stream>>>(deg, offs, cursor, N);
    scatter_kernel<<<(E + 255) / 256, 256, 0, stream>>>(ei, cursor, ssrc, E);

    // ---- 4 GAT layers ----
    const u16* linh[4] = {xinh, xh[0], xh[1], xh[3]};
    const u16* linl[4] = {xinl, xl[0], xl[1], xl[3]};
    int lK[4] = {F0, HDIM, HDIM, HDIM};
    // layer outputs: L0->x0, L1->x1, L2->x2 (+x3 residual), L3->xt (aliases x0, dead)
    u16* louth[4] = {xh[0], xh[1], xh[2], xh[0]};
    u16* loutl[4] = {xl[0], xl[1], xl[2], xl[0]};
    dim3 gemm_grid((N + 127) / 128, HDIM / 64);
    int agg_blocks = (N + 3) / 4;
    for (int L = 0; L < 4; L++) {
        gemm_split<<<gemm_grid, 256, 0, stream>>>(linh[L], linl[L], Wh[L], Wl[L],
                                                  Asc[L], Adc[L], hhi, es, ed, N, lK[L]);
        const u16* rh = (L == 2) ? xh[0] : nullptr;
        const u16* rl = (L == 2) ? xl[0] : nullptr;
        u16* qh = (L == 2) ? xh[3] : nullptr;
        u16* ql = (L == 2) ? xl[3] : nullptr;
        agg_kernel<<<agg_blocks, 256, 0, stream>>>(hhi, es, ed, offs, deg, ssrc, Bb[L],
                                                   louth[L], loutl[L], rh, rl, qh, ql, N);
    }

    // ---- pooling (two-stage): concat order (xt, x1, x2, x3); xt lives in xh/xl[0] ----
    dim3 pool1_grid(GNUM, 4, PSPLIT);
    pool1_kernel<<<pool1_grid, 256, 0, stream>>>(xh[0], xl[0], xh[1], xl[1], xh[2], xl[2],
                                                 xh[3], xl[3], batch, partial, N);
    dim3 pool2_grid(GNUM, 4);
    pool2_kernel<<<pool2_grid, 256, 0, stream>>>(partial, pooled);

    // ---- MLP head: bias-init z, split-K accumulate, BN+ReLU, final ----
    zinit_kernel<<<(GNUM * HDIM + 255) / 256, 256, 0, stream>>>(z, mb1);
    dim3 mlp_grid(GNUM, 8);
    mlp1_splitk<<<mlp_grid, 256, 0, stream>>>(pooled, mW1, z);
    bn_relu_kernel<<<HDIM, 64, 0, stream>>>(z, gammaf, betaf, zn);
    final_kernel<<<1, 640, 0, stream>>>(zn, mW2, mb2, (float*)d_out);
}

// Round 10
// 475.670 us; speedup vs baseline: 1.9739x; 1.0668x over previous
//
#include <hip/hip_runtime.h>

typedef unsigned short u16;
typedef __bf16 bfv8 __attribute__((ext_vector_type(8)));     // MFMA A/B fragment (4 VGPRs)
typedef float f32x16 __attribute__((ext_vector_type(16)));   // MFMA 32x32 C/D fragment

#define HDIM 512
#define NHEAD 8
#define GNUM 64
#define CNUM 10
#define SLOPE 0.01f
#define BNEPS 1e-5f
#define PSPLIT 8

__device__ __forceinline__ float b2f(u16 u) { return __uint_as_float(((unsigned)u) << 16); }
__device__ __forceinline__ u16 f2b(float f) {              // RNE f32->bf16
    unsigned u = __float_as_uint(f);
    u += 0x7FFFu + ((u >> 16) & 1u);
    return (u16)(u >> 16);
}
__device__ __forceinline__ void splitbf(float v, u16& hi, u16& lo) {
    u16 h = f2b(v);
    hi = h;
    lo = f2b(v - b2f(h));
}

__global__ void sentinel_kernel(float* out, int n, float val) {
    int i = blockIdx.x * 256 + threadIdx.x;
    if (i < n) out[i] = val;
}

__global__ void zero_i32_kernel(int* __restrict__ p, int n) {
    int i = blockIdx.x * 256 + threadIdx.x;
    if (i < n) p[i] = 0;
}

// ---- weight transpose+split via LDS tiles: W[K][512] f32 -> Whi/Wlo[n][K] bf16 ----
__device__ __forceinline__ void wsplit_body(const float* __restrict__ W, u16* __restrict__ Whi,
                                            u16* __restrict__ Wlo, int K) {
    __shared__ float tile[64][65];
    int kb = blockIdx.x * 64, nb = blockIdx.y * 64;
    int t = threadIdx.x;
    #pragma unroll
    for (int i = 0; i < 16; i++) {
        int idx = t + i * 256;
        int r = idx >> 6, c = idx & 63;
        tile[r][c] = W[(size_t)(kb + r) * HDIM + nb + c];
    }
    __syncthreads();
    #pragma unroll
    for (int i = 0; i < 16; i++) {
        int idx = t + i * 256;
        int r = idx >> 6, c = idx & 63;
        float v = tile[c][r];
        u16 hi, lo;
        splitbf(v, hi, lo);
        size_t o = (size_t)(nb + r) * K + kb + c;
        Whi[o] = hi;
        Wlo[o] = lo;
    }
}

__global__ void wsplit_kernel(const float* __restrict__ W, u16* __restrict__ Whi,
                              u16* __restrict__ Wlo, int K) {
    wsplit_body(W, Whi, Wlo, K);
}

// W1,W2,W3 (all K=512) in one launch, grid.z selects layer
__global__ void wsplit3_kernel(const float* __restrict__ W1, const float* __restrict__ W2,
                               const float* __restrict__ W3,
                               u16* __restrict__ h1, u16* __restrict__ l1,
                               u16* __restrict__ h2, u16* __restrict__ l2,
                               u16* __restrict__ h3, u16* __restrict__ l3) {
    const float* W = (blockIdx.z == 0) ? W1 : (blockIdx.z == 1) ? W2 : W3;
    u16* Wh = (blockIdx.z == 0) ? h1 : (blockIdx.z == 1) ? h2 : h3;
    u16* Wl = (blockIdx.z == 0) ? l1 : (blockIdx.z == 1) ? l2 : l3;
    wsplit_body(W, Wh, Wl, HDIM);
}

// ---- activation split: f32 -> hi/lo bf16 ----
__global__ void xsplit_kernel(const float* __restrict__ x, u16* __restrict__ hi,
                              u16* __restrict__ lo, int n) {
    int i = blockIdx.x * 256 + threadIdx.x;
    if (i < n) splitbf(x[i], hi[i], lo[i]);
}

// ---- split-bf16 MFMA GEMM (32x32x16), block tile 128x64, BK=32, 3-term ----
// 1-D grid of nrt*8 blocks with XCD-aware swizzle: XCD = id%8 (round-robin dispatch),
// w = (id&7)*nrt + id>>3 gives each XCD a contiguous run of row-tiles across ALL
// col-tiles -> A rows stay L2-resident, fetched from HBM once (was 8x).
// Epilogue: writes h as bf16-hi AND exact es/ed (col block == one head).
__global__ __launch_bounds__(256, 2) void gemm_split(const u16* __restrict__ Ah,
                                                     const u16* __restrict__ Al,
                                                     const u16* __restrict__ Bh,
                                                     const u16* __restrict__ Bl,
                                                     const float* __restrict__ a_src,
                                                     const float* __restrict__ a_dst,
                                                     u16* __restrict__ Chi,
                                                     float* __restrict__ es,
                                                     float* __restrict__ ed, int M, int K) {
    __shared__ u16 sAh[128 * 40];   // [m][k], pad 40 (80B row stride)
    __shared__ u16 sAl[128 * 40];
    __shared__ u16 sBh[64 * 40];    // [n][k]
    __shared__ u16 sBl[64 * 40];
    __shared__ float sE[128][2][2]; // [row][wn-half][es/ed]
    int t = threadIdx.x;
    int id = blockIdx.x;
    int nrt = gridDim.x >> 3;
    int w = (id & 7) * nrt + (id >> 3);
    int rt = w >> 3, ct = w & 7;
    int bm = rt * 128, bn = ct * 64;
    int hh = ct;                    // head index (64 cols per head)
    int wv = t >> 6, lane = t & 63;
    int wm = (wv >> 1) * 64, wn = (wv & 1) * 32;
    int l32 = lane & 31, kh = lane >> 5;

    int ar0 = (2 * t) >> 2, ac0 = ((2 * t) & 3) * 8;
    int ar1 = (2 * t + 1) >> 2, ac1 = ((2 * t + 1) & 3) * 8;
    int br = t >> 2, bc = (t & 3) * 8;

    f32x16 acc[2];
    for (int m = 0; m < 2; m++)
        for (int r = 0; r < 16; r++) acc[m][r] = 0.f;

    bool ok0 = (bm + ar0) < M, ok1 = (bm + ar1) < M;
    const u16* Ahp0 = Ah + (size_t)(bm + ar0) * K + ac0;
    const u16* Alp0 = Al + (size_t)(bm + ar0) * K + ac0;
    const u16* Ahp1 = Ah + (size_t)(bm + ar1) * K + ac1;
    const u16* Alp1 = Al + (size_t)(bm + ar1) * K + ac1;
    const u16* Bhp = Bh + (size_t)(bn + br) * K + bc;
    const u16* Blp = Bl + (size_t)(bn + br) * K + bc;

    for (int kt = 0; kt < K; kt += 32) {
        int4 a0h = make_int4(0, 0, 0, 0), a0l = a0h, a1h = a0h, a1l = a0h;
        if (ok0) { a0h = *(const int4*)(Ahp0 + kt); a0l = *(const int4*)(Alp0 + kt); }
        if (ok1) { a1h = *(const int4*)(Ahp1 + kt); a1l = *(const int4*)(Alp1 + kt); }
        int4 bvh = *(const int4*)(Bhp + kt);
        int4 bvl = *(const int4*)(Blp + kt);
        __syncthreads();
        *(int4*)&sAh[ar0 * 40 + ac0] = a0h;
        *(int4*)&sAl[ar0 * 40 + ac0] = a0l;
        *(int4*)&sAh[ar1 * 40 + ac1] = a1h;
        *(int4*)&sAl[ar1 * 40 + ac1] = a1l;
        *(int4*)&sBh[br * 40 + bc] = bvh;
        *(int4*)&sBl[br * 40 + bc] = bvl;
        __syncthreads();
        #pragma unroll
        for (int ks = 0; ks < 32; ks += 16) {
            int ko = ks + kh * 8;
            bfv8 a0 = *(bfv8*)&sAh[(wm + l32) * 40 + ko];
            bfv8 a0lo = *(bfv8*)&sAl[(wm + l32) * 40 + ko];
            bfv8 a1 = *(bfv8*)&sAh[(wm + 32 + l32) * 40 + ko];
            bfv8 a1lo = *(bfv8*)&sAl[(wm + 32 + l32) * 40 + ko];
            bfv8 b = *(bfv8*)&sBh[(wn + l32) * 40 + ko];
            bfv8 blo = *(bfv8*)&sBl[(wn + l32) * 40 + ko];
            acc[0] = __builtin_amdgcn_mfma_f32_32x32x16_bf16(a0lo, b, acc[0], 0, 0, 0);
            acc[0] = __builtin_amdgcn_mfma_f32_32x32x16_bf16(a0, blo, acc[0], 0, 0, 0);
            acc[0] = __builtin_amdgcn_mfma_f32_32x32x16_bf16(a0, b, acc[0], 0, 0, 0);
            acc[1] = __builtin_amdgcn_mfma_f32_32x32x16_bf16(a1lo, b, acc[1], 0, 0, 0);
            acc[1] = __builtin_amdgcn_mfma_f32_32x32x16_bf16(a1, blo, acc[1], 0, 0, 0);
            acc[1] = __builtin_amdgcn_mfma_f32_32x32x16_bf16(a1, b, acc[1], 0, 0, 0);
        }
    }
    float asv = a_src[hh * 64 + wn + l32];
    float adv = a_dst[hh * 64 + wn + l32];
    // C/D layout (m74/m101-verified): col=lane&31, row=(reg&3)+8*(reg>>2)+4*(lane>>5)
    int col = bn + wn + l32;
    #pragma unroll
    for (int mt = 0; mt < 2; mt++)
        #pragma unroll
        for (int r = 0; r < 16; r++) {
            float v = acc[mt][r];
            int lr = wm + mt * 32 + (r & 3) + 8 * (r >> 2) + 4 * kh;   // block-local row
            int row = bm + lr;
            if (row < M) Chi[(size_t)row * HDIM + col] = f2b(v);
            float s1 = v * asv, s2 = v * adv;
            #pragma unroll
            for (int msk = 1; msk <= 16; msk <<= 1) {
                s1 += __shfl_xor(s1, msk);
                s2 += __shfl_xor(s2, msk);
            }
            if (l32 == 0) { sE[lr][wv & 1][0] = s1; sE[lr][wv & 1][1] = s2; }
        }
    __syncthreads();
    if (t < 128) {
        int row = bm + t;
        if (row < M) {
            es[row * NHEAD + hh] = sE[t][0][0] + sE[t][1][0];
            ed[row * NHEAD + hh] = sE[t][0][1] + sE[t][1][1];
        }
    }
}

// ---- counting sort of edges by dst ----
__global__ void hist_kernel(const int* __restrict__ ei, int* __restrict__ deg, int E) {
    int e = blockIdx.x * 256 + threadIdx.x;
    if (e < E) atomicAdd(&deg[ei[E + e]], 1);
}

__global__ void scan_kernel(const int* __restrict__ deg, int* __restrict__ offs,
                            int* __restrict__ cursor, int n) {
    __shared__ int lds[1024];
    int t = threadIdx.x;
    const int CH = 16;
    int base = t * CH;
    int local[CH];
    int s = 0;
    for (int i = 0; i < CH; i++) {
        int idx = base + i;
        local[i] = (idx < n) ? deg[idx] : 0;
        s += local[i];
    }
    lds[t] = s;
    __syncthreads();
    for (int off = 1; off < 1024; off <<= 1) {
        int v = lds[t];
        int add = (t >= off) ? lds[t - off] : 0;
        __syncthreads();
        lds[t] = v + add;
        __syncthreads();
    }
    int ex = (t == 0) ? 0 : lds[t - 1];
    for (int i = 0; i < CH; i++) {
        int idx = base + i;
        if (idx < n) { offs[idx] = ex; cursor[idx] = ex; ex += local[i]; }
    }
}

__global__ void scatter_kernel(const int* __restrict__ ei, int* __restrict__ cursor,
                               int* __restrict__ ssrc, int E) {
    int e = blockIdx.x * 256 + threadIdx.x;
    if (e < E) {
        int p = atomicAdd(&cursor[ei[E + e]], 1);
        ssrc[p] = ei[e];
    }
}

// ---- fused per-dst ONLINE softmax + aggregation + bias + ELU (+ residual) ----
__global__ void agg_kernel(const u16* __restrict__ hh_buf, const float* __restrict__ es,
                           const float* __restrict__ ed, const int* __restrict__ offs,
                           const int* __restrict__ deg, const int* __restrict__ ssrc,
                           const float* __restrict__ bias,
                           u16* __restrict__ ohi, u16* __restrict__ olo,
                           const u16* __restrict__ rhi, const u16* __restrict__ rlo,
                           u16* __restrict__ qhi, u16* __restrict__ qlo, int n) {
    int node = blockIdx.x * 4 + (threadIdx.x >> 6);
    int lane = threadIdx.x & 63;
    if (node >= n) return;
    int hh = lane >> 3, f = lane * 8;
    float edv = ed[node * NHEAD + hh];
    int st = offs[node], cnt = deg[node];

    float m = -INFINITY, den = 0.f;
    float acc[8] = {0.f, 0.f, 0.f, 0.f, 0.f, 0.f, 0.f, 0.f};
    int i = 0;
    for (; i + 2 <= cnt; i += 2) {
        int s0 = ssrc[st + i];
        int s1 = ssrc[st + i + 1];
        float e0 = es[s0 * NHEAD + hh] + edv;
        float e1 = es[s1 * NHEAD + hh] + edv;
        union { int4 v; u16 u[8]; } U0, U1;
        U0.v = *(const int4*)(hh_buf + (size_t)s0 * HDIM + f);
        U1.v = *(const int4*)(hh_buf + (size_t)s1 * HDIM + f);
        e0 = e0 > 0.f ? e0 : SLOPE * e0;
        e1 = e1 > 0.f ? e1 : SLOPE * e1;
        float mn = fmaxf(m, fmaxf(e0, e1));
        float sc = __expf(m - mn);       // first iter: exp(-inf)=0
        float w0 = __expf(e0 - mn);
        float w1 = __expf(e1 - mn);
        den = den * sc + w0 + w1;
        #pragma unroll
        for (int j = 0; j < 8; j++)
            acc[j] = acc[j] * sc + w0 * b2f(U0.u[j]) + w1 * b2f(U1.u[j]);
        m = mn;
    }
    if (i < cnt) {
        int s0 = ssrc[st + i];
        float e0 = es[s0 * NHEAD + hh] + edv;
        union { int4 v; u16 u[8]; } U0;
        U0.v = *(const int4*)(hh_buf + (size_t)s0 * HDIM + f);
        e0 = e0 > 0.f ? e0 : SLOPE * e0;
        float mn = fmaxf(m, e0);
        float sc = __expf(m - mn);
        float w0 = __expf(e0 - mn);
        den = den * sc + w0;
        #pragma unroll
        for (int j = 0; j < 8; j++) acc[j] = acc[j] * sc + w0 * b2f(U0.u[j]);
    }
    float inv = den > 0.f ? 1.f / den : 0.f;
    union { int4 v; u16 u[8]; } Hi, Lo;
    float o[8];
    #pragma unroll
    for (int j = 0; j < 8; j++) {
        float v = acc[j] * inv + bias[f + j];
        o[j] = v > 0.f ? v : __expf(v) - 1.f;  // ELU
        splitbf(o[j], Hi.u[j], Lo.u[j]);
    }
    size_t base = (size_t)node * HDIM + f;
    *(int4*)&ohi[base] = Hi.v;
    *(int4*)&olo[base] = Lo.v;
    if (rhi) {
        union { int4 v; u16 u[8]; } Rh, Rl, Qh, Ql;
        Rh.v = *(const int4*)&rhi[base];
        Rl.v = *(const int4*)&rlo[base];
        #pragma unroll
        for (int j = 0; j < 8; j++) {
            float v = o[j] + b2f(Rh.u[j]) + b2f(Rl.u[j]);
            splitbf(v, Qh.u[j], Ql.u[j]);
        }
        *(int4*)&qhi[base] = Qh.v;
        *(int4*)&qlo[base] = Ql.v;
    }
}

// ---- pooling stage 1: partial segment-max over bf16-hi (0.4% max error, in budget) ----
__global__ void pool1_kernel(const u16* __restrict__ s0h, const u16* __restrict__ s1h,
                             const u16* __restrict__ s2h, const u16* __restrict__ s3h,
                             const int* __restrict__ batch, float* __restrict__ partial, int n) {
    int g = blockIdx.x, b = blockIdx.y, c = blockIdx.z;
    int t = threadIdx.x;
    const u16* hs[4] = {s0h, s1h, s2h, s3h};
    const u16* sh = hs[b];
    int lo = 0, hi = n;
    while (lo < hi) { int mid = (lo + hi) >> 1; if (batch[mid] < g) lo = mid + 1; else hi = mid; }
    int start = lo;
    lo = start; hi = n;
    while (lo < hi) { int mid = (lo + hi) >> 1; if (batch[mid] < g + 1) lo = mid + 1; else hi = mid; }
    int end = lo;
    int len = end - start;
    int cb = start + (int)(((long long)len * c) / PSPLIT);
    int ce = start + (int)(((long long)len * (c + 1)) / PSPLIT);
    float mx0 = -INFINITY, mx1 = -INFINITY;
    for (int i = cb; i < ce; i++) {
        size_t ro = (size_t)i * HDIM;
        mx0 = fmaxf(mx0, b2f(sh[ro + t]));
        mx1 = fmaxf(mx1, b2f(sh[ro + 256 + t]));
    }
    size_t pb = (size_t)((g * 4 + b) * PSPLIT + c) * 512;
    partial[pb + t] = mx0;
    partial[pb + 256 + t] = mx1;
}

// ---- pooling stage 2: reduce PSPLIT partials, clamp empties ----
__global__ void pool2_kernel(const float* __restrict__ partial, float* __restrict__ pooled) {
    int g = blockIdx.x, b = blockIdx.y;
    int t = threadIdx.x;
    float mx0 = -INFINITY, mx1 = -INFINITY;
    for (int c = 0; c < PSPLIT; c++) {
        size_t pb = (size_t)((g * 4 + b) * PSPLIT + c) * 512;
        mx0 = fmaxf(mx0, partial[pb + t]);
        mx1 = fmaxf(mx1, partial[pb + 256 + t]);
    }
    if (!isfinite(mx0)) mx0 = 0.f;
    if (!isfinite(mx1)) mx1 = 0.f;
    pooled[g * 2048 + b * 512 + t] = mx0;
    pooled[g * 2048 + b * 512 + 256 + t] = mx1;
}

// ---- z init: z[g][c] = mb1[c] ----
__global__ void zinit_kernel(float* __restrict__ z, const float* __restrict__ mb1) {
    int i = blockIdx.x * 256 + threadIdx.x;
    if (i < GNUM * HDIM) z[i] = mb1[i & (HDIM - 1)];
}

// ---- MLP layer 1, split-K: z[64,512] += pooled[64,2048-chunk] @ mW1-chunk ----
__global__ __launch_bounds__(256) void mlp1_splitk(const float* __restrict__ pooled,
                                                   const float* __restrict__ mW1,
                                                   float* __restrict__ z) {
    __shared__ float sp[256];
    int g = blockIdx.x, kc = blockIdx.y * 256;
    int t = threadIdx.x;
    sp[t] = pooled[g * 2048 + kc + t];
    __syncthreads();
    float acc0 = 0.f, acc1 = 0.f;
    const float* wp = mW1 + (size_t)kc * HDIM;
    #pragma unroll 8
    for (int k = 0; k < 256; k++) {
        float pv = sp[k];
        acc0 += pv * wp[(size_t)k * HDIM + t];
        acc1 += pv * wp[(size_t)k * HDIM + 256 + t];
    }
    atomicAdd(&z[g * HDIM + t], acc0);
    atomicAdd(&z[g * HDIM + 256 + t], acc1);
}

// ---- BatchNorm (batch stats over 64 graphs) + ReLU ----
__global__ void bn_relu_kernel(const float* __restrict__ z, const float* __restrict__ gammaf,
                               const float* __restrict__ betaf, float* __restrict__ zn) {
    int col = blockIdx.x;
    int g = threadIdx.x;   // 64 = one wave
    float v = z[g * HDIM + col];
    float s = v;
    for (int o = 32; o > 0; o >>= 1) s += __shfl_xor(s, o);
    float mu = s * (1.f / 64.f);
    float d = v - mu;
    float s2 = d * d;
    for (int o = 32; o > 0; o >>= 1) s2 += __shfl_xor(s2, o);
    float var = s2 * (1.f / 64.f);
    float o = d * rsqrtf(var + BNEPS) * gammaf[col] + betaf[col];
    zn[g * HDIM + col] = fmaxf(o, 0.f);
}

// ---- final: out[64,10] = zn @ mW2 + mb2 (f32 out) ----
__global__ void final_kernel(const float* __restrict__ zn, const float* __restrict__ mW2,
                             const float* __restrict__ mb2, float* __restrict__ out) {
    int t = threadIdx.x;
    if (t >= GNUM * CNUM) return;
    int g = t / CNUM, c = t - g * CNUM;
    float acc = mb2[c];
    for (int k = 0; k < HDIM; k++) acc += zn[g * HDIM + k] * mW2[k * CNUM + c];
    out[t] = acc;
}

extern "C" void kernel_launch(void* const* d_in, const int* in_sizes, int n_in,
                              void* d_out, int out_size, void* d_ws, size_t ws_size,
                              hipStream_t stream) {
    const float* x = (const float*)d_in[0];
    const int* ei = (const int*)d_in[1];
    const int* batch = (const int*)d_in[2];
    const float* Wm[4] = {(const float*)d_in[3], (const float*)d_in[7],
                          (const float*)d_in[11], (const float*)d_in[15]};
    const float* Asc[4] = {(const float*)d_in[4], (const float*)d_in[8],
                           (const float*)d_in[12], (const float*)d_in[16]};
    const float* Adc[4] = {(const float*)d_in[5], (const float*)d_in[9],
                           (const float*)d_in[13], (const float*)d_in[17]};
    const float* Bb[4] = {(const float*)d_in[6], (const float*)d_in[10],
                          (const float*)d_in[14], (const float*)d_in[18]};
    const float* mW1 = (const float*)d_in[19];
    const float* mb1 = (const float*)d_in[20];
    const float* gammaf = (const float*)d_in[21];
    const float* betaf = (const float*)d_in[22];
    const float* mW2 = (const float*)d_in[23];
    const float* mb2 = (const float*)d_in[24];
    (void)n_in;

    int N = in_sizes[2];
    int E = in_sizes[1] / 2;
    int F0 = in_sizes[0] / N;

    // ---- workspace carve (256B-aligned) ----
    char* p = (char*)d_ws;
    auto alloc = [&](size_t bytes) -> char* {
        char* r = p;
        p += (bytes + 255) & ~(size_t)255;
        return r;
    };
    u16 *Wh[4], *Wl[4];
    Wh[0] = (u16*)alloc((size_t)HDIM * F0 * 2);
    Wl[0] = (u16*)alloc((size_t)HDIM * F0 * 2);
    for (int l = 1; l < 4; l++) {
        Wh[l] = (u16*)alloc((size_t)HDIM * HDIM * 2);
        Wl[l] = (u16*)alloc((size_t)HDIM * HDIM * 2);
    }
    u16* xinh = (u16*)alloc((size_t)N * F0 * 2);
    u16* xinl = (u16*)alloc((size_t)N * F0 * 2);
    u16* hhi = (u16*)alloc((size_t)N * HDIM * 2);       // h of current layer (bf16-hi only)
    u16 *xh[4], *xl[4];                                 // x0,x1,x2,x3 as hi/lo bf16 pairs
    for (int l = 0; l < 4; l++) {
        xh[l] = (u16*)alloc((size_t)N * HDIM * 2);
        xl[l] = (u16*)alloc((size_t)N * HDIM * 2);
    }
    float* es = (float*)alloc((size_t)N * NHEAD * 4);
    float* ed = (float*)alloc((size_t)N * NHEAD * 4);
    int* deg = (int*)alloc((size_t)N * 4);
    int* offs = (int*)alloc((size_t)N * 4);
    int* cursor = (int*)alloc((size_t)N * 4);
    int* ssrc = (int*)alloc((size_t)E * 4);
    float* partial = (float*)alloc((size_t)GNUM * 4 * PSPLIT * 512 * 4);
    float* pooled = (float*)alloc((size_t)GNUM * 4 * HDIM * 4);
    float* z = (float*)alloc((size_t)GNUM * HDIM * 4);
    float* zn = (float*)alloc((size_t)GNUM * HDIM * 4);

    if ((size_t)(p - (char*)d_ws) > ws_size) {
        sentinel_kernel<<<(out_size + 255) / 256, 256, 0, stream>>>((float*)d_out, out_size, 999.f);
        return;
    }

    // ---- weight transpose+split (W0 alone; W1-3 batched), input split ----
    {
        dim3 wg0(F0 / 64, HDIM / 64);
        wsplit_kernel<<<wg0, 256, 0, stream>>>(Wm[0], Wh[0], Wl[0], F0);
        dim3 wg3(HDIM / 64, HDIM / 64, 3);
        wsplit3_kernel<<<wg3, 256, 0, stream>>>(Wm[1], Wm[2], Wm[3],
                                                Wh[1], Wl[1], Wh[2], Wl[2], Wh[3], Wl[3]);
    }
    xsplit_kernel<<<(N * F0 + 255) / 256, 256, 0, stream>>>(x, xinh, xinl, N * F0);

    // ---- counting sort of edges by dst ----
    zero_i32_kernel<<<(N + 255) / 256, 256, 0, stream>>>(deg, N);
    hist_kernel<<<(E + 255) / 256, 256, 0, stream>>>(ei, deg, E);
    scan_kernel<<<1, 1024, 0, stream>>>(deg, offs, cursor, N);
    scatter_kernel<<<(E + 255) / 256, 256, 0, stream>>>(ei, cursor, ssrc, E);

    // ---- 4 GAT layers ----
    const u16* linh[4] = {xinh, xh[0], xh[1], xh[3]};
    const u16* linl[4] = {xinl, xl[0], xl[1], xl[3]};
    int lK[4] = {F0, HDIM, HDIM, HDIM};
    // layer outputs: L0->x0, L1->x1, L2->x2 (+x3 residual), L3->xt (aliases x0, dead)
    u16* louth[4] = {xh[0], xh[1], xh[2], xh[0]};
    u16* loutl[4] = {xl[0], xl[1], xl[2], xl[0]};
    int nrt = (N + 127) / 128;
    int gemm_blocks = nrt * 8;                          // 1-D, XCD-swizzled inside
    int agg_blocks = (N + 3) / 4;
    for (int L = 0; L < 4; L++) {
        gemm_split<<<gemm_blocks, 256, 0, stream>>>(linh[L], linl[L], Wh[L], Wl[L],
                                                    Asc[L], Adc[L], hhi, es, ed, N, lK[L]);
        const u16* rh = (L == 2) ? xh[0] : nullptr;
        const u16* rl = (L == 2) ? xl[0] : nullptr;
        u16* qh = (L == 2) ? xh[3] : nullptr;
        u16* ql = (L == 2) ? xl[3] : nullptr;
        agg_kernel<<<agg_blocks, 256, 0, stream>>>(hhi, es, ed, offs, deg, ssrc, Bb[L],
                                                   louth[L], loutl[L], rh, rl, qh, ql, N);
    }

    // ---- pooling (two-stage, hi-only): concat order (xt, x1, x2, x3) ----
    dim3 pool1_grid(GNUM, 4, PSPLIT);
    pool1_kernel<<<pool1_grid, 256, 0, stream>>>(xh[0], xh[1], xh[2], xh[3],
                                                 batch, partial, N);
    dim3 pool2_grid(GNUM, 4);
    pool2_kernel<<<pool2_grid, 256, 0, stream>>>(partial, pooled);

    // ---- MLP head: bias-init z, split-K accumulate, BN+ReLU, final ----
    zinit_kernel<<<(GNUM * HDIM + 255) / 256, 256, 0, stream>>>(z, mb1);
    dim3 mlp_grid(GNUM, 8);
    mlp1_splitk<<<mlp_grid, 256, 0, stream>>>(pooled, mW1, z);
    bn_relu_kernel<<<HDIM, 64, 0, stream>>>(z, gammaf, betaf, zn);
    final_kernel<<<1, 640, 0, stream>>>(zn, mW2, mb2, (float*)d_out);
}

// Round 11
// 436.283 us; speedup vs baseline: 2.1521x; 1.0903x over previous
//
#include <hip/hip_runtime.h>

typedef unsigned short u16;
typedef __bf16 bfv8 __attribute__((ext_vector_type(8)));     // MFMA A/B fragment (4 VGPRs)
typedef float f32x16 __attribute__((ext_vector_type(16)));   // MFMA 32x32 C/D fragment

#define HDIM 512
#define NHEAD 8
#define GNUM 64
#define CNUM 10
#define SLOPE 0.01f
#define BNEPS 1e-5f
#define PSPLIT 8

__device__ __forceinline__ float b2f(u16 u) { return __uint_as_float(((unsigned)u) << 16); }
__device__ __forceinline__ u16 f2b(float f) {              // RNE f32->bf16
    unsigned u = __float_as_uint(f);
    u += 0x7FFFu + ((u >> 16) & 1u);
    return (u16)(u >> 16);
}
__device__ __forceinline__ void splitbf(float v, u16& hi, u16& lo) {
    u16 h = f2b(v);
    hi = h;
    lo = f2b(v - b2f(h));
}

__global__ void sentinel_kernel(float* out, int n, float val) {
    int i = blockIdx.x * 256 + threadIdx.x;
    if (i < n) out[i] = val;
}

__global__ void zero_i32_kernel(int* __restrict__ p, int n) {
    int i = blockIdx.x * 256 + threadIdx.x;
    if (i < n) p[i] = 0;
}

// ---- weight transpose+split via LDS tiles: W[K][512] f32 -> Whi/Wlo[n][K] bf16 ----
__device__ __forceinline__ void wsplit_body(const float* __restrict__ W, u16* __restrict__ Whi,
                                            u16* __restrict__ Wlo, int K) {
    __shared__ float tile[64][65];
    int kb = blockIdx.x * 64, nb = blockIdx.y * 64;
    int t = threadIdx.x;
    #pragma unroll
    for (int i = 0; i < 16; i++) {
        int idx = t + i * 256;
        int r = idx >> 6, c = idx & 63;
        tile[r][c] = W[(size_t)(kb + r) * HDIM + nb + c];
    }
    __syncthreads();
    #pragma unroll
    for (int i = 0; i < 16; i++) {
        int idx = t + i * 256;
        int r = idx >> 6, c = idx & 63;
        float v = tile[c][r];
        u16 hi, lo;
        splitbf(v, hi, lo);
        size_t o = (size_t)(nb + r) * K + kb + c;
        Whi[o] = hi;
        Wlo[o] = lo;
    }
}

__global__ void wsplit_kernel(const float* __restrict__ W, u16* __restrict__ Whi,
                              u16* __restrict__ Wlo, int K) {
    wsplit_body(W, Whi, Wlo, K);
}

// W1,W2,W3 (all K=512) in one launch, grid.z selects layer
__global__ void wsplit3_kernel(const float* __restrict__ W1, const float* __restrict__ W2,
                               const float* __restrict__ W3,
                               u16* __restrict__ h1, u16* __restrict__ l1,
                               u16* __restrict__ h2, u16* __restrict__ l2,
                               u16* __restrict__ h3, u16* __restrict__ l3) {
    const float* W = (blockIdx.z == 0) ? W1 : (blockIdx.z == 1) ? W2 : W3;
    u16* Wh = (blockIdx.z == 0) ? h1 : (blockIdx.z == 1) ? h2 : h3;
    u16* Wl = (blockIdx.z == 0) ? l1 : (blockIdx.z == 1) ? l2 : l3;
    wsplit_body(W, Wh, Wl, HDIM);
}

// ---- activation split: f32 -> hi/lo bf16 ----
__global__ void xsplit_kernel(const float* __restrict__ x, u16* __restrict__ hi,
                              u16* __restrict__ lo, int n) {
    int i = blockIdx.x * 256 + threadIdx.x;
    if (i < n) splitbf(x[i], hi[i], lo[i]);
}

// ---- split-bf16 MFMA GEMM (32x32x16), block tile 128x64, BK=32, 3-term ----
// XCD-swizzled 1-D grid (verified: FETCH 87->15 MB). Software-pipelined K-loop:
// next tile prefetched into regs right after the consume-barrier, overlapping the
// L2 staging latency with the 24-MFMA compute. 3 blocks/CU -> all blocks co-resident.
__global__ __launch_bounds__(256, 3) void gemm_split(const u16* __restrict__ Ah,
                                                     const u16* __restrict__ Al,
                                                     const u16* __restrict__ Bh,
                                                     const u16* __restrict__ Bl,
                                                     const float* __restrict__ a_src,
                                                     const float* __restrict__ a_dst,
                                                     u16* __restrict__ Chi,
                                                     float* __restrict__ es,
                                                     float* __restrict__ ed, int M, int K) {
    __shared__ u16 sAh[128 * 40];   // [m][k], pad 40 (80B row stride)
    __shared__ u16 sAl[128 * 40];
    __shared__ u16 sBh[64 * 40];    // [n][k]
    __shared__ u16 sBl[64 * 40];
    __shared__ float sE[128][2][2]; // [row][wn-half][es/ed]
    int t = threadIdx.x;
    int id = blockIdx.x;
    int nrt = gridDim.x >> 3;
    int w = (id & 7) * nrt + (id >> 3);
    int rt = w >> 3, ct = w & 7;
    int bm = rt * 128, bn = ct * 64;
    int hh = ct;                    // head index (64 cols per head)
    int wv = t >> 6, lane = t & 63;
    int wm = (wv >> 1) * 64, wn = (wv & 1) * 32;
    int l32 = lane & 31, kh = lane >> 5;

    int ar0 = (2 * t) >> 2, ac0 = ((2 * t) & 3) * 8;
    int ar1 = (2 * t + 1) >> 2, ac1 = ((2 * t + 1) & 3) * 8;
    int br = t >> 2, bc = (t & 3) * 8;

    f32x16 acc[2];
    for (int m = 0; m < 2; m++)
        for (int r = 0; r < 16; r++) acc[m][r] = 0.f;

    bool ok0 = (bm + ar0) < M, ok1 = (bm + ar1) < M;
    const u16* Ahp0 = Ah + (size_t)(bm + ar0) * K + ac0;
    const u16* Alp0 = Al + (size_t)(bm + ar0) * K + ac0;
    const u16* Ahp1 = Ah + (size_t)(bm + ar1) * K + ac1;
    const u16* Alp1 = Al + (size_t)(bm + ar1) * K + ac1;
    const u16* Bhp = Bh + (size_t)(bn + br) * K + bc;
    const u16* Blp = Bl + (size_t)(bn + br) * K + bc;

    int4 a0h = make_int4(0, 0, 0, 0), a0l = a0h, a1h = a0h, a1l = a0h;
    if (ok0) { a0h = *(const int4*)(Ahp0); a0l = *(const int4*)(Alp0); }
    if (ok1) { a1h = *(const int4*)(Ahp1); a1l = *(const int4*)(Alp1); }
    int4 bvh = *(const int4*)(Bhp);
    int4 bvl = *(const int4*)(Blp);

    for (int kt = 0; kt < K; kt += 32) {
        __syncthreads();
        *(int4*)&sAh[ar0 * 40 + ac0] = a0h;
        *(int4*)&sAl[ar0 * 40 + ac0] = a0l;
        *(int4*)&sAh[ar1 * 40 + ac1] = a1h;
        *(int4*)&sAl[ar1 * 40 + ac1] = a1l;
        *(int4*)&sBh[br * 40 + bc] = bvh;
        *(int4*)&sBl[br * 40 + bc] = bvl;
        __syncthreads();
        int ktn = kt + 32;
        if (ktn < K) {                      // prefetch next tile; waited at next LDS-write
            a0h = make_int4(0, 0, 0, 0); a0l = a0h; a1h = a0h; a1l = a0h;
            if (ok0) { a0h = *(const int4*)(Ahp0 + ktn); a0l = *(const int4*)(Alp0 + ktn); }
            if (ok1) { a1h = *(const int4*)(Ahp1 + ktn); a1l = *(const int4*)(Alp1 + ktn); }
            bvh = *(const int4*)(Bhp + ktn);
            bvl = *(const int4*)(Blp + ktn);
        }
        #pragma unroll
        for (int ks = 0; ks < 32; ks += 16) {
            int ko = ks + kh * 8;
            bfv8 a0 = *(bfv8*)&sAh[(wm + l32) * 40 + ko];
            bfv8 a0lo = *(bfv8*)&sAl[(wm + l32) * 40 + ko];
            bfv8 a1 = *(bfv8*)&sAh[(wm + 32 + l32) * 40 + ko];
            bfv8 a1lo = *(bfv8*)&sAl[(wm + 32 + l32) * 40 + ko];
            bfv8 b = *(bfv8*)&sBh[(wn + l32) * 40 + ko];
            bfv8 blo = *(bfv8*)&sBl[(wn + l32) * 40 + ko];
            acc[0] = __builtin_amdgcn_mfma_f32_32x32x16_bf16(a0lo, b, acc[0], 0, 0, 0);
            acc[0] = __builtin_amdgcn_mfma_f32_32x32x16_bf16(a0, blo, acc[0], 0, 0, 0);
            acc[0] = __builtin_amdgcn_mfma_f32_32x32x16_bf16(a0, b, acc[0], 0, 0, 0);
            acc[1] = __builtin_amdgcn_mfma_f32_32x32x16_bf16(a1lo, b, acc[1], 0, 0, 0);
            acc[1] = __builtin_amdgcn_mfma_f32_32x32x16_bf16(a1, blo, acc[1], 0, 0, 0);
            acc[1] = __builtin_amdgcn_mfma_f32_32x32x16_bf16(a1, b, acc[1], 0, 0, 0);
        }
    }
    float asv = a_src[hh * 64 + wn + l32];
    float adv = a_dst[hh * 64 + wn + l32];
    // C/D layout (m74/m101-verified): col=lane&31, row=(reg&3)+8*(reg>>2)+4*(lane>>5)
    int col = bn + wn + l32;
    #pragma unroll
    for (int mt = 0; mt < 2; mt++)
        #pragma unroll
        for (int r = 0; r < 16; r++) {
            float v = acc[mt][r];
            int lr = wm + mt * 32 + (r & 3) + 8 * (r >> 2) + 4 * kh;   // block-local row
            int row = bm + lr;
            if (row < M) Chi[(size_t)row * HDIM + col] = f2b(v);
            float s1 = v * asv, s2 = v * adv;
            #pragma unroll
            for (int msk = 1; msk <= 16; msk <<= 1) {
                s1 += __shfl_xor(s1, msk);
                s2 += __shfl_xor(s2, msk);
            }
            if (l32 == 0) { sE[lr][wv & 1][0] = s1; sE[lr][wv & 1][1] = s2; }
        }
    __syncthreads();
    if (t < 128) {
        int row = bm + t;
        if (row < M) {
            es[row * NHEAD + hh] = sE[t][0][0] + sE[t][1][0];
            ed[row * NHEAD + hh] = sE[t][0][1] + sE[t][1][1];
        }
    }
}

// ---- counting sort of edges by dst ----
__global__ void hist_kernel(const int* __restrict__ ei, int* __restrict__ deg, int E) {
    int e = blockIdx.x * 256 + threadIdx.x;
    if (e < E) atomicAdd(&deg[ei[E + e]], 1);
}

__global__ void scan_kernel(const int* __restrict__ deg, int* __restrict__ offs,
                            int* __restrict__ cursor, int n) {
    __shared__ int lds[1024];
    int t = threadIdx.x;
    const int CH = 16;
    int base = t * CH;
    int local[CH];
    int s = 0;
    for (int i = 0; i < CH; i++) {
        int idx = base + i;
        local[i] = (idx < n) ? deg[idx] : 0;
        s += local[i];
    }
    lds[t] = s;
    __syncthreads();
    for (int off = 1; off < 1024; off <<= 1) {
        int v = lds[t];
        int add = (t >= off) ? lds[t - off] : 0;
        __syncthreads();
        lds[t] = v + add;
        __syncthreads();
    }
    int ex = (t == 0) ? 0 : lds[t - 1];
    for (int i = 0; i < CH; i++) {
        int idx = base + i;
        if (idx < n) { offs[idx] = ex; cursor[idx] = ex; ex += local[i]; }
    }
}

__global__ void scatter_kernel(const int* __restrict__ ei, int* __restrict__ cursor,
                               int* __restrict__ ssrc, int E) {
    int e = blockIdx.x * 256 + threadIdx.x;
    if (e < E) {
        int p = atomicAdd(&cursor[ei[E + e]], 1);
        ssrc[p] = ei[e];
    }
}

// ---- fused per-dst ONLINE softmax + aggregation + bias + ELU (+ residual) ----
__global__ void agg_kernel(const u16* __restrict__ hh_buf, const float* __restrict__ es,
                           const float* __restrict__ ed, const int* __restrict__ offs,
                           const int* __restrict__ deg, const int* __restrict__ ssrc,
                           const float* __restrict__ bias,
                           u16* __restrict__ ohi, u16* __restrict__ olo,
                           const u16* __restrict__ rhi, const u16* __restrict__ rlo,
                           u16* __restrict__ qhi, u16* __restrict__ qlo, int n) {
    int node = blockIdx.x * 4 + (threadIdx.x >> 6);
    int lane = threadIdx.x & 63;
    if (node >= n) return;
    int hh = lane >> 3, f = lane * 8;
    float edv = ed[node * NHEAD + hh];
    int st = offs[node], cnt = deg[node];

    float m = -INFINITY, den = 0.f;
    float acc[8] = {0.f, 0.f, 0.f, 0.f, 0.f, 0.f, 0.f, 0.f};
    int i = 0;
    for (; i + 2 <= cnt; i += 2) {
        int s0 = ssrc[st + i];
        int s1 = ssrc[st + i + 1];
        float e0 = es[s0 * NHEAD + hh] + edv;
        float e1 = es[s1 * NHEAD + hh] + edv;
        union { int4 v; u16 u[8]; } U0, U1;
        U0.v = *(const int4*)(hh_buf + (size_t)s0 * HDIM + f);
        U1.v = *(const int4*)(hh_buf + (size_t)s1 * HDIM + f);
        e0 = e0 > 0.f ? e0 : SLOPE * e0;
        e1 = e1 > 0.f ? e1 : SLOPE * e1;
        float mn = fmaxf(m, fmaxf(e0, e1));
        float sc = __expf(m - mn);       // first iter: exp(-inf)=0
        float w0 = __expf(e0 - mn);
        float w1 = __expf(e1 - mn);
        den = den * sc + w0 + w1;
        #pragma unroll
        for (int j = 0; j < 8; j++)
            acc[j] = acc[j] * sc + w0 * b2f(U0.u[j]) + w1 * b2f(U1.u[j]);
        m = mn;
    }
    if (i < cnt) {
        int s0 = ssrc[st + i];
        float e0 = es[s0 * NHEAD + hh] + edv;
        union { int4 v; u16 u[8]; } U0;
        U0.v = *(const int4*)(hh_buf + (size_t)s0 * HDIM + f);
        e0 = e0 > 0.f ? e0 : SLOPE * e0;
        float mn = fmaxf(m, e0);
        float sc = __expf(m - mn);
        float w0 = __expf(e0 - mn);
        den = den * sc + w0;
        #pragma unroll
        for (int j = 0; j < 8; j++) acc[j] = acc[j] * sc + w0 * b2f(U0.u[j]);
    }
    float inv = den > 0.f ? 1.f / den : 0.f;
    union { int4 v; u16 u[8]; } Hi, Lo;
    float o[8];
    #pragma unroll
    for (int j = 0; j < 8; j++) {
        float v = acc[j] * inv + bias[f + j];
        o[j] = v > 0.f ? v : __expf(v) - 1.f;  // ELU
        splitbf(o[j], Hi.u[j], Lo.u[j]);
    }
    size_t base = (size_t)node * HDIM + f;
    *(int4*)&ohi[base] = Hi.v;
    *(int4*)&olo[base] = Lo.v;
    if (rhi) {
        union { int4 v; u16 u[8]; } Rh, Rl, Qh, Ql;
        Rh.v = *(const int4*)&rhi[base];
        Rl.v = *(const int4*)&rlo[base];
        #pragma unroll
        for (int j = 0; j < 8; j++) {
            float v = o[j] + b2f(Rh.u[j]) + b2f(Rl.u[j]);
            splitbf(v, Qh.u[j], Ql.u[j]);
        }
        *(int4*)&qhi[base] = Qh.v;
        *(int4*)&qlo[base] = Ql.v;
    }
}

// ---- pooling stage 1: partial segment-max over bf16-hi ----
__global__ void pool1_kernel(const u16* __restrict__ s0h, const u16* __restrict__ s1h,
                             const u16* __restrict__ s2h, const u16* __restrict__ s3h,
                             const int* __restrict__ batch, float* __restrict__ partial, int n) {
    int g = blockIdx.x, b = blockIdx.y, c = blockIdx.z;
    int t = threadIdx.x;
    const u16* hs[4] = {s0h, s1h, s2h, s3h};
    const u16* sh = hs[b];
    int lo = 0, hi = n;
    while (lo < hi) { int mid = (lo + hi) >> 1; if (batch[mid] < g) lo = mid + 1; else hi = mid; }
    int start = lo;
    lo = start; hi = n;
    while (lo < hi) { int mid = (lo + hi) >> 1; if (batch[mid] < g + 1) lo = mid + 1; else hi = mid; }
    int end = lo;
    int len = end - start;
    int cb = start + (int)(((long long)len * c) / PSPLIT);
    int ce = start + (int)(((long long)len * (c + 1)) / PSPLIT);
    float mx0 = -INFINITY, mx1 = -INFINITY;
    for (int i = cb; i < ce; i++) {
        size_t ro = (size_t)i * HDIM;
        mx0 = fmaxf(mx0, b2f(sh[ro + t]));
        mx1 = fmaxf(mx1, b2f(sh[ro + 256 + t]));
    }
    size_t pb = (size_t)((g * 4 + b) * PSPLIT + c) * 512;
    partial[pb + t] = mx0;
    partial[pb + 256 + t] = mx1;
}

// ---- pooling stage 2: reduce PSPLIT partials, clamp empties; fused z init ----
__global__ void pool2_kernel(const float* __restrict__ partial, float* __restrict__ pooled,
                             const float* __restrict__ mb1, float* __restrict__ z) {
    int g = blockIdx.x, b = blockIdx.y;
    int t = threadIdx.x;
    float mx0 = -INFINITY, mx1 = -INFINITY;
    for (int c = 0; c < PSPLIT; c++) {
        size_t pb = (size_t)((g * 4 + b) * PSPLIT + c) * 512;
        mx0 = fmaxf(mx0, partial[pb + t]);
        mx1 = fmaxf(mx1, partial[pb + 256 + t]);
    }
    if (!isfinite(mx0)) mx0 = 0.f;
    if (!isfinite(mx1)) mx1 = 0.f;
    pooled[g * 2048 + b * 512 + t] = mx0;
    pooled[g * 2048 + b * 512 + 256 + t] = mx1;
    if (t < 128) {                       // fused: z[g][b*128 + t] = mb1[...]
        int col = b * 128 + t;
        z[g * HDIM + col] = mb1[col];
    }
}

// ---- MLP layer 1, split-K: z[64,512] += pooled[64,2048-chunk] @ mW1-chunk ----
__global__ __launch_bounds__(256) void mlp1_splitk(const float* __restrict__ pooled,
                                                   const float* __restrict__ mW1,
                                                   float* __restrict__ z) {
    __shared__ float sp[256];
    int g = blockIdx.x, kc = blockIdx.y * 256;
    int t = threadIdx.x;
    sp[t] = pooled[g * 2048 + kc + t];
    __syncthreads();
    float acc0 = 0.f, acc1 = 0.f;
    const float* wp = mW1 + (size_t)kc * HDIM;
    #pragma unroll 8
    for (int k = 0; k < 256; k++) {
        float pv = sp[k];
        acc0 += pv * wp[(size_t)k * HDIM + t];
        acc1 += pv * wp[(size_t)k * HDIM + 256 + t];
    }
    atomicAdd(&z[g * HDIM + t], acc0);
    atomicAdd(&z[g * HDIM + 256 + t], acc1);
}

// ---- BatchNorm (batch stats over 64 graphs) + ReLU ----
__global__ void bn_relu_kernel(const float* __restrict__ z, const float* __restrict__ gammaf,
                               const float* __restrict__ betaf, float* __restrict__ zn) {
    int col = blockIdx.x;
    int g = threadIdx.x;   // 64 = one wave
    float v = z[g * HDIM + col];
    float s = v;
    for (int o = 32; o > 0; o >>= 1) s += __shfl_xor(s, o);
    float mu = s * (1.f / 64.f);
    float d = v - mu;
    float s2 = d * d;
    for (int o = 32; o > 0; o >>= 1) s2 += __shfl_xor(s2, o);
    float var = s2 * (1.f / 64.f);
    float o = d * rsqrtf(var + BNEPS) * gammaf[col] + betaf[col];
    zn[g * HDIM + col] = fmaxf(o, 0.f);
}

// ---- final: out[g][c] = zn[g,:] . mW2[:,c] + mb2[c]; one wave per output ----
__global__ void final_kernel(const float* __restrict__ zn, const float* __restrict__ mW2,
                             const float* __restrict__ mb2, float* __restrict__ out) {
    int g = blockIdx.x, c = blockIdx.y;
    int lane = threadIdx.x;   // 64
    float acc = 0.f;
    #pragma unroll
    for (int k = lane; k < HDIM; k += 64) acc += zn[g * HDIM + k] * mW2[k * CNUM + c];
    for (int o = 32; o > 0; o >>= 1) acc += __shfl_down(acc, o);
    if (lane == 0) out[g * CNUM + c] = acc + mb2[c];
}

extern "C" void kernel_launch(void* const* d_in, const int* in_sizes, int n_in,
                              void* d_out, int out_size, void* d_ws, size_t ws_size,
                              hipStream_t stream) {
    const float* x = (const float*)d_in[0];
    const int* ei = (const int*)d_in[1];
    const int* batch = (const int*)d_in[2];
    const float* Wm[4] = {(const float*)d_in[3], (const float*)d_in[7],
                          (const float*)d_in[11], (const float*)d_in[15]};
    const float* Asc[4] = {(const float*)d_in[4], (const float*)d_in[8],
                           (const float*)d_in[12], (const float*)d_in[16]};
    const float* Adc[4] = {(const float*)d_in[5], (const float*)d_in[9],
                           (const float*)d_in[13], (const float*)d_in[17]};
    const float* Bb[4] = {(const float*)d_in[6], (const float*)d_in[10],
                          (const float*)d_in[14], (const float*)d_in[18]};
    const float* mW1 = (const float*)d_in[19];
    const float* mb1 = (const float*)d_in[20];
    const float* gammaf = (const float*)d_in[21];
    const float* betaf = (const float*)d_in[22];
    const float* mW2 = (const float*)d_in[23];
    const float* mb2 = (const float*)d_in[24];
    (void)n_in;

    int N = in_sizes[2];
    int E = in_sizes[1] / 2;
    int F0 = in_sizes[0] / N;

    // ---- workspace carve (256B-aligned) ----
    char* p = (char*)d_ws;
    auto alloc = [&](size_t bytes) -> char* {
        char* r = p;
        p += (bytes + 255) & ~(size_t)255;
        return r;
    };
    u16 *Wh[4], *Wl[4];
    Wh[0] = (u16*)alloc((size_t)HDIM * F0 * 2);
    Wl[0] = (u16*)alloc((size_t)HDIM * F0 * 2);
    for (int l = 1; l < 4; l++) {
        Wh[l] = (u16*)alloc((size_t)HDIM * HDIM * 2);
        Wl[l] = (u16*)alloc((size_t)HDIM * HDIM * 2);
    }
    u16* xinh = (u16*)alloc((size_t)N * F0 * 2);
    u16* xinl = (u16*)alloc((size_t)N * F0 * 2);
    u16* hhi = (u16*)alloc((size_t)N * HDIM * 2);       // h of current layer (bf16-hi only)
    u16 *xh[4], *xl[4];                                 // x0,x1,x2,x3 as hi/lo bf16 pairs
    for (int l = 0; l < 4; l++) {
        xh[l] = (u16*)alloc((size_t)N * HDIM * 2);
        xl[l] = (u16*)alloc((size_t)N * HDIM * 2);
    }
    float* es = (float*)alloc((size_t)N * NHEAD * 4);
    float* ed = (float*)alloc((size_t)N * NHEAD * 4);
    int* deg = (int*)alloc((size_t)N * 4);
    int* offs = (int*)alloc((size_t)N * 4);
    int* cursor = (int*)alloc((size_t)N * 4);
    int* ssrc = (int*)alloc((size_t)E * 4);
    float* partial = (float*)alloc((size_t)GNUM * 4 * PSPLIT * 512 * 4);
    float* pooled = (float*)alloc((size_t)GNUM * 4 * HDIM * 4);
    float* z = (float*)alloc((size_t)GNUM * HDIM * 4);
    float* zn = (float*)alloc((size_t)GNUM * HDIM * 4);

    if ((size_t)(p - (char*)d_ws) > ws_size) {
        sentinel_kernel<<<(out_size + 255) / 256, 256, 0, stream>>>((float*)d_out, out_size, 999.f);
        return;
    }

    // ---- weight transpose+split (W0 alone; W1-3 batched), input split ----
    {
        dim3 wg0(F0 / 64, HDIM / 64);
        wsplit_kernel<<<wg0, 256, 0, stream>>>(Wm[0], Wh[0], Wl[0], F0);
        dim3 wg3(HDIM / 64, HDIM / 64, 3);
        wsplit3_kernel<<<wg3, 256, 0, stream>>>(Wm[1], Wm[2], Wm[3],
                                                Wh[1], Wl[1], Wh[2], Wl[2], Wh[3], Wl[3]);
    }
    xsplit_kernel<<<(N * F0 + 255) / 256, 256, 0, stream>>>(x, xinh, xinl, N * F0);

    // ---- counting sort of edges by dst ----
    zero_i32_kernel<<<(N + 255) / 256, 256, 0, stream>>>(deg, N);
    hist_kernel<<<(E + 255) / 256, 256, 0, stream>>>(ei, deg, E);
    scan_kernel<<<1, 1024, 0, stream>>>(deg, offs, cursor, N);
    scatter_kernel<<<(E + 255) / 256, 256, 0, stream>>>(ei, cursor, ssrc, E);

    // ---- 4 GAT layers ----
    const u16* linh[4] = {xinh, xh[0], xh[1], xh[3]};
    const u16* linl[4] = {xinl, xl[0], xl[1], xl[3]};
    int lK[4] = {F0, HDIM, HDIM, HDIM};
    // layer outputs: L0->x0, L1->x1, L2->x2 (+x3 residual), L3->xt (aliases x0, dead)
    u16* louth[4] = {xh[0], xh[1], xh[2], xh[0]};
    u16* loutl[4] = {xl[0], xl[1], xl[2], xl[0]};
    int nrt = (N + 127) / 128;
    int gemm_blocks = nrt * 8;                          // 1-D, XCD-swizzled inside
    int agg_blocks = (N + 3) / 4;
    for (int L = 0; L < 4; L++) {
        gemm_split<<<gemm_blocks, 256, 0, stream>>>(linh[L], linl[L], Wh[L], Wl[L],
                                                    Asc[L], Adc[L], hhi, es, ed, N, lK[L]);
        const u16* rh = (L == 2) ? xh[0] : nullptr;
        const u16* rl = (L == 2) ? xl[0] : nullptr;
        u16* qh = (L == 2) ? xh[3] : nullptr;
        u16* ql = (L == 2) ? xl[3] : nullptr;
        agg_kernel<<<agg_blocks, 256, 0, stream>>>(hhi, es, ed, offs, deg, ssrc, Bb[L],
                                                   louth[L], loutl[L], rh, rl, qh, ql, N);
    }

    // ---- pooling (two-stage, hi-only): concat order (xt, x1, x2, x3) ----
    dim3 pool1_grid(GNUM, 4, PSPLIT);
    pool1_kernel<<<pool1_grid, 256, 0, stream>>>(xh[0], xh[1], xh[2], xh[3],
                                                 batch, partial, N);
    dim3 pool2_grid(GNUM, 4);
    pool2_kernel<<<pool2_grid, 256, 0, stream>>>(partial, pooled, mb1, z);

    // ---- MLP head: split-K accumulate, BN+ReLU, final ----
    dim3 mlp_grid(GNUM, 8);
    mlp1_splitk<<<mlp_grid, 256, 0, stream>>>(pooled, mW1, z);
    bn_relu_kernel<<<HDIM, 64, 0, stream>>>(z, gammaf, betaf, zn);
    dim3 final_grid(GNUM, CNUM);
    final_kernel<<<final_grid, 64, 0, stream>>>(zn, mW2, mb2, (float*)d_out);
}